// Round 8
// baseline (4752.788 us; speedup 1.0000x reference)
//
#include <hip/hip_runtime.h>
#include <hip/hip_bf16.h>
#include <math.h>

#define L_SEQ 24
#define DT 1024
#define DM 256
#define NLAYER 12
#define NHEAD 4
#define HDIM 64
#define FFND 1024
#define NCLS 2
#define NBATCH 2048
#define NTOK (NBATCH*L_SEQ)   // 49152

typedef float f32x4 __attribute__((ext_vector_type(4)));
typedef __bf16 bf16x4 __attribute__((ext_vector_type(4)));
typedef __bf16 bf16x8 __attribute__((ext_vector_type(8)));

#define GLDS16(gp, lp) __builtin_amdgcn_global_load_lds((const __attribute__((address_space(1))) void*)(gp), (__attribute__((address_space(3))) void*)(lp), 16, 0, 0)
#define VMWAIT(N) asm volatile("s_waitcnt vmcnt(" #N ")" ::: "memory")
#define LGKM0()   asm volatile("s_waitcnt lgkmcnt(0)" ::: "memory")

__device__ inline float wred_sum(float v){
#pragma unroll
  for (int o = 32; o > 0; o >>= 1) v += __shfl_xor(v, o);
  return v;
}
__device__ inline float wred_max(float v){
#pragma unroll
  for (int o = 32; o > 0; o >>= 1) v = fmaxf(v, __shfl_xor(v, o));
  return v;
}

// ---- [R][32]-bf16 LDS tiles, BK=32: linear glds dest + global-source XOR swizzle ----
__device__ __forceinline__ void stage16x32(const __bf16* __restrict__ g, int ldk, int k0,
                                           __bf16* ldsbase, int lane, int rowbase){
  int r = rowbase + (lane >> 2);
  int cs = (lane & 3) ^ ((lane >> 3) & 3);
  GLDS16(g + (size_t)r*ldk + k0 + cs*8, ldsbase);
}
__device__ __forceinline__ bf16x8 frag32(const __bf16* tile, int row, int lane){
  int p = (lane >> 4) ^ ((row >> 1) & 3);
  return *(const bf16x8*)(tile + (row << 5) + (p << 3));
}

// XCD-aware swizzle (T1). Requires gridDim.x % 8 == 0.
__device__ __forceinline__ int xcd_work(){
  int nwg = gridDim.x, bid = blockIdx.x;
  return (bid & 7) * (nwg >> 3) + (bid >> 3);
}

// ---------------- merged weight fp32 -> bf16 convert (5 segments, 1 dispatch) --------
__global__ void cvt_all_kernel(const float* __restrict__ a0, __bf16* __restrict__ o0, int n0,
                               const float* __restrict__ a1, __bf16* __restrict__ o1, int n1,
                               const float* __restrict__ a2, __bf16* __restrict__ o2, int n2,
                               const float* __restrict__ a3, __bf16* __restrict__ o3, int n3,
                               const float* __restrict__ a4, __bf16* __restrict__ o4, int n4){
  int stride = gridDim.x * blockDim.x;
  int i0 = blockIdx.x * blockDim.x + threadIdx.x;
  const float* as[5] = {a0,a1,a2,a3,a4};
  __bf16* os[5] = {o0,o1,o2,o3,o4};
  int ns[5] = {n0,n1,n2,n3,n4};
#pragma unroll
  for (int s = 0; s < 5; s++){
    const float* a = as[s]; __bf16* o = os[s]; int n = ns[s];
    for (int i = i0; i < n; i += stride){
      float4 v = ((const float4*)a)[i];
      bf16x4 ov;
      ov[0] = (__bf16)v.x; ov[1] = (__bf16)v.y; ov[2] = (__bf16)v.z; ov[3] = (__bf16)v.w;
      ((bf16x4*)o)[i] = ov;
    }
  }
}

// ---------------- LN over 1024 (block per row) ----------------
__global__ __launch_bounds__(256) void ln1024_kernel(
    const float* __restrict__ in, const float* __restrict__ g, const float* __restrict__ bb,
    __bf16* __restrict__ out){
  int row = blockIdx.x;
  int tid = threadIdx.x, wid = tid >> 6, lane = tid & 63;
  float4 x = ((const float4*)(in + (size_t)row*DT))[tid];
  float s = x.x + x.y + x.z + x.w;
  float q = x.x*x.x + x.y*x.y + x.z*x.z + x.w*x.w;
  s = wred_sum(s); q = wred_sum(q);
  __shared__ float red[8];
  if (lane == 0){ red[wid] = s; red[4+wid] = q; }
  __syncthreads();
  s = red[0]+red[1]+red[2]+red[3];
  q = red[4]+red[5]+red[6]+red[7];
  float mean = s * (1.f/DT);
  float rstd = rsqrtf(q*(1.f/DT) - mean*mean + 1e-5f);
  float4 gv = ((const float4*)g)[tid], bv = ((const float4*)bb)[tid];
  bf16x4 o;
  o[0] = (__bf16)((x.x-mean)*rstd*gv.x + bv.x);
  o[1] = (__bf16)((x.y-mean)*rstd*gv.y + bv.y);
  o[2] = (__bf16)((x.z-mean)*rstd*gv.z + bv.z);
  o[3] = (__bf16)((x.w-mean)*rstd*gv.w + bv.w);
  ((bf16x4*)(out + (size_t)row*DT))[tid] = o;
}

// ---------------- RoPE + pre-LN + layer0 LN1 (wave per row) ----------------
__global__ __launch_bounds__(256) void rope_preln_kernel(
    float* __restrict__ z, const float* __restrict__ cosc, const float* __restrict__ sinc,
    const float* __restrict__ g, const float* __restrict__ bb,
    const float* __restrict__ g1, const float* __restrict__ b1, __bf16* __restrict__ xnb){
  int row = blockIdx.x*4 + (threadIdx.x >> 6);
  int lane = threadIdx.x & 63;
  int l = row % L_SEQ;
  float4 x = ((const float4*)(z + (size_t)row*DM))[lane];
  float4 p;
  p.x = __shfl_xor(x.x, 32); p.y = __shfl_xor(x.y, 32);
  p.z = __shfl_xor(x.z, 32); p.w = __shfl_xor(x.w, 32);
  float sgn = (lane < 32) ? -1.f : 1.f;
  float4 c = ((const float4*)(cosc + l*DM))[lane];
  float4 sn = ((const float4*)(sinc + l*DM))[lane];
  float4 xr;
  xr.x = x.x*c.x + sgn*p.x*sn.x;
  xr.y = x.y*c.y + sgn*p.y*sn.y;
  xr.z = x.z*c.z + sgn*p.z*sn.z;
  xr.w = x.w*c.w + sgn*p.w*sn.w;
  float s = wred_sum(xr.x + xr.y + xr.z + xr.w);
  float q = wred_sum(xr.x*xr.x + xr.y*xr.y + xr.z*xr.z + xr.w*xr.w);
  float mean = s * (1.f/DM);
  float rstd = rsqrtf(q*(1.f/DM) - mean*mean + 1e-5f);
  float4 gv = ((const float4*)g)[lane], bv = ((const float4*)bb)[lane];
  float4 y;
  y.x = (xr.x-mean)*rstd*gv.x + bv.x;
  y.y = (xr.y-mean)*rstd*gv.y + bv.y;
  y.z = (xr.z-mean)*rstd*gv.z + bv.z;
  y.w = (xr.w-mean)*rstd*gv.w + bv.w;
  ((float4*)(z + (size_t)row*DM))[lane] = y;
  float s2 = wred_sum(y.x + y.y + y.z + y.w);
  float q2 = wred_sum(y.x*y.x + y.y*y.y + y.z*y.z + y.w*y.w);
  float mean2 = s2 * (1.f/DM);
  float rstd2 = rsqrtf(q2*(1.f/DM) - mean2*mean2 + 1e-5f);
  float4 g1v = ((const float4*)g1)[lane], b1v = ((const float4*)b1)[lane];
  bf16x4 o;
  o[0] = (__bf16)((y.x-mean2)*rstd2*g1v.x + b1v.x);
  o[1] = (__bf16)((y.y-mean2)*rstd2*g1v.y + b1v.y);
  o[2] = (__bf16)((y.z-mean2)*rstd2*g1v.z + b1v.z);
  o[3] = (__bf16)((y.w-mean2)*rstd2*g1v.w + b1v.w);
  ((bf16x4*)(xnb + (size_t)row*DM))[lane] = o;
}

// ---------------- GEMM 256x256, 8 waves, BK=32, counted-vmcnt ----------------
template<int MODE, int K>
__global__ __launch_bounds__(512) void gemm512_kernel(
    const __bf16* __restrict__ A, const __bf16* __restrict__ W,
    const float* __restrict__ bias,
    float* __restrict__ Cf, __bf16* __restrict__ Cb,
    int N, int nt){
  __shared__ __align__(16) __bf16 As[2][256*32];
  __shared__ __align__(16) __bf16 Bs[2][256*32];
  int work = xcd_work();
  int bm = work / nt, bn = work % nt;
  int wid = threadIdx.x >> 6, lane = threadIdx.x & 63;
  int wr = wid >> 1, wc = wid & 1;
  int li = lane & 15, g4 = (lane >> 4) << 2;
  f32x4 acc[8][4] = {};
  const __bf16* ga = A + (size_t)bm*256*K;
  const __bf16* gb = W + (size_t)bn*256*K;
  const int NT = K/32;
  auto STAGE = [&](int b, int t){
    int k0 = t*32;
    if (wid < 4){
#pragma unroll
      for (int j = 0; j < 4; j++){ int r = (wid*4 + j)*16; stage16x32(ga, K, k0, &As[b][r<<5], lane, r); }
    } else {
#pragma unroll
      for (int j = 0; j < 4; j++){ int r = ((wid-4)*4 + j)*16; stage16x32(gb, K, k0, &Bs[b][r<<5], lane, r); }
    }
  };
  STAGE(0, 0);
  STAGE(1, 1);
  int cur = 0;
  for (int t = 0; t < NT; t++){
    if (t + 1 < NT) { VMWAIT(4); } else { VMWAIT(0); }
    __builtin_amdgcn_s_barrier();
    bf16x8 xf[4], wf[8];
#pragma unroll
    for (int mi = 0; mi < 4; mi++) xf[mi] = frag32(As[cur], wr*64 + mi*16 + li, lane);
#pragma unroll
    for (int ni = 0; ni < 8; ni++) wf[ni] = frag32(Bs[cur], wc*128 + ni*16 + li, lane);
    LGKM0();
    __builtin_amdgcn_sched_barrier(0);
    __builtin_amdgcn_s_barrier();
    if (t + 2 < NT) STAGE(cur, t+2);
    __builtin_amdgcn_s_setprio(1);
#pragma unroll
    for (int ni = 0; ni < 8; ni++)
#pragma unroll
      for (int mi = 0; mi < 4; mi++)
        acc[ni][mi] = __builtin_amdgcn_mfma_f32_16x16x32_bf16(wf[ni], xf[mi], acc[ni][mi], 0, 0, 0);
    __builtin_amdgcn_s_setprio(0);
    cur ^= 1;
  }
#pragma unroll
  for (int mi = 0; mi < 4; mi++){
    int m = bm*256 + wr*64 + mi*16 + li;
#pragma unroll
    for (int ni = 0; ni < 8; ni++){
      int n = bn*256 + wc*128 + ni*16 + g4;
      f32x4 bv = *(const f32x4*)(bias + n);
      f32x4 o = acc[ni][mi] + bv;
      if (MODE == 0){
        *(f32x4*)(Cf + (size_t)m*N + n) = o;
      } else {
        bf16x4 ob;
        ob[0] = (__bf16)o[0]; ob[1] = (__bf16)o[1]; ob[2] = (__bf16)o[2]; ob[3] = (__bf16)o[3];
        *(bf16x4*)(Cb + (size_t)m*N + n) = ob;
      }
    }
  }
}

// ---------------- fused w12 GEMM + SwiGLU, 256x128, 8 waves, counted-vmcnt -----------
__global__ __launch_bounds__(512) void gemm_glu_kernel(
    const __bf16* __restrict__ A, const __bf16* __restrict__ W12,
    const float* __restrict__ bias, __bf16* __restrict__ H){
  __shared__ __align__(16) __bf16 As[2][256*32];
  __shared__ __align__(16) __bf16 B1s[2][128*32];
  __shared__ __align__(16) __bf16 B2s[2][128*32];
  const int K = 256;
  int work = xcd_work();
  int bm = work >> 3, bn = work & 7;
  int wid = threadIdx.x >> 6, lane = threadIdx.x & 63;
  int wr = wid >> 1, wc = wid & 1;
  int li = lane & 15, g4 = (lane >> 4) << 2;
  f32x4 acc1[4][4] = {}, acc2[4][4] = {};
  const __bf16* ga  = A   + (size_t)bm*256*K;
  const __bf16* gb1 = W12 + (size_t)bn*128*K;
  const __bf16* gb2 = gb1 + (size_t)1024*K;
  auto STAGE = [&](int b, int t){
    int k0 = t*32;
    if (wid < 4){
#pragma unroll
      for (int j = 0; j < 4; j++){ int r = (wid*4 + j)*16; stage16x32(ga, K, k0, &As[b][r<<5], lane, r); }
    } else if (wid < 6){
#pragma unroll
      for (int j = 0; j < 4; j++){ int r = ((wid-4)*4 + j)*16; stage16x32(gb1, K, k0, &B1s[b][r<<5], lane, r); }
    } else {
#pragma unroll
      for (int j = 0; j < 4; j++){ int r = ((wid-6)*4 + j)*16; stage16x32(gb2, K, k0, &B2s[b][r<<5], lane, r); }
    }
  };
  STAGE(0, 0);
  STAGE(1, 1);
  int cur = 0;
  for (int t = 0; t < 8; t++){
    if (t + 1 < 8) { VMWAIT(4); } else { VMWAIT(0); }
    __builtin_amdgcn_s_barrier();
    bf16x8 xf[4], w1f[4], w2f[4];
#pragma unroll
    for (int mi = 0; mi < 4; mi++) xf[mi] = frag32(As[cur], wr*64 + mi*16 + li, lane);
#pragma unroll
    for (int ni = 0; ni < 4; ni++){
      w1f[ni] = frag32(B1s[cur], wc*64 + ni*16 + li, lane);
      w2f[ni] = frag32(B2s[cur], wc*64 + ni*16 + li, lane);
    }
    LGKM0();
    __builtin_amdgcn_sched_barrier(0);
    __builtin_amdgcn_s_barrier();
    if (t + 2 < 8) STAGE(cur, t+2);
    __builtin_amdgcn_s_setprio(1);
#pragma unroll
    for (int ni = 0; ni < 4; ni++)
#pragma unroll
      for (int mi = 0; mi < 4; mi++){
        acc1[ni][mi] = __builtin_amdgcn_mfma_f32_16x16x32_bf16(w1f[ni], xf[mi], acc1[ni][mi], 0, 0, 0);
        acc2[ni][mi] = __builtin_amdgcn_mfma_f32_16x16x32_bf16(w2f[ni], xf[mi], acc2[ni][mi], 0, 0, 0);
      }
    __builtin_amdgcn_s_setprio(0);
    cur ^= 1;
  }
#pragma unroll
  for (int mi = 0; mi < 4; mi++){
    int m = bm*256 + wr*64 + mi*16 + li;
#pragma unroll
    for (int ni = 0; ni < 4; ni++){
      int n = bn*128 + wc*64 + ni*16 + g4;
      f32x4 b1v = *(const f32x4*)(bias + n);
      f32x4 b2v = *(const f32x4*)(bias + 1024 + n);
      bf16x4 ob;
#pragma unroll
      for (int r = 0; r < 4; r++){
        float v1 = acc1[ni][mi][r] + b1v[r];
        float v2 = acc2[ni][mi][r] + b2v[r];
        float sig = 1.f/(1.f + __expf(-v1));
        ob[r] = (__bf16)(v1*sig*v2);
      }
      *(bf16x4*)(H + (size_t)m*FFND + n) = ob;
    }
  }
}

// ---------------- GEMM 256x256 + residual + LayerNorm (w3), 8 waves ----------------
template<int K>
__global__ __launch_bounds__(512) void gemm_ln_kernel(
    const __bf16* __restrict__ A, const __bf16* __restrict__ W,
    const float* __restrict__ bias, float* __restrict__ z,
    const float* __restrict__ lng, const float* __restrict__ lnb,
    __bf16* __restrict__ outb, float* __restrict__ outf){
  __shared__ __align__(16) __bf16 As[2][256*32];
  __shared__ __align__(16) __bf16 Bs[2][256*32];
  __shared__ float redS[256][2], redQ[256][2];
  int bm = xcd_work();
  int wid = threadIdx.x >> 6, lane = threadIdx.x & 63;
  int wr = wid >> 1, wc = wid & 1;
  int li = lane & 15, g4 = (lane >> 4) << 2;
  f32x4 acc[8][4] = {};
  const __bf16* ga = A + (size_t)bm*256*K;
  const int NT = K/32;
  auto STAGE = [&](int b, int t){
    int k0 = t*32;
    if (wid < 4){
#pragma unroll
      for (int j = 0; j < 4; j++){ int r = (wid*4 + j)*16; stage16x32(ga, K, k0, &As[b][r<<5], lane, r); }
    } else {
#pragma unroll
      for (int j = 0; j < 4; j++){ int r = ((wid-4)*4 + j)*16; stage16x32(W, K, k0, &Bs[b][r<<5], lane, r); }
    }
  };
  STAGE(0, 0);
  STAGE(1, 1);
  int cur = 0;
  for (int t = 0; t < NT; t++){
    if (t + 1 < NT) { VMWAIT(4); } else { VMWAIT(0); }
    __builtin_amdgcn_s_barrier();
    bf16x8 xf[4], wf[8];
#pragma unroll
    for (int mi = 0; mi < 4; mi++) xf[mi] = frag32(As[cur], wr*64 + mi*16 + li, lane);
#pragma unroll
    for (int ni = 0; ni < 8; ni++) wf[ni] = frag32(Bs[cur], wc*128 + ni*16 + li, lane);
    LGKM0();
    __builtin_amdgcn_sched_barrier(0);
    __builtin_amdgcn_s_barrier();
    if (t + 2 < NT) STAGE(cur, t+2);
    __builtin_amdgcn_s_setprio(1);
#pragma unroll
    for (int ni = 0; ni < 8; ni++)
#pragma unroll
      for (int mi = 0; mi < 4; mi++)
        acc[ni][mi] = __builtin_amdgcn_mfma_f32_16x16x32_bf16(wf[ni], xf[mi], acc[ni][mi], 0, 0, 0);
    __builtin_amdgcn_s_setprio(0);
    cur ^= 1;
  }
  float sA[4] = {}, qA[4] = {};
#pragma unroll
  for (int mi = 0; mi < 4; mi++){
    int m = bm*256 + wr*64 + mi*16 + li;
#pragma unroll
    for (int ni = 0; ni < 8; ni++){
      int n = wc*128 + ni*16 + g4;
      f32x4 zv = *(const f32x4*)(z + (size_t)m*DM + n);
      f32x4 bv = *(const f32x4*)(bias + n);
      f32x4 v = acc[ni][mi] + bv + zv;
      acc[ni][mi] = v;
      *(f32x4*)(z + (size_t)m*DM + n) = v;
#pragma unroll
      for (int r = 0; r < 4; r++){ sA[mi] += v[r]; qA[mi] += v[r]*v[r]; }
    }
  }
  __syncthreads();
#pragma unroll
  for (int mi = 0; mi < 4; mi++){
    float s = sA[mi], q = qA[mi];
    s += __shfl_xor(s, 16); q += __shfl_xor(q, 16);
    s += __shfl_xor(s, 32); q += __shfl_xor(q, 32);
    if (lane < 16){ redS[wr*64 + mi*16 + li][wc] = s; redQ[wr*64 + mi*16 + li][wc] = q; }
  }
  __syncthreads();
#pragma unroll
  for (int mi = 0; mi < 4; mi++){
    int ml = wr*64 + mi*16 + li;
    float s = redS[ml][0] + redS[ml][1];
    float q = redQ[ml][0] + redQ[ml][1];
    float mean = s * (1.f/DM);
    float rstd = rsqrtf(q*(1.f/DM) - mean*mean + 1e-5f);
    int m = bm*256 + ml;
#pragma unroll
    for (int ni = 0; ni < 8; ni++){
      int n = wc*128 + ni*16 + g4;
      f32x4 gv = *(const f32x4*)(lng + n);
      f32x4 bv = *(const f32x4*)(lnb + n);
      if (outb){
        bf16x4 o;
#pragma unroll
        for (int r = 0; r < 4; r++) o[r] = (__bf16)((acc[ni][mi][r] - mean)*rstd*gv[r] + bv[r]);
        *(bf16x4*)(outb + (size_t)m*DM + n) = o;
      } else {
        f32x4 o;
#pragma unroll
        for (int r = 0; r < 4; r++) o[r] = (acc[ni][mi][r] - mean)*rstd*gv[r] + bv[r];
        *(f32x4*)(outf + (size_t)m*DM + n) = o;
      }
    }
  }
}

// ---------------- FUSED attention + out-proj + residual + LN2 ----------------
// Block = 8 sequences = 192 token rows; 512 threads (8 waves). Wave w handles
// sequence w's 4 heads (wave-local softmax), writes O into a 96KB LDS tile in
// frag32 layout; then the K=256 out-proj GEMM reads A-frags from LDS (zero
// A-staging) with W double-buffered via counted-vmcnt glds. Epilogue:
// z += O Wout^T + bias; LN2 -> xnb.
#define O_OFF   0               // 8 chunks x [192][32] bf16 = 98304 B
#define U_OFF   98304           // union: attn scratch (QK 49152 + Ps 12288) | {W dbuf 32768, red 3072}
#define QK_OFF  (U_OFF)
#define PS_OFF  (U_OFF + 49152)
#define SM_SIZE 159744

__global__ __launch_bounds__(512) void attn_proj_ln_kernel(
    const __bf16* __restrict__ qkv, const __bf16* __restrict__ Wout,
    const float* __restrict__ bias, float* __restrict__ z,
    const float* __restrict__ lng, const float* __restrict__ lnb,
    __bf16* __restrict__ xnb){
  __shared__ __align__(16) char SM[SM_SIZE];
  __bf16* Otile = (__bf16*)(SM + O_OFF);                 // [8][192*32]
  int bm = blockIdx.x;
  int wid = threadIdx.x >> 6, lane = threadIdx.x & 63;
  // padded-triangular row offsets for P (rows padded to multiples of 4)
  const int ROFF[24] = {0,4,8,12,16,24,32,40,48,60,72,84,96,112,128,144,160,180,200,220,240,264,288,312};

  // ---- attention: wave `wid` owns sequence bm*8 + wid ----
  {
    const __bf16* base = qkv + (size_t)(bm*8 + wid)*L_SEQ*768;
    __bf16* Qs = (__bf16*)(SM + QK_OFF + wid*6144);      // [24][64]
    __bf16* Ks = Qs + 24*64;
    float*  Ps = (float*)(SM + PS_OFF + wid*1536);       // 384 floats padded-tri
    for (int j = 0; j < NHEAD; j++){
      float V[L_SEQ];
#pragma unroll
      for (int t = 0; t < L_SEQ; t++){
        int sw = lane ^ ((t & 7) << 3);
        Qs[t*64 + sw] = base[t*768 + j*64 + lane];
        Ks[t*64 + sw] = base[t*768 + 256 + j*64 + lane];
        V[t] = (float)base[t*768 + 512 + j*64 + lane];
      }
      __syncthreads();
      for (int p = lane; p < L_SEQ*L_SEQ; p += 64){
        int q = p / L_SEQ, k = p - q*L_SEQ;
        if (k <= q){
          int qx = (q & 7) << 3, kx = (k & 7) << 3;
          const __bf16* qr = Qs + q*64;
          const __bf16* kr = Ks + k*64;
          float s = 0.f;
#pragma unroll
          for (int d = 0; d < 64; d += 4){
            bf16x4 qa = *(const bf16x4*)(qr + (d ^ qx));
            bf16x4 ka = *(const bf16x4*)(kr + (d ^ kx));
            s += (float)qa[0]*(float)ka[0] + (float)qa[1]*(float)ka[1]
               + (float)qa[2]*(float)ka[2] + (float)qa[3]*(float)ka[3];
          }
          Ps[ROFF[q] + k] = s * 0.125f;
        }
      }
      __syncthreads();
#pragma unroll
      for (int q = 0; q < L_SEQ; q++){
        float v = (lane <= q) ? Ps[ROFF[q] + lane] : -1e30f;
        float mx = wred_max(v);
        float e = (lane <= q) ? __expf(v - mx) : 0.f;
        float sm = wred_sum(e);
        int plen = (q + 4) & ~3;
        if (lane <= q) Ps[ROFF[q] + lane] = e / sm;
        else if (lane < plen) Ps[ROFF[q] + lane] = 0.f;  // zero the padding
      }
      __syncthreads();
#pragma unroll
      for (int q = 0; q < L_SEQ; q++){
        float o = 0.f;
        int plen = (q + 4) & ~3;
        for (int k0 = 0; k0 < plen; k0 += 4){
          float4 pv = *(const float4*)&Ps[ROFF[q] + k0];
          o += pv.x*V[k0] + pv.y*V[k0+1] + pv.z*V[k0+2] + pv.w*V[k0+3];
        }
        int row = wid*24 + q;
        int col = j*64 + lane;
        int kc = col >> 5, c = col & 31;
        int p8 = (c >> 3) ^ ((row >> 1) & 3);
        Otile[kc*(192*32) + row*32 + p8*8 + (c & 7)] = (__bf16)o;
      }
      __syncthreads();
    }
  }
  __syncthreads();   // O tile complete; attn scratch dead -> W dbuf may reuse it

  // ---- out-proj GEMM: A = Otile (LDS), W staged dbuf, counted vmcnt ----
  __bf16* Wd = (__bf16*)(SM + U_OFF);                    // 2 x [256][32]
  int wr = wid >> 1, wc = wid & 1;                       // 4M x 2N
  int li = lane & 15, g4 = (lane >> 4) << 2;
  f32x4 acc[8][3] = {};
  auto STAGE = [&](int b, int t){                        // 2 glds per lane
    int k0 = t*32;
    stage16x32(Wout, 256, k0, Wd + b*8192 + ((wid*32) << 5),      lane, wid*32);
    stage16x32(Wout, 256, k0, Wd + b*8192 + ((wid*32 + 16) << 5), lane, wid*32 + 16);
  };
  STAGE(0, 0);
  STAGE(1, 1);
  int cur = 0;
  for (int t = 0; t < 8; t++){
    if (t + 1 < 8) { VMWAIT(2); } else { VMWAIT(0); }
    __builtin_amdgcn_s_barrier();
    bf16x8 xf[3], wf[8];
#pragma unroll
    for (int mi = 0; mi < 3; mi++) xf[mi] = frag32(Otile + t*(192*32), wr*48 + mi*16 + li, lane);
#pragma unroll
    for (int ni = 0; ni < 8; ni++) wf[ni] = frag32(Wd + cur*8192, wc*128 + ni*16 + li, lane);
    LGKM0();
    __builtin_amdgcn_sched_barrier(0);
    __builtin_amdgcn_s_barrier();
    if (t + 2 < 8) STAGE(cur, t+2);
    __builtin_amdgcn_s_setprio(1);
#pragma unroll
    for (int ni = 0; ni < 8; ni++)
#pragma unroll
      for (int mi = 0; mi < 3; mi++)
        acc[ni][mi] = __builtin_amdgcn_mfma_f32_16x16x32_bf16(wf[ni], xf[mi], acc[ni][mi], 0, 0, 0);
    __builtin_amdgcn_s_setprio(0);
    cur ^= 1;
  }
  // residual + LN2 over 192 rows
  float* redS = (float*)(SM + U_OFF + 32768);            // [192][2]
  float* redQ = redS + 384;
  float sA[3] = {}, qA[3] = {};
#pragma unroll
  for (int mi = 0; mi < 3; mi++){
    int m = bm*192 + wr*48 + mi*16 + li;
#pragma unroll
    for (int ni = 0; ni < 8; ni++){
      int n = wc*128 + ni*16 + g4;
      f32x4 zv = *(const f32x4*)(z + (size_t)m*DM + n);
      f32x4 bv = *(const f32x4*)(bias + n);
      f32x4 v = acc[ni][mi] + bv + zv;
      acc[ni][mi] = v;
      *(f32x4*)(z + (size_t)m*DM + n) = v;
#pragma unroll
      for (int r = 0; r < 4; r++){ sA[mi] += v[r]; qA[mi] += v[r]*v[r]; }
    }
  }
  __syncthreads();
#pragma unroll
  for (int mi = 0; mi < 3; mi++){
    float s = sA[mi], q = qA[mi];
    s += __shfl_xor(s, 16); q += __shfl_xor(q, 16);
    s += __shfl_xor(s, 32); q += __shfl_xor(q, 32);
    if (lane < 16){ int rl = wr*48 + mi*16 + li; redS[rl*2 + wc] = s; redQ[rl*2 + wc] = q; }
  }
  __syncthreads();
#pragma unroll
  for (int mi = 0; mi < 3; mi++){
    int rl = wr*48 + mi*16 + li;
    float s = redS[rl*2 + 0] + redS[rl*2 + 1];
    float q = redQ[rl*2 + 0] + redQ[rl*2 + 1];
    float mean = s * (1.f/DM);
    float rstd = rsqrtf(q*(1.f/DM) - mean*mean + 1e-5f);
    int m = bm*192 + rl;
#pragma unroll
    for (int ni = 0; ni < 8; ni++){
      int n = wc*128 + ni*16 + g4;
      f32x4 gv = *(const f32x4*)(lng + n);
      f32x4 bv = *(const f32x4*)(lnb + n);
      bf16x4 o;
#pragma unroll
      for (int r = 0; r < 4; r++) o[r] = (__bf16)((acc[ni][mi][r] - mean)*rstd*gv[r] + bv[r]);
      *(bf16x4*)(xnb + (size_t)m*DM + n) = o;
    }
  }
}

// ---------------- per-token heads ----------------
__global__ __launch_bounds__(256) void heads_kernel(
    const float* __restrict__ z,
    const float* __restrict__ cls_w, const float* __restrict__ cls_b,
    const float* __restrict__ eg_w1, const float* __restrict__ eg_b1,
    const float* __restrict__ eg_w2, const float* __restrict__ eg_b2,
    const float* __restrict__ halt_w, const float* __restrict__ halt_b,
    float* __restrict__ halt_out, float* __restrict__ cls_out){
  int m = blockIdx.x*4 + (threadIdx.x >> 6);
  int lane = threadIdx.x & 63;
  int l = m % L_SEQ;
  float4 zv = ((const float4*)(z + (size_t)m*DM))[lane];
  float4 w0 = ((const float4*)(cls_w + ((size_t)l*2 + 0)*DM))[lane];
  float4 w1 = ((const float4*)(cls_w + ((size_t)l*2 + 1)*DM))[lane];
  float c0 = wred_sum(zv.x*w0.x + zv.y*w0.y + zv.z*w0.z + zv.w*w0.w) + cls_b[l*2 + 0];
  float c1 = wred_sum(zv.x*w1.x + zv.y*w1.y + zv.z*w1.z + zv.w*w1.w) + cls_b[l*2 + 1];
  float mx = fmaxf(c0, c1);
  float e0 = __expf(c0 - mx), e1 = __expf(c1 - mx);
  float inv = 1.f/(e0 + e1);
  float p0 = fminf(fmaxf(e0*inv, 1e-10f), 1.f);
  float p1 = fminf(fmaxf(e1*inv, 1e-10f), 1.f);
  float ent = -(p0*__logf(p0) + p1*__logf(p1));
  float entn = fminf(fmaxf(ent * 1.44269504f, 0.f), 1.f);
  const float4* wg = (const float4*)(eg_w1 + ((size_t)l*DM + 4*lane)*8);
  float hacc[8] = {};
#pragma unroll
  for (int dd = 0; dd < 4; dd++){
    float zd = (dd==0) ? zv.x : (dd==1) ? zv.y : (dd==2) ? zv.z : zv.w;
    float4 a = wg[dd*2], b = wg[dd*2 + 1];
    hacc[0] += zd*a.x; hacc[1] += zd*a.y; hacc[2] += zd*a.z; hacc[3] += zd*a.w;
    hacc[4] += zd*b.x; hacc[5] += zd*b.y; hacc[6] += zd*b.z; hacc[7] += zd*b.w;
  }
  float gin = 0.f;
#pragma unroll
  for (int j = 0; j < 8; j++){
    float hj = wred_sum(hacc[j]);
    hj = tanhf(hj + eg_b1[l*8 + j]);
    gin += hj * eg_w2[l*8 + j];
  }
  gin += eg_b2[l];
  float gate = 1.f/(1.f + __expf(-gin));
  float gated = entn * gate;
  const float* hw = halt_w + (size_t)l*257;
  float hp = zv.x*hw[4*lane] + zv.y*hw[4*lane+1] + zv.z*hw[4*lane+2] + zv.w*hw[4*lane+3];
  float hl = wred_sum(hp) + gated*hw[256] + halt_b[l];
  if (lane == 0) halt_out[m] = hl;
  if (lane < 2) cls_out[(size_t)m*2 + lane] = lane ? c1 : c0;
}

extern "C" void kernel_launch(void* const* d_in, const int* in_sizes, int n_in,
                              void* d_out, int out_size, void* d_ws, size_t ws_size,
                              hipStream_t stream){
  const float* teacher = (const float*)d_in[0];
  const float* in_ln_g = (const float*)d_in[1];
  const float* in_ln_b = (const float*)d_in[2];
  const float* proj_w  = (const float*)d_in[3];
  const float* proj_b  = (const float*)d_in[4];
  const float* cosc    = (const float*)d_in[5];
  const float* sinc    = (const float*)d_in[6];
  const float* pre_g   = (const float*)d_in[7];
  const float* pre_b   = (const float*)d_in[8];
  const float* l_ln1_g = (const float*)d_in[9];
  const float* l_ln1_b = (const float*)d_in[10];
  const float* l_inw   = (const float*)d_in[11];
  const float* l_inb   = (const float*)d_in[12];
  const float* l_outw  = (const float*)d_in[13];
  const float* l_outb  = (const float*)d_in[14];
  const float* l_ln2_g = (const float*)d_in[15];
  const float* l_ln2_b = (const float*)d_in[16];
  const float* l_w12   = (const float*)d_in[17];
  const float* l_b12   = (const float*)d_in[18];
  const float* l_w3    = (const float*)d_in[19];
  const float* l_b3    = (const float*)d_in[20];
  const float* post_g  = (const float*)d_in[21];
  const float* post_b  = (const float*)d_in[22];
  const float* eg_w1   = (const float*)d_in[23];
  const float* eg_b1   = (const float*)d_in[24];
  const float* eg_w2   = (const float*)d_in[25];
  const float* eg_b2   = (const float*)d_in[26];
  const float* halt_w  = (const float*)d_in[27];
  const float* halt_b  = (const float*)d_in[28];
  const float* cls_w   = (const float*)d_in[29];
  const float* cls_b   = (const float*)d_in[30];

  float* out = (float*)d_out;
  float* halt_out = out;
  float* cls_out  = out + NTOK;
  float* z_out    = out + NTOK + (size_t)NTOK*NCLS;

  char* ws = (char*)d_ws;
  size_t off = 0;
  auto alloc = [&](size_t bytes){ void* p = ws + off; off += (bytes + 255) & ~(size_t)255; return p; };
  float*  zbuf = (float*) alloc((size_t)NTOK*DM*4);
  __bf16* xnb  = (__bf16*)alloc((size_t)NTOK*DM*2);
  __bf16* qkvb = (__bf16*)alloc((size_t)NTOK*768*2);
  __bf16* bigb = (__bf16*)alloc((size_t)NTOK*1024*2);
  __bf16* w_proj = (__bf16*)alloc((size_t)262144*2);
  __bf16* w_in   = (__bf16*)alloc((size_t)2359296*2);
  __bf16* w_out  = (__bf16*)alloc((size_t)786432*2);
  __bf16* w_12   = (__bf16*)alloc((size_t)6291456*2);
  __bf16* w_3    = (__bf16*)alloc((size_t)3145728*2);

  cvt_all_kernel<<<2048, 256, 0, stream>>>(proj_w, w_proj, 262144/4,
                                           l_inw, w_in, 2359296/4,
                                           l_outw, w_out, 786432/4,
                                           l_w12, w_12, 6291456/4,
                                           l_w3, w_3, 3145728/4);

  ln1024_kernel<<<NTOK, 256, 0, stream>>>(teacher, in_ln_g, in_ln_b, bigb);
  gemm512_kernel<0, 1024><<<192, 512, 0, stream>>>(bigb, w_proj, proj_b, zbuf, nullptr, 256, 1);
  rope_preln_kernel<<<NTOK/4, 256, 0, stream>>>(zbuf, cosc, sinc, pre_g, pre_b, l_ln1_g, l_ln1_b, xnb);

  for (int i = 0; i < NLAYER; i++){
    gemm512_kernel<1, 256><<<576, 512, 0, stream>>>(xnb, w_in + (size_t)i*768*256, l_inb + i*768, nullptr, qkvb, 768, 3);
    attn_proj_ln_kernel<<<NBATCH/8, 512, 0, stream>>>(qkvb, w_out + (size_t)i*256*256, l_outb + i*256,
                                                      zbuf, l_ln2_g + i*256, l_ln2_b + i*256, xnb);
    gemm_glu_kernel<<<1536, 512, 0, stream>>>(xnb, w_12 + (size_t)i*2048*256, l_b12 + i*2048, bigb);
    bool last = (i == NLAYER-1);
    gemm_ln_kernel<1024><<<192, 512, 0, stream>>>(bigb, w_3 + (size_t)i*256*1024, l_b3 + i*256,
                                                  zbuf,
                                                  last ? post_g : l_ln1_g + (i+1)*256,
                                                  last ? post_b : l_ln1_b + (i+1)*256,
                                                  last ? nullptr : xnb,
                                                  last ? z_out : nullptr);
  }

  heads_kernel<<<NTOK/4, 256, 0, stream>>>(z_out, cls_w, cls_b, eg_w1, eg_b1, eg_w2, eg_b2,
                                           halt_w, halt_b, halt_out, cls_out);
}

// Round 9
// 4143.126 us; speedup vs baseline: 1.1472x; 1.1472x over previous
//
#include <hip/hip_runtime.h>
#include <hip/hip_bf16.h>
#include <math.h>

#define L_SEQ 24
#define DT 1024
#define DM 256
#define NLAYER 12
#define NHEAD 4
#define HDIM 64
#define FFND 1024
#define NCLS 2
#define NBATCH 2048
#define NTOK (NBATCH*L_SEQ)   // 49152

typedef float f32x4 __attribute__((ext_vector_type(4)));
typedef __bf16 bf16x4 __attribute__((ext_vector_type(4)));
typedef __bf16 bf16x8 __attribute__((ext_vector_type(8)));

#define GLDS16(gp, lp) __builtin_amdgcn_global_load_lds((const __attribute__((address_space(1))) void*)(gp), (__attribute__((address_space(3))) void*)(lp), 16, 0, 0)
#define VMWAIT(N) asm volatile("s_waitcnt vmcnt(" #N ")" ::: "memory")
#define LGKM0()   asm volatile("s_waitcnt lgkmcnt(0)" ::: "memory")

__device__ inline float wred_sum(float v){
#pragma unroll
  for (int o = 32; o > 0; o >>= 1) v += __shfl_xor(v, o);
  return v;
}
__device__ inline float wred_max(float v){
#pragma unroll
  for (int o = 32; o > 0; o >>= 1) v = fmaxf(v, __shfl_xor(v, o));
  return v;
}

// ---- [R][32]-bf16 LDS tiles, BK=32: linear glds dest + global-source XOR swizzle ----
__device__ __forceinline__ void stage16x32(const __bf16* __restrict__ g, int ldk, int k0,
                                           __bf16* ldsbase, int lane, int rowbase){
  int r = rowbase + (lane >> 2);
  int cs = (lane & 3) ^ ((lane >> 3) & 3);
  GLDS16(g + (size_t)r*ldk + k0 + cs*8, ldsbase);
}
__device__ __forceinline__ bf16x8 frag32(const __bf16* tile, int row, int lane){
  int p = (lane >> 4) ^ ((row >> 1) & 3);
  return *(const bf16x8*)(tile + (row << 5) + (p << 3));
}

// XCD-aware swizzle (T1). Requires gridDim.x % 8 == 0.
__device__ __forceinline__ int xcd_work(){
  int nwg = gridDim.x, bid = blockIdx.x;
  return (bid & 7) * (nwg >> 3) + (bid >> 3);
}

// ---------------- merged weight fp32 -> bf16 convert ----------------
__global__ void cvt_all_kernel(const float* __restrict__ a0, __bf16* __restrict__ o0, int n0,
                               const float* __restrict__ a1, __bf16* __restrict__ o1, int n1,
                               const float* __restrict__ a2, __bf16* __restrict__ o2, int n2,
                               const float* __restrict__ a3, __bf16* __restrict__ o3, int n3,
                               const float* __restrict__ a4, __bf16* __restrict__ o4, int n4){
  int stride = gridDim.x * blockDim.x;
  int i0 = blockIdx.x * blockDim.x + threadIdx.x;
  const float* as[5] = {a0,a1,a2,a3,a4};
  __bf16* os[5] = {o0,o1,o2,o3,o4};
  int ns[5] = {n0,n1,n2,n3,n4};
#pragma unroll
  for (int s = 0; s < 5; s++){
    const float* a = as[s]; __bf16* o = os[s]; int n = ns[s];
    for (int i = i0; i < n; i += stride){
      float4 v = ((const float4*)a)[i];
      bf16x4 ov;
      ov[0] = (__bf16)v.x; ov[1] = (__bf16)v.y; ov[2] = (__bf16)v.z; ov[3] = (__bf16)v.w;
      ((bf16x4*)o)[i] = ov;
    }
  }
}

// ---------------- LN over 1024 (block per row) ----------------
__global__ __launch_bounds__(256) void ln1024_kernel(
    const float* __restrict__ in, const float* __restrict__ g, const float* __restrict__ bb,
    __bf16* __restrict__ out){
  int row = blockIdx.x;
  int tid = threadIdx.x, wid = tid >> 6, lane = tid & 63;
  float4 x = ((const float4*)(in + (size_t)row*DT))[tid];
  float s = x.x + x.y + x.z + x.w;
  float q = x.x*x.x + x.y*x.y + x.z*x.z + x.w*x.w;
  s = wred_sum(s); q = wred_sum(q);
  __shared__ float red[8];
  if (lane == 0){ red[wid] = s; red[4+wid] = q; }
  __syncthreads();
  s = red[0]+red[1]+red[2]+red[3];
  q = red[4]+red[5]+red[6]+red[7];
  float mean = s * (1.f/DT);
  float rstd = rsqrtf(q*(1.f/DT) - mean*mean + 1e-5f);
  float4 gv = ((const float4*)g)[tid], bv = ((const float4*)bb)[tid];
  bf16x4 o;
  o[0] = (__bf16)((x.x-mean)*rstd*gv.x + bv.x);
  o[1] = (__bf16)((x.y-mean)*rstd*gv.y + bv.y);
  o[2] = (__bf16)((x.z-mean)*rstd*gv.z + bv.z);
  o[3] = (__bf16)((x.w-mean)*rstd*gv.w + bv.w);
  ((bf16x4*)(out + (size_t)row*DT))[tid] = o;
}

// ---------------- RoPE + pre-LN + layer0 LN1 (wave per row) ----------------
__global__ __launch_bounds__(256) void rope_preln_kernel(
    float* __restrict__ z, const float* __restrict__ cosc, const float* __restrict__ sinc,
    const float* __restrict__ g, const float* __restrict__ bb,
    const float* __restrict__ g1, const float* __restrict__ b1, __bf16* __restrict__ xnb){
  int row = blockIdx.x*4 + (threadIdx.x >> 6);
  int lane = threadIdx.x & 63;
  int l = row % L_SEQ;
  float4 x = ((const float4*)(z + (size_t)row*DM))[lane];
  float4 p;
  p.x = __shfl_xor(x.x, 32); p.y = __shfl_xor(x.y, 32);
  p.z = __shfl_xor(x.z, 32); p.w = __shfl_xor(x.w, 32);
  float sgn = (lane < 32) ? -1.f : 1.f;
  float4 c = ((const float4*)(cosc + l*DM))[lane];
  float4 sn = ((const float4*)(sinc + l*DM))[lane];
  float4 xr;
  xr.x = x.x*c.x + sgn*p.x*sn.x;
  xr.y = x.y*c.y + sgn*p.y*sn.y;
  xr.z = x.z*c.z + sgn*p.z*sn.z;
  xr.w = x.w*c.w + sgn*p.w*sn.w;
  float s = wred_sum(xr.x + xr.y + xr.z + xr.w);
  float q = wred_sum(xr.x*xr.x + xr.y*xr.y + xr.z*xr.z + xr.w*xr.w);
  float mean = s * (1.f/DM);
  float rstd = rsqrtf(q*(1.f/DM) - mean*mean + 1e-5f);
  float4 gv = ((const float4*)g)[lane], bv = ((const float4*)bb)[lane];
  float4 y;
  y.x = (xr.x-mean)*rstd*gv.x + bv.x;
  y.y = (xr.y-mean)*rstd*gv.y + bv.y;
  y.z = (xr.z-mean)*rstd*gv.z + bv.z;
  y.w = (xr.w-mean)*rstd*gv.w + bv.w;
  ((float4*)(z + (size_t)row*DM))[lane] = y;
  float s2 = wred_sum(y.x + y.y + y.z + y.w);
  float q2 = wred_sum(y.x*y.x + y.y*y.y + y.z*y.z + y.w*y.w);
  float mean2 = s2 * (1.f/DM);
  float rstd2 = rsqrtf(q2*(1.f/DM) - mean2*mean2 + 1e-5f);
  float4 g1v = ((const float4*)g1)[lane], b1v = ((const float4*)b1)[lane];
  bf16x4 o;
  o[0] = (__bf16)((y.x-mean2)*rstd2*g1v.x + b1v.x);
  o[1] = (__bf16)((y.y-mean2)*rstd2*g1v.y + b1v.y);
  o[2] = (__bf16)((y.z-mean2)*rstd2*g1v.z + b1v.z);
  o[3] = (__bf16)((y.w-mean2)*rstd2*g1v.w + b1v.w);
  ((bf16x4*)(xnb + (size_t)row*DM))[lane] = o;
}

// ---------------- GEMM 256x256, 8 waves, BK=32, counted-vmcnt ----------------
template<int MODE, int K>
__global__ __launch_bounds__(512) void gemm512_kernel(
    const __bf16* __restrict__ A, const __bf16* __restrict__ W,
    const float* __restrict__ bias,
    float* __restrict__ Cf, __bf16* __restrict__ Cb,
    int N, int nt){
  __shared__ __align__(16) __bf16 As[2][256*32];
  __shared__ __align__(16) __bf16 Bs[2][256*32];
  int work = xcd_work();
  int bm = work / nt, bn = work % nt;
  int wid = threadIdx.x >> 6, lane = threadIdx.x & 63;
  int wr = wid >> 1, wc = wid & 1;
  int li = lane & 15, g4 = (lane >> 4) << 2;
  f32x4 acc[8][4] = {};
  const __bf16* ga = A + (size_t)bm*256*K;
  const __bf16* gb = W + (size_t)bn*256*K;
  const int NT = K/32;
  auto STAGE = [&](int b, int t){
    int k0 = t*32;
    if (wid < 4){
#pragma unroll
      for (int j = 0; j < 4; j++){ int r = (wid*4 + j)*16; stage16x32(ga, K, k0, &As[b][r<<5], lane, r); }
    } else {
#pragma unroll
      for (int j = 0; j < 4; j++){ int r = ((wid-4)*4 + j)*16; stage16x32(gb, K, k0, &Bs[b][r<<5], lane, r); }
    }
  };
  STAGE(0, 0);
  STAGE(1, 1);
  int cur = 0;
  for (int t = 0; t < NT; t++){
    if (t + 1 < NT) { VMWAIT(4); } else { VMWAIT(0); }
    __builtin_amdgcn_s_barrier();
    bf16x8 xf[4], wf[8];
#pragma unroll
    for (int mi = 0; mi < 4; mi++) xf[mi] = frag32(As[cur], wr*64 + mi*16 + li, lane);
#pragma unroll
    for (int ni = 0; ni < 8; ni++) wf[ni] = frag32(Bs[cur], wc*128 + ni*16 + li, lane);
    LGKM0();
    __builtin_amdgcn_sched_barrier(0);
    __builtin_amdgcn_s_barrier();
    if (t + 2 < NT) STAGE(cur, t+2);
    __builtin_amdgcn_s_setprio(1);
#pragma unroll
    for (int ni = 0; ni < 8; ni++)
#pragma unroll
      for (int mi = 0; mi < 4; mi++)
        acc[ni][mi] = __builtin_amdgcn_mfma_f32_16x16x32_bf16(wf[ni], xf[mi], acc[ni][mi], 0, 0, 0);
    __builtin_amdgcn_s_setprio(0);
    cur ^= 1;
  }
#pragma unroll
  for (int mi = 0; mi < 4; mi++){
    int m = bm*256 + wr*64 + mi*16 + li;
#pragma unroll
    for (int ni = 0; ni < 8; ni++){
      int n = bn*256 + wc*128 + ni*16 + g4;
      f32x4 bv = *(const f32x4*)(bias + n);
      f32x4 o = acc[ni][mi] + bv;
      if (MODE == 0){
        *(f32x4*)(Cf + (size_t)m*N + n) = o;
      } else {
        bf16x4 ob;
        ob[0] = (__bf16)o[0]; ob[1] = (__bf16)o[1]; ob[2] = (__bf16)o[2]; ob[3] = (__bf16)o[3];
        *(bf16x4*)(Cb + (size_t)m*N + n) = ob;
      }
    }
  }
}

// ---------------- persistent-A fused w12 GEMM + SwiGLU ----------------
// Block owns 192 rows; A tile (192x256) staged ONCE into resident LDS (96KB);
// loops over all 8 bn tiles (128 dual cols), double-buffering only W chunks
// (counted vmcnt). Grid = 256 = 1 block/CU. Traffic: A 25MB (was 201MB).
__global__ __launch_bounds__(512) void gemm_glu_kernel(
    const __bf16* __restrict__ A, const __bf16* __restrict__ W12,
    const float* __restrict__ bias, __bf16* __restrict__ H){
  __shared__ __align__(16) __bf16 As[8][192*32];   // 96 KB resident A
  __shared__ __align__(16) __bf16 B1s[2][128*32];  // 16 KB
  __shared__ __align__(16) __bf16 B2s[2][128*32];  // 16 KB
  const int K = 256;
  int bm = xcd_work();
  int wid = threadIdx.x >> 6, lane = threadIdx.x & 63;
  int wr = wid >> 1, wc = wid & 1;                 // 4M x 2N
  int li = lane & 15, g4 = (lane >> 4) << 2;
  const __bf16* ga = A + (size_t)bm*192*K;
  // stage A fully: 96 units of 16 rows, 12 per wave (uniform vmcnt)
#pragma unroll
  for (int j = 0; j < 12; j++){
    int g = j*8 + wid;
    int chunk = g / 12, u = g % 12;
    stage16x32(ga, K, chunk*32, &As[chunk][(u*16) << 5], lane, u*16);
  }
  auto STAGEB = [&](int buf, int g){               // 2 glds per lane
    int bn = g >> 3, k0 = (g & 7)*32;
    const __bf16* gb1 = W12 + (size_t)bn*128*K;
    stage16x32(gb1,              K, k0, &B1s[buf][(wid*16) << 5], lane, wid*16);
    stage16x32(gb1 + (size_t)1024*K, K, k0, &B2s[buf][(wid*16) << 5], lane, wid*16);
  };
  STAGEB(0, 0);
  STAGEB(1, 1);
  f32x4 acc1[4][3] = {}, acc2[4][3] = {};
  int cur = 0;
  for (int g = 0; g < 64; g++){
    int k = g & 7, bn = g >> 3;
    // vmcnt: steady = 2 (next chunk in flight); bn-boundary adds 12 epilogue
    // stores still outstanding; tail drains.
    if (g == 0)            { VMWAIT(2);  }   // A(12)+B0 done, B1 chunk outstanding
    else if (g == 63)      { VMWAIT(0);  }
    else if (k == 0)       { VMWAIT(14); }   // 2 loads + 12 stores outstanding
    else                   { VMWAIT(2);  }
    __builtin_amdgcn_s_barrier();
    bf16x8 xf[3], w1f[4], w2f[4];
#pragma unroll
    for (int mi = 0; mi < 3; mi++) xf[mi] = frag32(As[k], wr*48 + mi*16 + li, lane);
#pragma unroll
    for (int ni = 0; ni < 4; ni++){
      w1f[ni] = frag32(B1s[cur], wc*64 + ni*16 + li, lane);
      w2f[ni] = frag32(B2s[cur], wc*64 + ni*16 + li, lane);
    }
    LGKM0();
    __builtin_amdgcn_sched_barrier(0);
    __builtin_amdgcn_s_barrier();
    if (g + 2 < 64) STAGEB(cur, g + 2);
    __builtin_amdgcn_s_setprio(1);
#pragma unroll
    for (int ni = 0; ni < 4; ni++)
#pragma unroll
      for (int mi = 0; mi < 3; mi++){
        acc1[ni][mi] = __builtin_amdgcn_mfma_f32_16x16x32_bf16(w1f[ni], xf[mi], acc1[ni][mi], 0, 0, 0);
        acc2[ni][mi] = __builtin_amdgcn_mfma_f32_16x16x32_bf16(w2f[ni], xf[mi], acc2[ni][mi], 0, 0, 0);
      }
    __builtin_amdgcn_s_setprio(0);
    cur ^= 1;
    if (k == 7){
      // epilogue for this bn tile: SwiGLU + store, then reset acc
#pragma unroll
      for (int mi = 0; mi < 3; mi++){
        int m = bm*192 + wr*48 + mi*16 + li;
#pragma unroll
        for (int ni = 0; ni < 4; ni++){
          int n = bn*128 + wc*64 + ni*16 + g4;
          f32x4 b1v = *(const f32x4*)(bias + n);
          f32x4 b2v = *(const f32x4*)(bias + 1024 + n);
          bf16x4 ob;
#pragma unroll
          for (int r = 0; r < 4; r++){
            float v1 = acc1[ni][mi][r] + b1v[r];
            float v2 = acc2[ni][mi][r] + b2v[r];
            float sig = 1.f/(1.f + __expf(-v1));
            ob[r] = (__bf16)(v1*sig*v2);
          }
          *(bf16x4*)(H + (size_t)m*FFND + n) = ob;
          acc1[ni][mi] = (f32x4)(0.f);
          acc2[ni][mi] = (f32x4)(0.f);
        }
      }
    }
  }
}

// ---------------- GEMM 256x256 + residual + LayerNorm, 8 waves ----------------
template<int K>
__global__ __launch_bounds__(512) void gemm_ln_kernel(
    const __bf16* __restrict__ A, const __bf16* __restrict__ W,
    const float* __restrict__ bias, float* __restrict__ z,
    const float* __restrict__ lng, const float* __restrict__ lnb,
    __bf16* __restrict__ outb, float* __restrict__ outf){
  __shared__ __align__(16) __bf16 As[2][256*32];
  __shared__ __align__(16) __bf16 Bs[2][256*32];
  __shared__ float redS[256][2], redQ[256][2];
  int bm = xcd_work();
  int wid = threadIdx.x >> 6, lane = threadIdx.x & 63;
  int wr = wid >> 1, wc = wid & 1;
  int li = lane & 15, g4 = (lane >> 4) << 2;
  f32x4 acc[8][4] = {};
  const __bf16* ga = A + (size_t)bm*256*K;
  const int NT = K/32;
  auto STAGE = [&](int b, int t){
    int k0 = t*32;
    if (wid < 4){
#pragma unroll
      for (int j = 0; j < 4; j++){ int r = (wid*4 + j)*16; stage16x32(ga, K, k0, &As[b][r<<5], lane, r); }
    } else {
#pragma unroll
      for (int j = 0; j < 4; j++){ int r = ((wid-4)*4 + j)*16; stage16x32(W, K, k0, &Bs[b][r<<5], lane, r); }
    }
  };
  STAGE(0, 0);
  STAGE(1, 1);
  int cur = 0;
  for (int t = 0; t < NT; t++){
    if (t + 1 < NT) { VMWAIT(4); } else { VMWAIT(0); }
    __builtin_amdgcn_s_barrier();
    bf16x8 xf[4], wf[8];
#pragma unroll
    for (int mi = 0; mi < 4; mi++) xf[mi] = frag32(As[cur], wr*64 + mi*16 + li, lane);
#pragma unroll
    for (int ni = 0; ni < 8; ni++) wf[ni] = frag32(Bs[cur], wc*128 + ni*16 + li, lane);
    LGKM0();
    __builtin_amdgcn_sched_barrier(0);
    __builtin_amdgcn_s_barrier();
    if (t + 2 < NT) STAGE(cur, t+2);
    __builtin_amdgcn_s_setprio(1);
#pragma unroll
    for (int ni = 0; ni < 8; ni++)
#pragma unroll
      for (int mi = 0; mi < 4; mi++)
        acc[ni][mi] = __builtin_amdgcn_mfma_f32_16x16x32_bf16(wf[ni], xf[mi], acc[ni][mi], 0, 0, 0);
    __builtin_amdgcn_s_setprio(0);
    cur ^= 1;
  }
  float sA[4] = {}, qA[4] = {};
#pragma unroll
  for (int mi = 0; mi < 4; mi++){
    int m = bm*256 + wr*64 + mi*16 + li;
#pragma unroll
    for (int ni = 0; ni < 8; ni++){
      int n = wc*128 + ni*16 + g4;
      f32x4 zv = *(const f32x4*)(z + (size_t)m*DM + n);
      f32x4 bv = *(const f32x4*)(bias + n);
      f32x4 v = acc[ni][mi] + bv + zv;
      acc[ni][mi] = v;
      *(f32x4*)(z + (size_t)m*DM + n) = v;
#pragma unroll
      for (int r = 0; r < 4; r++){ sA[mi] += v[r]; qA[mi] += v[r]*v[r]; }
    }
  }
  __syncthreads();
#pragma unroll
  for (int mi = 0; mi < 4; mi++){
    float s = sA[mi], q = qA[mi];
    s += __shfl_xor(s, 16); q += __shfl_xor(q, 16);
    s += __shfl_xor(s, 32); q += __shfl_xor(q, 32);
    if (lane < 16){ redS[wr*64 + mi*16 + li][wc] = s; redQ[wr*64 + mi*16 + li][wc] = q; }
  }
  __syncthreads();
#pragma unroll
  for (int mi = 0; mi < 4; mi++){
    int ml = wr*64 + mi*16 + li;
    float s = redS[ml][0] + redS[ml][1];
    float q = redQ[ml][0] + redQ[ml][1];
    float mean = s * (1.f/DM);
    float rstd = rsqrtf(q*(1.f/DM) - mean*mean + 1e-5f);
    int m = bm*256 + ml;
#pragma unroll
    for (int ni = 0; ni < 8; ni++){
      int n = wc*128 + ni*16 + g4;
      f32x4 gv = *(const f32x4*)(lng + n);
      f32x4 bv = *(const f32x4*)(lnb + n);
      if (outb){
        bf16x4 o;
#pragma unroll
        for (int r = 0; r < 4; r++) o[r] = (__bf16)((acc[ni][mi][r] - mean)*rstd*gv[r] + bv[r]);
        *(bf16x4*)(outb + (size_t)m*DM + n) = o;
      } else {
        f32x4 o;
#pragma unroll
        for (int r = 0; r < 4; r++) o[r] = (acc[ni][mi][r] - mean)*rstd*gv[r] + bv[r];
        *(f32x4*)(outf + (size_t)m*DM + n) = o;
      }
    }
  }
}

// ---------------- attention: block per sequence, wave per head ----------------
__global__ __launch_bounds__(256) void attn_kernel(const __bf16* __restrict__ qkv, __bf16* __restrict__ ob){
  int b = blockIdx.x;
  int h = threadIdx.x >> 6, lane = threadIdx.x & 63;
  __shared__ __align__(16) __bf16 Qs[NHEAD][L_SEQ][HDIM];
  __shared__ __align__(16) __bf16 Ks[NHEAD][L_SEQ][HDIM];
  __shared__ float Ps[NHEAD][L_SEQ][L_SEQ];
  const __bf16* base = qkv + (size_t)b*L_SEQ*768;
  float V[L_SEQ];
#pragma unroll
  for (int t = 0; t < L_SEQ; t++){
    int sw = lane ^ ((t & 7) << 3);
    Qs[h][t][sw] = base[t*768 + h*64 + lane];
    Ks[h][t][sw] = base[t*768 + 256 + h*64 + lane];
    V[t] = (float)base[t*768 + 512 + h*64 + lane];
  }
  __syncthreads();
  for (int p = lane; p < L_SEQ*L_SEQ; p += 64){
    int q = p / L_SEQ, k = p - q*L_SEQ;
    if (k <= q){
      int qx = (q & 7) << 3, kx = (k & 7) << 3;
      const __bf16* qr = Qs[h][q];
      const __bf16* kr = Ks[h][k];
      float s = 0.f;
#pragma unroll
      for (int d = 0; d < 64; d += 4){
        bf16x4 qa = *(const bf16x4*)(qr + (d ^ qx));
        bf16x4 ka = *(const bf16x4*)(kr + (d ^ kx));
        s += (float)qa[0]*(float)ka[0] + (float)qa[1]*(float)ka[1]
           + (float)qa[2]*(float)ka[2] + (float)qa[3]*(float)ka[3];
      }
      Ps[h][q][k] = s * 0.125f;
    }
  }
  __syncthreads();
  for (int q = 0; q < L_SEQ; q++){
    float v = (lane <= q) ? Ps[h][q][lane] : -1e30f;
    float mx = wred_max(v);
    float e = (lane <= q) ? __expf(v - mx) : 0.f;
    float sm = wred_sum(e);
    if (lane < L_SEQ) Ps[h][q][lane] = e / sm;
  }
  __syncthreads();
  for (int q = 0; q < L_SEQ; q++){
    float o = 0.f;
    for (int k = 0; k <= q; k++) o += Ps[h][q][k] * V[k];
    ob[((size_t)b*L_SEQ + q)*DM + h*64 + lane] = (__bf16)o;
  }
}

// ---------------- per-token heads ----------------
__global__ __launch_bounds__(256) void heads_kernel(
    const float* __restrict__ z,
    const float* __restrict__ cls_w, const float* __restrict__ cls_b,
    const float* __restrict__ eg_w1, const float* __restrict__ eg_b1,
    const float* __restrict__ eg_w2, const float* __restrict__ eg_b2,
    const float* __restrict__ halt_w, const float* __restrict__ halt_b,
    float* __restrict__ halt_out, float* __restrict__ cls_out){
  int m = blockIdx.x*4 + (threadIdx.x >> 6);
  int lane = threadIdx.x & 63;
  int l = m % L_SEQ;
  float4 zv = ((const float4*)(z + (size_t)m*DM))[lane];
  float4 w0 = ((const float4*)(cls_w + ((size_t)l*2 + 0)*DM))[lane];
  float4 w1 = ((const float4*)(cls_w + ((size_t)l*2 + 1)*DM))[lane];
  float c0 = wred_sum(zv.x*w0.x + zv.y*w0.y + zv.z*w0.z + zv.w*w0.w) + cls_b[l*2 + 0];
  float c1 = wred_sum(zv.x*w1.x + zv.y*w1.y + zv.z*w1.z + zv.w*w1.w) + cls_b[l*2 + 1];
  float mx = fmaxf(c0, c1);
  float e0 = __expf(c0 - mx), e1 = __expf(c1 - mx);
  float inv = 1.f/(e0 + e1);
  float p0 = fminf(fmaxf(e0*inv, 1e-10f), 1.f);
  float p1 = fminf(fmaxf(e1*inv, 1e-10f), 1.f);
  float ent = -(p0*__logf(p0) + p1*__logf(p1));
  float entn = fminf(fmaxf(ent * 1.44269504f, 0.f), 1.f);
  const float4* wg = (const float4*)(eg_w1 + ((size_t)l*DM + 4*lane)*8);
  float hacc[8] = {};
#pragma unroll
  for (int dd = 0; dd < 4; dd++){
    float zd = (dd==0) ? zv.x : (dd==1) ? zv.y : (dd==2) ? zv.z : zv.w;
    float4 a = wg[dd*2], b = wg[dd*2 + 1];
    hacc[0] += zd*a.x; hacc[1] += zd*a.y; hacc[2] += zd*a.z; hacc[3] += zd*a.w;
    hacc[4] += zd*b.x; hacc[5] += zd*b.y; hacc[6] += zd*b.z; hacc[7] += zd*b.w;
  }
  float gin = 0.f;
#pragma unroll
  for (int j = 0; j < 8; j++){
    float hj = wred_sum(hacc[j]);
    hj = tanhf(hj + eg_b1[l*8 + j]);
    gin += hj * eg_w2[l*8 + j];
  }
  gin += eg_b2[l];
  float gate = 1.f/(1.f + __expf(-gin));
  float gated = entn * gate;
  const float* hw = halt_w + (size_t)l*257;
  float hp = zv.x*hw[4*lane] + zv.y*hw[4*lane+1] + zv.z*hw[4*lane+2] + zv.w*hw[4*lane+3];
  float hl = wred_sum(hp) + gated*hw[256] + halt_b[l];
  if (lane == 0) halt_out[m] = hl;
  if (lane < 2) cls_out[(size_t)m*2 + lane] = lane ? c1 : c0;
}

extern "C" void kernel_launch(void* const* d_in, const int* in_sizes, int n_in,
                              void* d_out, int out_size, void* d_ws, size_t ws_size,
                              hipStream_t stream){
  const float* teacher = (const float*)d_in[0];
  const float* in_ln_g = (const float*)d_in[1];
  const float* in_ln_b = (const float*)d_in[2];
  const float* proj_w  = (const float*)d_in[3];
  const float* proj_b  = (const float*)d_in[4];
  const float* cosc    = (const float*)d_in[5];
  const float* sinc    = (const float*)d_in[6];
  const float* pre_g   = (const float*)d_in[7];
  const float* pre_b   = (const float*)d_in[8];
  const float* l_ln1_g = (const float*)d_in[9];
  const float* l_ln1_b = (const float*)d_in[10];
  const float* l_inw   = (const float*)d_in[11];
  const float* l_inb   = (const float*)d_in[12];
  const float* l_outw  = (const float*)d_in[13];
  const float* l_outb  = (const float*)d_in[14];
  const float* l_ln2_g = (const float*)d_in[15];
  const float* l_ln2_b = (const float*)d_in[16];
  const float* l_w12   = (const float*)d_in[17];
  const float* l_b12   = (const float*)d_in[18];
  const float* l_w3    = (const float*)d_in[19];
  const float* l_b3    = (const float*)d_in[20];
  const float* post_g  = (const float*)d_in[21];
  const float* post_b  = (const float*)d_in[22];
  const float* eg_w1   = (const float*)d_in[23];
  const float* eg_b1   = (const float*)d_in[24];
  const float* eg_w2   = (const float*)d_in[25];
  const float* eg_b2   = (const float*)d_in[26];
  const float* halt_w  = (const float*)d_in[27];
  const float* halt_b  = (const float*)d_in[28];
  const float* cls_w   = (const float*)d_in[29];
  const float* cls_b   = (const float*)d_in[30];

  float* out = (float*)d_out;
  float* halt_out = out;
  float* cls_out  = out + NTOK;
  float* z_out    = out + NTOK + (size_t)NTOK*NCLS;

  char* ws = (char*)d_ws;
  size_t off = 0;
  auto alloc = [&](size_t bytes){ void* p = ws + off; off += (bytes + 255) & ~(size_t)255; return p; };
  float*  zbuf = (float*) alloc((size_t)NTOK*DM*4);
  __bf16* xnb  = (__bf16*)alloc((size_t)NTOK*DM*2);
  __bf16* qkvb = (__bf16*)alloc((size_t)NTOK*768*2);
  __bf16* obuf = (__bf16*)alloc((size_t)NTOK*DM*2);
  __bf16* bigb = (__bf16*)alloc((size_t)NTOK*1024*2);
  __bf16* w_proj = (__bf16*)alloc((size_t)262144*2);
  __bf16* w_in   = (__bf16*)alloc((size_t)2359296*2);
  __bf16* w_out  = (__bf16*)alloc((size_t)786432*2);
  __bf16* w_12   = (__bf16*)alloc((size_t)6291456*2);
  __bf16* w_3    = (__bf16*)alloc((size_t)3145728*2);

  cvt_all_kernel<<<2048, 256, 0, stream>>>(proj_w, w_proj, 262144/4,
                                           l_inw, w_in, 2359296/4,
                                           l_outw, w_out, 786432/4,
                                           l_w12, w_12, 6291456/4,
                                           l_w3, w_3, 3145728/4);

  ln1024_kernel<<<NTOK, 256, 0, stream>>>(teacher, in_ln_g, in_ln_b, bigb);
  gemm512_kernel<0, 1024><<<192, 512, 0, stream>>>(bigb, w_proj, proj_b, zbuf, nullptr, 256, 1);
  rope_preln_kernel<<<NTOK/4, 256, 0, stream>>>(zbuf, cosc, sinc, pre_g, pre_b, l_ln1_g, l_ln1_b, xnb);

  for (int i = 0; i < NLAYER; i++){
    gemm512_kernel<1, 256><<<576, 512, 0, stream>>>(xnb, w_in + (size_t)i*768*256, l_inb + i*768, nullptr, qkvb, 768, 3);
    attn_kernel<<<NBATCH, 256, 0, stream>>>(qkvb, obuf);
    gemm_ln_kernel<256><<<192, 512, 0, stream>>>(obuf, w_out + (size_t)i*256*256, l_outb + i*256,
                                                 zbuf, l_ln2_g + i*256, l_ln2_b + i*256, xnb, nullptr);
    gemm_glu_kernel<<<256, 512, 0, stream>>>(xnb, w_12 + (size_t)i*2048*256, l_b12 + i*2048, bigb);
    bool last = (i == NLAYER-1);
    gemm_ln_kernel<1024><<<192, 512, 0, stream>>>(bigb, w_3 + (size_t)i*256*1024, l_b3 + i*256,
                                                  zbuf,
                                                  last ? post_g : l_ln1_g + (i+1)*256,
                                                  last ? post_b : l_ln1_b + (i+1)*256,
                                                  last ? nullptr : xnb,
                                                  last ? z_out : nullptr);
  }

  heads_kernel<<<NTOK/4, 256, 0, stream>>>(z_out, cls_w, cls_b, eg_w1, eg_b1, eg_w2, eg_b2,
                                           halt_w, halt_b, halt_out, cls_out);
}

// Round 10
// 4044.574 us; speedup vs baseline: 1.1751x; 1.0244x over previous
//
#include <hip/hip_runtime.h>
#include <hip/hip_bf16.h>
#include <math.h>

#define L_SEQ 24
#define DT 1024
#define DM 256
#define NLAYER 12
#define NHEAD 4
#define HDIM 64
#define FFND 1024
#define NCLS 2
#define NBATCH 2048
#define NTOK (NBATCH*L_SEQ)   // 49152

typedef float f32x4 __attribute__((ext_vector_type(4)));
typedef __bf16 bf16x4 __attribute__((ext_vector_type(4)));
typedef __bf16 bf16x8 __attribute__((ext_vector_type(8)));

#define GLDS16(gp, lp) __builtin_amdgcn_global_load_lds((const __attribute__((address_space(1))) void*)(gp), (__attribute__((address_space(3))) void*)(lp), 16, 0, 0)
#define VMWAIT(N) asm volatile("s_waitcnt vmcnt(" #N ")" ::: "memory")
#define LGKM0()   asm volatile("s_waitcnt lgkmcnt(0)" ::: "memory")

__device__ inline float wred_sum(float v){
#pragma unroll
  for (int o = 32; o > 0; o >>= 1) v += __shfl_xor(v, o);
  return v;
}
__device__ inline float wred_max(float v){
#pragma unroll
  for (int o = 32; o > 0; o >>= 1) v = fmaxf(v, __shfl_xor(v, o));
  return v;
}

// ---- [R][32]-bf16 LDS tiles, BK=32: linear glds dest + global-source XOR swizzle ----
__device__ __forceinline__ void stage16x32(const __bf16* __restrict__ g, int ldk, int k0,
                                           __bf16* ldsbase, int lane, int rowbase){
  int r = rowbase + (lane >> 2);
  int cs = (lane & 3) ^ ((lane >> 3) & 3);
  GLDS16(g + (size_t)r*ldk + k0 + cs*8, ldsbase);
}
__device__ __forceinline__ bf16x8 frag32(const __bf16* tile, int row, int lane){
  int p = (lane >> 4) ^ ((row >> 1) & 3);
  return *(const bf16x8*)(tile + (row << 5) + (p << 3));
}

// XCD-aware swizzle (T1). Requires gridDim.x % 8 == 0.
__device__ __forceinline__ int xcd_work(){
  int nwg = gridDim.x, bid = blockIdx.x;
  return (bid & 7) * (nwg >> 3) + (bid >> 3);
}

// ---------------- merged weight fp32 -> bf16 convert ----------------
__global__ void cvt_all_kernel(const float* __restrict__ a0, __bf16* __restrict__ o0, int n0,
                               const float* __restrict__ a1, __bf16* __restrict__ o1, int n1,
                               const float* __restrict__ a2, __bf16* __restrict__ o2, int n2,
                               const float* __restrict__ a3, __bf16* __restrict__ o3, int n3,
                               const float* __restrict__ a4, __bf16* __restrict__ o4, int n4){
  int stride = gridDim.x * blockDim.x;
  int i0 = blockIdx.x * blockDim.x + threadIdx.x;
  const float* as[5] = {a0,a1,a2,a3,a4};
  __bf16* os[5] = {o0,o1,o2,o3,o4};
  int ns[5] = {n0,n1,n2,n3,n4};
#pragma unroll
  for (int s = 0; s < 5; s++){
    const float* a = as[s]; __bf16* o = os[s]; int n = ns[s];
    for (int i = i0; i < n; i += stride){
      float4 v = ((const float4*)a)[i];
      bf16x4 ov;
      ov[0] = (__bf16)v.x; ov[1] = (__bf16)v.y; ov[2] = (__bf16)v.z; ov[3] = (__bf16)v.w;
      ((bf16x4*)o)[i] = ov;
    }
  }
}

// ---------------- LN over 1024 (block per row) ----------------
__global__ __launch_bounds__(256) void ln1024_kernel(
    const float* __restrict__ in, const float* __restrict__ g, const float* __restrict__ bb,
    __bf16* __restrict__ out){
  int row = blockIdx.x;
  int tid = threadIdx.x, wid = tid >> 6, lane = tid & 63;
  float4 x = ((const float4*)(in + (size_t)row*DT))[tid];
  float s = x.x + x.y + x.z + x.w;
  float q = x.x*x.x + x.y*x.y + x.z*x.z + x.w*x.w;
  s = wred_sum(s); q = wred_sum(q);
  __shared__ float red[8];
  if (lane == 0){ red[wid] = s; red[4+wid] = q; }
  __syncthreads();
  s = red[0]+red[1]+red[2]+red[3];
  q = red[4]+red[5]+red[6]+red[7];
  float mean = s * (1.f/DT);
  float rstd = rsqrtf(q*(1.f/DT) - mean*mean + 1e-5f);
  float4 gv = ((const float4*)g)[tid], bv = ((const float4*)bb)[tid];
  bf16x4 o;
  o[0] = (__bf16)((x.x-mean)*rstd*gv.x + bv.x);
  o[1] = (__bf16)((x.y-mean)*rstd*gv.y + bv.y);
  o[2] = (__bf16)((x.z-mean)*rstd*gv.z + bv.z);
  o[3] = (__bf16)((x.w-mean)*rstd*gv.w + bv.w);
  ((bf16x4*)(out + (size_t)row*DT))[tid] = o;
}

// ---------------- RoPE + pre-LN + layer0 LN1 (wave per row) ----------------
__global__ __launch_bounds__(256) void rope_preln_kernel(
    float* __restrict__ z, const float* __restrict__ cosc, const float* __restrict__ sinc,
    const float* __restrict__ g, const float* __restrict__ bb,
    const float* __restrict__ g1, const float* __restrict__ b1, __bf16* __restrict__ xnb){
  int row = blockIdx.x*4 + (threadIdx.x >> 6);
  int lane = threadIdx.x & 63;
  int l = row % L_SEQ;
  float4 x = ((const float4*)(z + (size_t)row*DM))[lane];
  float4 p;
  p.x = __shfl_xor(x.x, 32); p.y = __shfl_xor(x.y, 32);
  p.z = __shfl_xor(x.z, 32); p.w = __shfl_xor(x.w, 32);
  float sgn = (lane < 32) ? -1.f : 1.f;
  float4 c = ((const float4*)(cosc + l*DM))[lane];
  float4 sn = ((const float4*)(sinc + l*DM))[lane];
  float4 xr;
  xr.x = x.x*c.x + sgn*p.x*sn.x;
  xr.y = x.y*c.y + sgn*p.y*sn.y;
  xr.z = x.z*c.z + sgn*p.z*sn.z;
  xr.w = x.w*c.w + sgn*p.w*sn.w;
  float s = wred_sum(xr.x + xr.y + xr.z + xr.w);
  float q = wred_sum(xr.x*xr.x + xr.y*xr.y + xr.z*xr.z + xr.w*xr.w);
  float mean = s * (1.f/DM);
  float rstd = rsqrtf(q*(1.f/DM) - mean*mean + 1e-5f);
  float4 gv = ((const float4*)g)[lane], bv = ((const float4*)bb)[lane];
  float4 y;
  y.x = (xr.x-mean)*rstd*gv.x + bv.x;
  y.y = (xr.y-mean)*rstd*gv.y + bv.y;
  y.z = (xr.z-mean)*rstd*gv.z + bv.z;
  y.w = (xr.w-mean)*rstd*gv.w + bv.w;
  ((float4*)(z + (size_t)row*DM))[lane] = y;
  float s2 = wred_sum(y.x + y.y + y.z + y.w);
  float q2 = wred_sum(y.x*y.x + y.y*y.y + y.z*y.z + y.w*y.w);
  float mean2 = s2 * (1.f/DM);
  float rstd2 = rsqrtf(q2*(1.f/DM) - mean2*mean2 + 1e-5f);
  float4 g1v = ((const float4*)g1)[lane], b1v = ((const float4*)b1)[lane];
  bf16x4 o;
  o[0] = (__bf16)((y.x-mean2)*rstd2*g1v.x + b1v.x);
  o[1] = (__bf16)((y.y-mean2)*rstd2*g1v.y + b1v.y);
  o[2] = (__bf16)((y.z-mean2)*rstd2*g1v.z + b1v.z);
  o[3] = (__bf16)((y.w-mean2)*rstd2*g1v.w + b1v.w);
  ((bf16x4*)(xnb + (size_t)row*DM))[lane] = o;
}

// ---------------- GEMM 256x256, 8 waves, BK=32, counted-vmcnt ----------------
template<int MODE, int K>
__global__ __launch_bounds__(512) void gemm512_kernel(
    const __bf16* __restrict__ A, const __bf16* __restrict__ W,
    const float* __restrict__ bias,
    float* __restrict__ Cf, __bf16* __restrict__ Cb,
    int N, int nt){
  __shared__ __align__(16) __bf16 As[2][256*32];
  __shared__ __align__(16) __bf16 Bs[2][256*32];
  int work = xcd_work();
  int bm = work / nt, bn = work % nt;
  int wid = threadIdx.x >> 6, lane = threadIdx.x & 63;
  int wr = wid >> 1, wc = wid & 1;
  int li = lane & 15, g4 = (lane >> 4) << 2;
  f32x4 acc[8][4] = {};
  const __bf16* ga = A + (size_t)bm*256*K;
  const __bf16* gb = W + (size_t)bn*256*K;
  const int NT = K/32;
  auto STAGE = [&](int b, int t){
    int k0 = t*32;
    if (wid < 4){
#pragma unroll
      for (int j = 0; j < 4; j++){ int r = (wid*4 + j)*16; stage16x32(ga, K, k0, &As[b][r<<5], lane, r); }
    } else {
#pragma unroll
      for (int j = 0; j < 4; j++){ int r = ((wid-4)*4 + j)*16; stage16x32(gb, K, k0, &Bs[b][r<<5], lane, r); }
    }
  };
  STAGE(0, 0);
  STAGE(1, 1);
  int cur = 0;
  for (int t = 0; t < NT; t++){
    if (t + 1 < NT) { VMWAIT(4); } else { VMWAIT(0); }
    __builtin_amdgcn_s_barrier();
    bf16x8 xf[4], wf[8];
#pragma unroll
    for (int mi = 0; mi < 4; mi++) xf[mi] = frag32(As[cur], wr*64 + mi*16 + li, lane);
#pragma unroll
    for (int ni = 0; ni < 8; ni++) wf[ni] = frag32(Bs[cur], wc*128 + ni*16 + li, lane);
    LGKM0();
    __builtin_amdgcn_sched_barrier(0);
    __builtin_amdgcn_s_barrier();
    if (t + 2 < NT) STAGE(cur, t+2);
    __builtin_amdgcn_s_setprio(1);
#pragma unroll
    for (int ni = 0; ni < 8; ni++)
#pragma unroll
      for (int mi = 0; mi < 4; mi++)
        acc[ni][mi] = __builtin_amdgcn_mfma_f32_16x16x32_bf16(wf[ni], xf[mi], acc[ni][mi], 0, 0, 0);
    __builtin_amdgcn_s_setprio(0);
    cur ^= 1;
  }
#pragma unroll
  for (int mi = 0; mi < 4; mi++){
    int m = bm*256 + wr*64 + mi*16 + li;
#pragma unroll
    for (int ni = 0; ni < 8; ni++){
      int n = bn*256 + wc*128 + ni*16 + g4;
      f32x4 bv = *(const f32x4*)(bias + n);
      f32x4 o = acc[ni][mi] + bv;
      if (MODE == 0){
        *(f32x4*)(Cf + (size_t)m*N + n) = o;
      } else {
        bf16x4 ob;
        ob[0] = (__bf16)o[0]; ob[1] = (__bf16)o[1]; ob[2] = (__bf16)o[2]; ob[3] = (__bf16)o[3];
        *(bf16x4*)(Cb + (size_t)m*N + n) = ob;
      }
    }
  }
}

// ---------------- GEMM 256x256 + residual + LayerNorm (out-proj), 8 waves ----------------
template<int K>
__global__ __launch_bounds__(512) void gemm_ln_kernel(
    const __bf16* __restrict__ A, const __bf16* __restrict__ W,
    const float* __restrict__ bias, float* __restrict__ z,
    const float* __restrict__ lng, const float* __restrict__ lnb,
    __bf16* __restrict__ outb, float* __restrict__ outf){
  __shared__ __align__(16) __bf16 As[2][256*32];
  __shared__ __align__(16) __bf16 Bs[2][256*32];
  __shared__ float redS[256][2], redQ[256][2];
  int bm = xcd_work();
  int wid = threadIdx.x >> 6, lane = threadIdx.x & 63;
  int wr = wid >> 1, wc = wid & 1;
  int li = lane & 15, g4 = (lane >> 4) << 2;
  f32x4 acc[8][4] = {};
  const __bf16* ga = A + (size_t)bm*256*K;
  const int NT = K/32;
  auto STAGE = [&](int b, int t){
    int k0 = t*32;
    if (wid < 4){
#pragma unroll
      for (int j = 0; j < 4; j++){ int r = (wid*4 + j)*16; stage16x32(ga, K, k0, &As[b][r<<5], lane, r); }
    } else {
#pragma unroll
      for (int j = 0; j < 4; j++){ int r = ((wid-4)*4 + j)*16; stage16x32(W, K, k0, &Bs[b][r<<5], lane, r); }
    }
  };
  STAGE(0, 0);
  STAGE(1, 1);
  int cur = 0;
  for (int t = 0; t < NT; t++){
    if (t + 1 < NT) { VMWAIT(4); } else { VMWAIT(0); }
    __builtin_amdgcn_s_barrier();
    bf16x8 xf[4], wf[8];
#pragma unroll
    for (int mi = 0; mi < 4; mi++) xf[mi] = frag32(As[cur], wr*64 + mi*16 + li, lane);
#pragma unroll
    for (int ni = 0; ni < 8; ni++) wf[ni] = frag32(Bs[cur], wc*128 + ni*16 + li, lane);
    LGKM0();
    __builtin_amdgcn_sched_barrier(0);
    __builtin_amdgcn_s_barrier();
    if (t + 2 < NT) STAGE(cur, t+2);
    __builtin_amdgcn_s_setprio(1);
#pragma unroll
    for (int ni = 0; ni < 8; ni++)
#pragma unroll
      for (int mi = 0; mi < 4; mi++)
        acc[ni][mi] = __builtin_amdgcn_mfma_f32_16x16x32_bf16(wf[ni], xf[mi], acc[ni][mi], 0, 0, 0);
    __builtin_amdgcn_s_setprio(0);
    cur ^= 1;
  }
  float sA[4] = {}, qA[4] = {};
#pragma unroll
  for (int mi = 0; mi < 4; mi++){
    int m = bm*256 + wr*64 + mi*16 + li;
#pragma unroll
    for (int ni = 0; ni < 8; ni++){
      int n = wc*128 + ni*16 + g4;
      f32x4 zv = *(const f32x4*)(z + (size_t)m*DM + n);
      f32x4 bv = *(const f32x4*)(bias + n);
      f32x4 v = acc[ni][mi] + bv + zv;
      acc[ni][mi] = v;
      *(f32x4*)(z + (size_t)m*DM + n) = v;
#pragma unroll
      for (int r = 0; r < 4; r++){ sA[mi] += v[r]; qA[mi] += v[r]*v[r]; }
    }
  }
  __syncthreads();
#pragma unroll
  for (int mi = 0; mi < 4; mi++){
    float s = sA[mi], q = qA[mi];
    s += __shfl_xor(s, 16); q += __shfl_xor(q, 16);
    s += __shfl_xor(s, 32); q += __shfl_xor(q, 32);
    if (lane < 16){ redS[wr*64 + mi*16 + li][wc] = s; redQ[wr*64 + mi*16 + li][wc] = q; }
  }
  __syncthreads();
#pragma unroll
  for (int mi = 0; mi < 4; mi++){
    int ml = wr*64 + mi*16 + li;
    float s = redS[ml][0] + redS[ml][1];
    float q = redQ[ml][0] + redQ[ml][1];
    float mean = s * (1.f/DM);
    float rstd = rsqrtf(q*(1.f/DM) - mean*mean + 1e-5f);
    int m = bm*256 + ml;
#pragma unroll
    for (int ni = 0; ni < 8; ni++){
      int n = wc*128 + ni*16 + g4;
      f32x4 gv = *(const f32x4*)(lng + n);
      f32x4 bv = *(const f32x4*)(lnb + n);
      if (outb){
        bf16x4 o;
#pragma unroll
        for (int r = 0; r < 4; r++) o[r] = (__bf16)((acc[ni][mi][r] - mean)*rstd*gv[r] + bv[r]);
        *(bf16x4*)(outb + (size_t)m*DM + n) = o;
      } else {
        f32x4 o;
#pragma unroll
        for (int r = 0; r < 4; r++) o[r] = (acc[ni][mi][r] - mean)*rstd*gv[r] + bv[r];
        *(f32x4*)(outf + (size_t)m*DM + n) = o;
      }
    }
  }
}

// ---------------- FUSED FFN: z += swiglu(xn W12^T + b12) W3^T + b3 ; LN -> out -------
// Block = 192 rows, 512 threads (8 waves: 4M x 2N). A resident in LDS (staged once).
// Loop over 16 x 64-col H chunks: GEMM1 (W12 ring-3, vmcnt(2) depth-2) -> SwiGLU ->
// H in LDS (frag32 layout) -> GEMM2 (W3 single-buffer, refilled under MFMA).
// Eliminates the FFN-hidden global round-trip (200 MB/layer HBM) and A refetch.
__global__ __launch_bounds__(512) void gemm_ffn_kernel(
    const __bf16* __restrict__ A, const __bf16* __restrict__ W12,
    const float* __restrict__ b12, const __bf16* __restrict__ W3,
    const float* __restrict__ b3, float* __restrict__ z,
    const float* __restrict__ lng, const float* __restrict__ lnb,
    __bf16* __restrict__ outb, float* __restrict__ outf){
  __shared__ __align__(16) __bf16 As[8][192*32];    // 96 KB resident A
  __shared__ __align__(16) __bf16 Wb[3][128*32];    // 24 KB W12 ring-3 (aliased as red at epilogue)
  __shared__ __align__(16) __bf16 Hb[192*32];       // 12 KB H chunk
  __shared__ __align__(16) __bf16 W3b[256*32];      // 16 KB W3 chunk
  float* redS = (float*)&Wb[0][0];                  // [192][2]
  float* redQ = redS + 384;
  int bm = blockIdx.x;
  int wid = threadIdx.x >> 6, lane = threadIdx.x & 63;
  int wr = wid >> 1, wc = wid & 1;
  int li = lane & 15, g4 = (lane >> 4) << 2;
  const __bf16* ga = A + (size_t)bm*192*256;

  auto STAGE_W3 = [&](int bn, int kc){   // 2 glds/lane
#pragma unroll
    for (int j = 0; j < 2; j++){
      int u = j*8 + wid;
      stage16x32(W3, 1024, bn*64 + kc*32, &W3b[(u*16) << 5], lane, u*16);
    }
  };
  auto STAGE_W12 = [&](int buf, int bn, int c){   // 1 glds/lane
    const __bf16* src = W12 + ((wid < 4) ? (size_t)(bn*64 + wid*16)*256
                                         : (size_t)(1024 + bn*64 + (wid-4)*16)*256);
    stage16x32(src, 256, c*32, &Wb[buf][(wid*16) << 5], lane, 0);
  };
  // prologue: A fully (12/lane), W3 chunk (bn0,kc0), W12 c0..c2
#pragma unroll
  for (int j = 0; j < 12; j++){
    int u = j*8 + wid;
    int c = u / 12, rj = u % 12;
    stage16x32(ga, 256, c*32, &As[c][(rj*16) << 5], lane, rj*16);
  }
  STAGE_W3(0, 0);
  STAGE_W12(0, 0, 0);
  STAGE_W12(1, 0, 1);
  STAGE_W12(2, 0, 2);

  f32x4 Cacc[8][3] = {};
  for (int bn = 0; bn < 16; bn++){
    f32x4 a1[2][3] = {}, a2[2][3] = {};
    // ---- GEMM1: H chunk = xn * W12slice^T, 8 BK=32 steps, ring-3 depth-2 ----
    for (int s = 0; s < 8; s++){
      if (s < 6) { VMWAIT(2); } else if (s == 6) { VMWAIT(1); } else { VMWAIT(0); }
      __builtin_amdgcn_s_barrier();
      bf16x8 xf[3], w1f[2], w2f[2];
      const __bf16* wbuf = Wb[s % 3];
#pragma unroll
      for (int mi = 0; mi < 3; mi++) xf[mi] = frag32(As[s], wr*48 + mi*16 + li, lane);
#pragma unroll
      for (int ni = 0; ni < 2; ni++){
        w1f[ni] = frag32(wbuf, wc*32 + ni*16 + li, lane);
        w2f[ni] = frag32(wbuf, 64 + wc*32 + ni*16 + li, lane);
      }
      LGKM0();
      __builtin_amdgcn_sched_barrier(0);
      __builtin_amdgcn_s_barrier();
      if (s <= 4) STAGE_W12(s % 3, bn, s + 3);
      __builtin_amdgcn_s_setprio(1);
#pragma unroll
      for (int ni = 0; ni < 2; ni++)
#pragma unroll
        for (int mi = 0; mi < 3; mi++){
          a1[ni][mi] = __builtin_amdgcn_mfma_f32_16x16x32_bf16(w1f[ni], xf[mi], a1[ni][mi], 0, 0, 0);
          a2[ni][mi] = __builtin_amdgcn_mfma_f32_16x16x32_bf16(w2f[ni], xf[mi], a2[ni][mi], 0, 0, 0);
        }
      __builtin_amdgcn_s_setprio(0);
    }
    // ---- SwiGLU -> Hb ; GEMM2: Cacc += H * W3slice^T (2 x BK=32) ----
    for (int kc = 0; kc < 2; kc++){
      if (wc == kc){
#pragma unroll
        for (int ni = 0; ni < 2; ni++){
          int cl0 = ni*16 + g4;                       // col within 32-col chunk
          int ncol = bn*64 + kc*32 + cl0;
          f32x4 b1v = *(const f32x4*)(b12 + ncol);
          f32x4 b2v = *(const f32x4*)(b12 + 1024 + ncol);
#pragma unroll
          for (int mi = 0; mi < 3; mi++){
            int m = wr*48 + mi*16 + li;
            bf16x4 hv;
#pragma unroll
            for (int r = 0; r < 4; r++){
              float v1 = a1[ni][mi][r] + b1v[r];
              float v2 = a2[ni][mi][r] + b2v[r];
              float sig = 1.f/(1.f + __expf(-v1));
              hv[r] = (__bf16)(v1*sig*v2);
            }
            int p = (cl0 >> 3) ^ ((m >> 1) & 3);      // frag32 swizzle on write
            *(bf16x4*)((char*)Hb + m*64 + p*16 + (cl0 & 7)*2) = hv;
          }
        }
      }
      LGKM0();
      if (kc == 1) { VMWAIT(0); }   // W3(bn,kc1) staged during kc0 MFMA must land
      __builtin_amdgcn_s_barrier();
      bf16x8 hf[3], w3f[8];
#pragma unroll
      for (int mi = 0; mi < 3; mi++) hf[mi] = frag32(Hb, wr*48 + mi*16 + li, lane);
#pragma unroll
      for (int ni = 0; ni < 8; ni++) w3f[ni] = frag32(W3b, wc*128 + ni*16 + li, lane);
      LGKM0();
      __builtin_amdgcn_sched_barrier(0);
      __builtin_amdgcn_s_barrier();
      if (kc == 0){
        STAGE_W3(bn, 1);                              // refill W3b under kc0 MFMA
      } else if (bn < 15){
        STAGE_W3(bn + 1, 0);
        STAGE_W12(0, bn + 1, 0);
        STAGE_W12(1, bn + 1, 1);
        STAGE_W12(2, bn + 1, 2);
      }
      __builtin_amdgcn_s_setprio(1);
#pragma unroll
      for (int ni = 0; ni < 8; ni++)
#pragma unroll
        for (int mi = 0; mi < 3; mi++)
          Cacc[ni][mi] = __builtin_amdgcn_mfma_f32_16x16x32_bf16(w3f[ni], hf[mi], Cacc[ni][mi], 0, 0, 0);
      __builtin_amdgcn_s_setprio(0);
    }
  }
  __syncthreads();
  // ---- epilogue: z += C + b3 ; LN -> outb/outf ----
  float sA[3] = {}, qA[3] = {};
#pragma unroll
  for (int mi = 0; mi < 3; mi++){
    int m = bm*192 + wr*48 + mi*16 + li;
#pragma unroll
    for (int ni = 0; ni < 8; ni++){
      int n = wc*128 + ni*16 + g4;
      f32x4 zv = *(const f32x4*)(z + (size_t)m*DM + n);
      f32x4 bv = *(const f32x4*)(b3 + n);
      f32x4 v = Cacc[ni][mi] + bv + zv;
      Cacc[ni][mi] = v;
      *(f32x4*)(z + (size_t)m*DM + n) = v;
#pragma unroll
      for (int r = 0; r < 4; r++){ sA[mi] += v[r]; qA[mi] += v[r]*v[r]; }
    }
  }
#pragma unroll
  for (int mi = 0; mi < 3; mi++){
    float s = sA[mi], q = qA[mi];
    s += __shfl_xor(s, 16); q += __shfl_xor(q, 16);
    s += __shfl_xor(s, 32); q += __shfl_xor(q, 32);
    if (lane < 16){ int rl = wr*48 + mi*16 + li; redS[rl*2 + wc] = s; redQ[rl*2 + wc] = q; }
  }
  __syncthreads();
#pragma unroll
  for (int mi = 0; mi < 3; mi++){
    int rl = wr*48 + mi*16 + li;
    float s = redS[rl*2 + 0] + redS[rl*2 + 1];
    float q = redQ[rl*2 + 0] + redQ[rl*2 + 1];
    float mean = s * (1.f/DM);
    float rstd = rsqrtf(q*(1.f/DM) - mean*mean + 1e-5f);
    int m = bm*192 + rl;
#pragma unroll
    for (int ni = 0; ni < 8; ni++){
      int n = wc*128 + ni*16 + g4;
      f32x4 gv = *(const f32x4*)(lng + n);
      f32x4 bv = *(const f32x4*)(lnb + n);
      if (outb){
        bf16x4 o;
#pragma unroll
        for (int r = 0; r < 4; r++) o[r] = (__bf16)((Cacc[ni][mi][r] - mean)*rstd*gv[r] + bv[r]);
        *(bf16x4*)(outb + (size_t)m*DM + n) = o;
      } else {
        f32x4 o;
#pragma unroll
        for (int r = 0; r < 4; r++) o[r] = (Cacc[ni][mi][r] - mean)*rstd*gv[r] + bv[r];
        *(f32x4*)(outf + (size_t)m*DM + n) = o;
      }
    }
  }
}

// ---------------- attention: block per sequence, wave per head ----------------
__global__ __launch_bounds__(256) void attn_kernel(const __bf16* __restrict__ qkv, __bf16* __restrict__ ob){
  int b = blockIdx.x;
  int h = threadIdx.x >> 6, lane = threadIdx.x & 63;
  __shared__ __align__(16) __bf16 Qs[NHEAD][L_SEQ][HDIM];
  __shared__ __align__(16) __bf16 Ks[NHEAD][L_SEQ][HDIM];
  __shared__ float Ps[NHEAD][L_SEQ][L_SEQ];
  const __bf16* base = qkv + (size_t)b*L_SEQ*768;
  float V[L_SEQ];
#pragma unroll
  for (int t = 0; t < L_SEQ; t++){
    int sw = lane ^ ((t & 7) << 3);
    Qs[h][t][sw] = base[t*768 + h*64 + lane];
    Ks[h][t][sw] = base[t*768 + 256 + h*64 + lane];
    V[t] = (float)base[t*768 + 512 + h*64 + lane];
  }
  __syncthreads();
  for (int p = lane; p < L_SEQ*L_SEQ; p += 64){
    int q = p / L_SEQ, k = p - q*L_SEQ;
    if (k <= q){
      int qx = (q & 7) << 3, kx = (k & 7) << 3;
      const __bf16* qr = Qs[h][q];
      const __bf16* kr = Ks[h][k];
      float s = 0.f;
#pragma unroll
      for (int d = 0; d < 64; d += 4){
        bf16x4 qa = *(const bf16x4*)(qr + (d ^ qx));
        bf16x4 ka = *(const bf16x4*)(kr + (d ^ kx));
        s += (float)qa[0]*(float)ka[0] + (float)qa[1]*(float)ka[1]
           + (float)qa[2]*(float)ka[2] + (float)qa[3]*(float)ka[3];
      }
      Ps[h][q][k] = s * 0.125f;
    }
  }
  __syncthreads();
  for (int q = 0; q < L_SEQ; q++){
    float v = (lane <= q) ? Ps[h][q][lane] : -1e30f;
    float mx = wred_max(v);
    float e = (lane <= q) ? __expf(v - mx) : 0.f;
    float sm = wred_sum(e);
    if (lane < L_SEQ) Ps[h][q][lane] = e / sm;
  }
  __syncthreads();
  for (int q = 0; q < L_SEQ; q++){
    float o = 0.f;
    for (int k = 0; k <= q; k++) o += Ps[h][q][k] * V[k];
    ob[((size_t)b*L_SEQ + q)*DM + h*64 + lane] = (__bf16)o;
  }
}

// ---------------- per-token heads ----------------
__global__ __launch_bounds__(256) void heads_kernel(
    const float* __restrict__ z,
    const float* __restrict__ cls_w, const float* __restrict__ cls_b,
    const float* __restrict__ eg_w1, const float* __restrict__ eg_b1,
    const float* __restrict__ eg_w2, const float* __restrict__ eg_b2,
    const float* __restrict__ halt_w, const float* __restrict__ halt_b,
    float* __restrict__ halt_out, float* __restrict__ cls_out){
  int m = blockIdx.x*4 + (threadIdx.x >> 6);
  int lane = threadIdx.x & 63;
  int l = m % L_SEQ;
  float4 zv = ((const float4*)(z + (size_t)m*DM))[lane];
  float4 w0 = ((const float4*)(cls_w + ((size_t)l*2 + 0)*DM))[lane];
  float4 w1 = ((const float4*)(cls_w + ((size_t)l*2 + 1)*DM))[lane];
  float c0 = wred_sum(zv.x*w0.x + zv.y*w0.y + zv.z*w0.z + zv.w*w0.w) + cls_b[l*2 + 0];
  float c1 = wred_sum(zv.x*w1.x + zv.y*w1.y + zv.z*w1.z + zv.w*w1.w) + cls_b[l*2 + 1];
  float mx = fmaxf(c0, c1);
  float e0 = __expf(c0 - mx), e1 = __expf(c1 - mx);
  float inv = 1.f/(e0 + e1);
  float p0 = fminf(fmaxf(e0*inv, 1e-10f), 1.f);
  float p1 = fminf(fmaxf(e1*inv, 1e-10f), 1.f);
  float ent = -(p0*__logf(p0) + p1*__logf(p1));
  float entn = fminf(fmaxf(ent * 1.44269504f, 0.f), 1.f);
  const float4* wg = (const float4*)(eg_w1 + ((size_t)l*DM + 4*lane)*8);
  float hacc[8] = {};
#pragma unroll
  for (int dd = 0; dd < 4; dd++){
    float zd = (dd==0) ? zv.x : (dd==1) ? zv.y : (dd==2) ? zv.z : zv.w;
    float4 a = wg[dd*2], b = wg[dd*2 + 1];
    hacc[0] += zd*a.x; hacc[1] += zd*a.y; hacc[2] += zd*a.z; hacc[3] += zd*a.w;
    hacc[4] += zd*b.x; hacc[5] += zd*b.y; hacc[6] += zd*b.z; hacc[7] += zd*b.w;
  }
  float gin = 0.f;
#pragma unroll
  for (int j = 0; j < 8; j++){
    float hj = wred_sum(hacc[j]);
    hj = tanhf(hj + eg_b1[l*8 + j]);
    gin += hj * eg_w2[l*8 + j];
  }
  gin += eg_b2[l];
  float gate = 1.f/(1.f + __expf(-gin));
  float gated = entn * gate;
  const float* hw = halt_w + (size_t)l*257;
  float hp = zv.x*hw[4*lane] + zv.y*hw[4*lane+1] + zv.z*hw[4*lane+2] + zv.w*hw[4*lane+3];
  float hl = wred_sum(hp) + gated*hw[256] + halt_b[l];
  if (lane == 0) halt_out[m] = hl;
  if (lane < 2) cls_out[(size_t)m*2 + lane] = lane ? c1 : c0;
}

extern "C" void kernel_launch(void* const* d_in, const int* in_sizes, int n_in,
                              void* d_out, int out_size, void* d_ws, size_t ws_size,
                              hipStream_t stream){
  const float* teacher = (const float*)d_in[0];
  const float* in_ln_g = (const float*)d_in[1];
  const float* in_ln_b = (const float*)d_in[2];
  const float* proj_w  = (const float*)d_in[3];
  const float* proj_b  = (const float*)d_in[4];
  const float* cosc    = (const float*)d_in[5];
  const float* sinc    = (const float*)d_in[6];
  const float* pre_g   = (const float*)d_in[7];
  const float* pre_b   = (const float*)d_in[8];
  const float* l_ln1_g = (const float*)d_in[9];
  const float* l_ln1_b = (const float*)d_in[10];
  const float* l_inw   = (const float*)d_in[11];
  const float* l_inb   = (const float*)d_in[12];
  const float* l_outw  = (const float*)d_in[13];
  const float* l_outb  = (const float*)d_in[14];
  const float* l_ln2_g = (const float*)d_in[15];
  const float* l_ln2_b = (const float*)d_in[16];
  const float* l_w12   = (const float*)d_in[17];
  const float* l_b12   = (const float*)d_in[18];
  const float* l_w3    = (const float*)d_in[19];
  const float* l_b3    = (const float*)d_in[20];
  const float* post_g  = (const float*)d_in[21];
  const float* post_b  = (const float*)d_in[22];
  const float* eg_w1   = (const float*)d_in[23];
  const float* eg_b1   = (const float*)d_in[24];
  const float* eg_w2   = (const float*)d_in[25];
  const float* eg_b2   = (const float*)d_in[26];
  const float* halt_w  = (const float*)d_in[27];
  const float* halt_b  = (const float*)d_in[28];
  const float* cls_w   = (const float*)d_in[29];
  const float* cls_b   = (const float*)d_in[30];

  float* out = (float*)d_out;
  float* halt_out = out;
  float* cls_out  = out + NTOK;
  float* z_out    = out + NTOK + (size_t)NTOK*NCLS;

  char* ws = (char*)d_ws;
  size_t off = 0;
  auto alloc = [&](size_t bytes){ void* p = ws + off; off += (bytes + 255) & ~(size_t)255; return p; };
  float*  zbuf = (float*) alloc((size_t)NTOK*DM*4);
  __bf16* xnb  = (__bf16*)alloc((size_t)NTOK*DM*2);
  __bf16* qkvb = (__bf16*)alloc((size_t)NTOK*768*2);
  __bf16* obuf = (__bf16*)alloc((size_t)NTOK*DM*2);
  __bf16* bigb = (__bf16*)alloc((size_t)NTOK*1024*2);
  __bf16* w_proj = (__bf16*)alloc((size_t)262144*2);
  __bf16* w_in   = (__bf16*)alloc((size_t)2359296*2);
  __bf16* w_out  = (__bf16*)alloc((size_t)786432*2);
  __bf16* w_12   = (__bf16*)alloc((size_t)6291456*2);
  __bf16* w_3    = (__bf16*)alloc((size_t)3145728*2);

  cvt_all_kernel<<<2048, 256, 0, stream>>>(proj_w, w_proj, 262144/4,
                                           l_inw, w_in, 2359296/4,
                                           l_outw, w_out, 786432/4,
                                           l_w12, w_12, 6291456/4,
                                           l_w3, w_3, 3145728/4);

  ln1024_kernel<<<NTOK, 256, 0, stream>>>(teacher, in_ln_g, in_ln_b, bigb);
  gemm512_kernel<0, 1024><<<192, 512, 0, stream>>>(bigb, w_proj, proj_b, zbuf, nullptr, 256, 1);
  rope_preln_kernel<<<NTOK/4, 256, 0, stream>>>(zbuf, cosc, sinc, pre_g, pre_b, l_ln1_g, l_ln1_b, xnb);

  for (int i = 0; i < NLAYER; i++){
    gemm512_kernel<1, 256><<<576, 512, 0, stream>>>(xnb, w_in + (size_t)i*768*256, l_inb + i*768, nullptr, qkvb, 768, 3);
    attn_kernel<<<NBATCH, 256, 0, stream>>>(qkvb, obuf);
    gemm_ln_kernel<256><<<192, 512, 0, stream>>>(obuf, w_out + (size_t)i*256*256, l_outb + i*256,
                                                 zbuf, l_ln2_g + i*256, l_ln2_b + i*256, xnb, nullptr);
    bool last = (i == NLAYER-1);
    gemm_ffn_kernel<<<256, 512, 0, stream>>>(xnb, w_12 + (size_t)i*2048*256, l_b12 + i*2048,
                                             w_3 + (size_t)i*256*1024, l_b3 + i*256, zbuf,
                                             last ? post_g : l_ln1_g + (i+1)*256,
                                             last ? post_b : l_ln1_b + (i+1)*256,
                                             last ? nullptr : xnb,
                                             last ? z_out : nullptr);
  }

  heads_kernel<<<NTOK/4, 256, 0, stream>>>(z_out, cls_w, cls_b, eg_w1, eg_b1, eg_w2, eg_b2,
                                           halt_w, halt_b, halt_out, cls_out);
}

// Round 11
// 3927.555 us; speedup vs baseline: 1.2101x; 1.0298x over previous
//
#include <hip/hip_runtime.h>
#include <hip/hip_bf16.h>
#include <math.h>

#define L_SEQ 24
#define DT 1024
#define DM 256
#define NLAYER 12
#define NHEAD 4
#define HDIM 64
#define FFND 1024
#define NCLS 2
#define NBATCH 2048
#define NTOK (NBATCH*L_SEQ)   // 49152

typedef float f32x4 __attribute__((ext_vector_type(4)));
typedef __bf16 bf16x4 __attribute__((ext_vector_type(4)));
typedef __bf16 bf16x8 __attribute__((ext_vector_type(8)));

#define GLDS16(gp, lp) __builtin_amdgcn_global_load_lds((const __attribute__((address_space(1))) void*)(gp), (__attribute__((address_space(3))) void*)(lp), 16, 0, 0)
#define VMWAIT(N) asm volatile("s_waitcnt vmcnt(" #N ")" ::: "memory")
#define LGKM0()   asm volatile("s_waitcnt lgkmcnt(0)" ::: "memory")

__device__ inline float wred_sum(float v){
#pragma unroll
  for (int o = 32; o > 0; o >>= 1) v += __shfl_xor(v, o);
  return v;
}
__device__ inline float wred_max(float v){
#pragma unroll
  for (int o = 32; o > 0; o >>= 1) v = fmaxf(v, __shfl_xor(v, o));
  return v;
}

// ---- [R][32]-bf16 LDS tiles, BK=32: linear glds dest + global-source XOR swizzle ----
__device__ __forceinline__ void stage16x32(const __bf16* __restrict__ g, int ldk, int k0,
                                           __bf16* ldsbase, int lane, int rowbase){
  int r = rowbase + (lane >> 2);
  int cs = (lane & 3) ^ ((lane >> 3) & 3);
  GLDS16(g + (size_t)r*ldk + k0 + cs*8, ldsbase);
}
__device__ __forceinline__ bf16x8 frag32(const __bf16* tile, int row, int lane){
  int p = (lane >> 4) ^ ((row >> 1) & 3);
  return *(const bf16x8*)(tile + (row << 5) + (p << 3));
}

// XCD-aware swizzle (T1). Requires gridDim.x % 8 == 0.
__device__ __forceinline__ int xcd_work(){
  int nwg = gridDim.x, bid = blockIdx.x;
  return (bid & 7) * (nwg >> 3) + (bid >> 3);
}

// ---------------- merged weight fp32 -> bf16 convert ----------------
__global__ void cvt_all_kernel(const float* __restrict__ a0, __bf16* __restrict__ o0, int n0,
                               const float* __restrict__ a1, __bf16* __restrict__ o1, int n1,
                               const float* __restrict__ a2, __bf16* __restrict__ o2, int n2,
                               const float* __restrict__ a3, __bf16* __restrict__ o3, int n3,
                               const float* __restrict__ a4, __bf16* __restrict__ o4, int n4){
  int stride = gridDim.x * blockDim.x;
  int i0 = blockIdx.x * blockDim.x + threadIdx.x;
  const float* as[5] = {a0,a1,a2,a3,a4};
  __bf16* os[5] = {o0,o1,o2,o3,o4};
  int ns[5] = {n0,n1,n2,n3,n4};
#pragma unroll
  for (int s = 0; s < 5; s++){
    const float* a = as[s]; __bf16* o = os[s]; int n = ns[s];
    for (int i = i0; i < n; i += stride){
      float4 v = ((const float4*)a)[i];
      bf16x4 ov;
      ov[0] = (__bf16)v.x; ov[1] = (__bf16)v.y; ov[2] = (__bf16)v.z; ov[3] = (__bf16)v.w;
      ((bf16x4*)o)[i] = ov;
    }
  }
}

// ---------------- LN over 1024 (block per row) ----------------
__global__ __launch_bounds__(256) void ln1024_kernel(
    const float* __restrict__ in, const float* __restrict__ g, const float* __restrict__ bb,
    __bf16* __restrict__ out){
  int row = blockIdx.x;
  int tid = threadIdx.x, wid = tid >> 6, lane = tid & 63;
  float4 x = ((const float4*)(in + (size_t)row*DT))[tid];
  float s = x.x + x.y + x.z + x.w;
  float q = x.x*x.x + x.y*x.y + x.z*x.z + x.w*x.w;
  s = wred_sum(s); q = wred_sum(q);
  __shared__ float red[8];
  if (lane == 0){ red[wid] = s; red[4+wid] = q; }
  __syncthreads();
  s = red[0]+red[1]+red[2]+red[3];
  q = red[4]+red[5]+red[6]+red[7];
  float mean = s * (1.f/DT);
  float rstd = rsqrtf(q*(1.f/DT) - mean*mean + 1e-5f);
  float4 gv = ((const float4*)g)[tid], bv = ((const float4*)bb)[tid];
  bf16x4 o;
  o[0] = (__bf16)((x.x-mean)*rstd*gv.x + bv.x);
  o[1] = (__bf16)((x.y-mean)*rstd*gv.y + bv.y);
  o[2] = (__bf16)((x.z-mean)*rstd*gv.z + bv.z);
  o[3] = (__bf16)((x.w-mean)*rstd*gv.w + bv.w);
  ((bf16x4*)(out + (size_t)row*DT))[tid] = o;
}

// ---------------- RoPE + pre-LN + layer0 LN1 (wave per row) ----------------
__global__ __launch_bounds__(256) void rope_preln_kernel(
    float* __restrict__ z, const float* __restrict__ cosc, const float* __restrict__ sinc,
    const float* __restrict__ g, const float* __restrict__ bb,
    const float* __restrict__ g1, const float* __restrict__ b1, __bf16* __restrict__ xnb){
  int row = blockIdx.x*4 + (threadIdx.x >> 6);
  int lane = threadIdx.x & 63;
  int l = row % L_SEQ;
  float4 x = ((const float4*)(z + (size_t)row*DM))[lane];
  float4 p;
  p.x = __shfl_xor(x.x, 32); p.y = __shfl_xor(x.y, 32);
  p.z = __shfl_xor(x.z, 32); p.w = __shfl_xor(x.w, 32);
  float sgn = (lane < 32) ? -1.f : 1.f;
  float4 c = ((const float4*)(cosc + l*DM))[lane];
  float4 sn = ((const float4*)(sinc + l*DM))[lane];
  float4 xr;
  xr.x = x.x*c.x + sgn*p.x*sn.x;
  xr.y = x.y*c.y + sgn*p.y*sn.y;
  xr.z = x.z*c.z + sgn*p.z*sn.z;
  xr.w = x.w*c.w + sgn*p.w*sn.w;
  float s = wred_sum(xr.x + xr.y + xr.z + xr.w);
  float q = wred_sum(xr.x*xr.x + xr.y*xr.y + xr.z*xr.z + xr.w*xr.w);
  float mean = s * (1.f/DM);
  float rstd = rsqrtf(q*(1.f/DM) - mean*mean + 1e-5f);
  float4 gv = ((const float4*)g)[lane], bv = ((const float4*)bb)[lane];
  float4 y;
  y.x = (xr.x-mean)*rstd*gv.x + bv.x;
  y.y = (xr.y-mean)*rstd*gv.y + bv.y;
  y.z = (xr.z-mean)*rstd*gv.z + bv.z;
  y.w = (xr.w-mean)*rstd*gv.w + bv.w;
  ((float4*)(z + (size_t)row*DM))[lane] = y;
  float s2 = wred_sum(y.x + y.y + y.z + y.w);
  float q2 = wred_sum(y.x*y.x + y.y*y.y + y.z*y.z + y.w*y.w);
  float mean2 = s2 * (1.f/DM);
  float rstd2 = rsqrtf(q2*(1.f/DM) - mean2*mean2 + 1e-5f);
  float4 g1v = ((const float4*)g1)[lane], b1v = ((const float4*)b1)[lane];
  bf16x4 o;
  o[0] = (__bf16)((y.x-mean2)*rstd2*g1v.x + b1v.x);
  o[1] = (__bf16)((y.y-mean2)*rstd2*g1v.y + b1v.y);
  o[2] = (__bf16)((y.z-mean2)*rstd2*g1v.z + b1v.z);
  o[3] = (__bf16)((y.w-mean2)*rstd2*g1v.w + b1v.w);
  ((bf16x4*)(xnb + (size_t)row*DM))[lane] = o;
}

// ---------------- GEMM 256x256, 8 waves, BK=32, counted-vmcnt (proj/qkv) ----------------
template<int MODE, int K>
__global__ __launch_bounds__(512) void gemm512_kernel(
    const __bf16* __restrict__ A, const __bf16* __restrict__ W,
    const float* __restrict__ bias,
    float* __restrict__ Cf, __bf16* __restrict__ Cb,
    int N, int nt){
  __shared__ __align__(16) __bf16 As[2][256*32];
  __shared__ __align__(16) __bf16 Bs[2][256*32];
  int work = xcd_work();
  int bm = work / nt, bn = work % nt;
  int wid = threadIdx.x >> 6, lane = threadIdx.x & 63;
  int wr = wid >> 1, wc = wid & 1;
  int li = lane & 15, g4 = (lane >> 4) << 2;
  f32x4 acc[8][4] = {};
  const __bf16* ga = A + (size_t)bm*256*K;
  const __bf16* gb = W + (size_t)bn*256*K;
  const int NT = K/32;
  auto STAGE = [&](int b, int t){
    int k0 = t*32;
    if (wid < 4){
#pragma unroll
      for (int j = 0; j < 4; j++){ int r = (wid*4 + j)*16; stage16x32(ga, K, k0, &As[b][r<<5], lane, r); }
    } else {
#pragma unroll
      for (int j = 0; j < 4; j++){ int r = ((wid-4)*4 + j)*16; stage16x32(gb, K, k0, &Bs[b][r<<5], lane, r); }
    }
  };
  STAGE(0, 0);
  STAGE(1, 1);
  int cur = 0;
  for (int t = 0; t < NT; t++){
    if (t + 1 < NT) { VMWAIT(4); } else { VMWAIT(0); }
    __builtin_amdgcn_s_barrier();
    bf16x8 xf[4], wf[8];
#pragma unroll
    for (int mi = 0; mi < 4; mi++) xf[mi] = frag32(As[cur], wr*64 + mi*16 + li, lane);
#pragma unroll
    for (int ni = 0; ni < 8; ni++) wf[ni] = frag32(Bs[cur], wc*128 + ni*16 + li, lane);
    LGKM0();
    __builtin_amdgcn_sched_barrier(0);
    __builtin_amdgcn_s_barrier();
    if (t + 2 < NT) STAGE(cur, t+2);
    __builtin_amdgcn_s_setprio(1);
#pragma unroll
    for (int ni = 0; ni < 8; ni++)
#pragma unroll
      for (int mi = 0; mi < 4; mi++)
        acc[ni][mi] = __builtin_amdgcn_mfma_f32_16x16x32_bf16(wf[ni], xf[mi], acc[ni][mi], 0, 0, 0);
    __builtin_amdgcn_s_setprio(0);
    cur ^= 1;
  }
#pragma unroll
  for (int mi = 0; mi < 4; mi++){
    int m = bm*256 + wr*64 + mi*16 + li;
#pragma unroll
    for (int ni = 0; ni < 8; ni++){
      int n = bn*256 + wc*128 + ni*16 + g4;
      f32x4 bv = *(const f32x4*)(bias + n);
      f32x4 o = acc[ni][mi] + bv;
      if (MODE == 0){
        *(f32x4*)(Cf + (size_t)m*N + n) = o;
      } else {
        bf16x4 ob;
        ob[0] = (__bf16)o[0]; ob[1] = (__bf16)o[1]; ob[2] = (__bf16)o[2]; ob[3] = (__bf16)o[3];
        *(bf16x4*)(Cb + (size_t)m*N + n) = ob;
      }
    }
  }
}

// ---------------- continuous-pipeline fused w12 GEMM + SwiGLU ----------------
// Grid 512 (= 2 blocks/CU exactly, one occupancy round). Each block processes 3
// consecutive tiles (T = work*3 + j; tile: bm=T>>3, bn=T&7; 256x128 dual-gemm)
// in ONE 24-step counted-vmcnt stream -- the glds pipeline never drains at tile
// boundaries. Bias loads hoisted to each tile's first step (old by use-time, so
// no implicit vmcnt(0) drain); stores/loads pinned with sched_barrier(0) so the
// wait-counts are exact: k0->20, k1->28, k2->12, else 4 (tail 0).
__global__ __launch_bounds__(512) void gemm_glu_kernel(
    const __bf16* __restrict__ A, const __bf16* __restrict__ W12,
    const float* __restrict__ bias, __bf16* __restrict__ H){
  __shared__ __align__(16) __bf16 As[2][256*32];
  __shared__ __align__(16) __bf16 B1s[2][128*32];
  __shared__ __align__(16) __bf16 B2s[2][128*32];
  const int K = 256;
  int work = xcd_work();
  int wid = threadIdx.x >> 6, lane = threadIdx.x & 63;
  int wr = wid >> 1, wc = wid & 1;
  int li = lane & 15, g4 = (lane >> 4) << 2;
  f32x4 acc1[4][4] = {}, acc2[4][4] = {};
  f32x4 B1v[4], B2v[4];
  auto STAGE = [&](int buf, int g){   // 4 glds per lane
    int T = work*3 + (g >> 3);
    int bmT = T >> 3, bnT = T & 7;
    int k0 = (g & 7)*32;
    const __bf16* ga  = A   + (size_t)bmT*256*K;
    const __bf16* gb1 = W12 + (size_t)bnT*128*K;
    const __bf16* gb2 = gb1 + (size_t)1024*K;
    if (wid < 4){
#pragma unroll
      for (int j = 0; j < 4; j++){ int r = (wid*4 + j)*16; stage16x32(ga, K, k0, &As[buf][r<<5], lane, r); }
    } else if (wid < 6){
#pragma unroll
      for (int j = 0; j < 4; j++){ int r = ((wid-4)*4 + j)*16; stage16x32(gb1, K, k0, &B1s[buf][r<<5], lane, r); }
    } else {
#pragma unroll
      for (int j = 0; j < 4; j++){ int r = ((wid-6)*4 + j)*16; stage16x32(gb2, K, k0, &B2s[buf][r<<5], lane, r); }
    }
  };
  STAGE(0, 0);
  STAGE(1, 1);
  int cur = 0;
  for (int g = 0; g < 24; g++){
    int k = g & 7;
    if (g == 23)      { VMWAIT(0); }
    else if (k == 0)  { if (g) { VMWAIT(20); } else { VMWAIT(4); } }
    else if (k == 1)  { if (g == 1) { VMWAIT(12); } else { VMWAIT(28); } }
    else if (k == 2)  { VMWAIT(12); }
    else              { VMWAIT(4); }
    __builtin_amdgcn_s_barrier();
    bf16x8 xf[4], w1f[4], w2f[4];
#pragma unroll
    for (int mi = 0; mi < 4; mi++) xf[mi] = frag32(As[cur], wr*64 + mi*16 + li, lane);
#pragma unroll
    for (int ni = 0; ni < 4; ni++){
      w1f[ni] = frag32(B1s[cur], wc*64 + ni*16 + li, lane);
      w2f[ni] = frag32(B2s[cur], wc*64 + ni*16 + li, lane);
    }
    LGKM0();
    __builtin_amdgcn_sched_barrier(0);
    __builtin_amdgcn_s_barrier();
    if (g + 2 < 24) STAGE(cur, g + 2);
    __builtin_amdgcn_sched_barrier(0);
    if (k == 0){
      int bnT = (work*3 + (g >> 3)) & 7;
#pragma unroll
      for (int ni = 0; ni < 4; ni++){
        int n = bnT*128 + wc*64 + ni*16 + g4;
        B1v[ni] = *(const f32x4*)(bias + n);
        B2v[ni] = *(const f32x4*)(bias + 1024 + n);
      }
      __builtin_amdgcn_sched_barrier(0);
    }
    __builtin_amdgcn_s_setprio(1);
#pragma unroll
    for (int ni = 0; ni < 4; ni++)
#pragma unroll
      for (int mi = 0; mi < 4; mi++){
        acc1[ni][mi] = __builtin_amdgcn_mfma_f32_16x16x32_bf16(w1f[ni], xf[mi], acc1[ni][mi], 0, 0, 0);
        acc2[ni][mi] = __builtin_amdgcn_mfma_f32_16x16x32_bf16(w2f[ni], xf[mi], acc2[ni][mi], 0, 0, 0);
      }
    __builtin_amdgcn_s_setprio(0);
    cur ^= 1;
    if (k == 7){
      __builtin_amdgcn_sched_barrier(0);
      int T = work*3 + (g >> 3);
      int bmT = T >> 3, bnT = T & 7;
#pragma unroll
      for (int mi = 0; mi < 4; mi++){
        int m = bmT*256 + wr*64 + mi*16 + li;
#pragma unroll
        for (int ni = 0; ni < 4; ni++){
          int n = bnT*128 + wc*64 + ni*16 + g4;
          bf16x4 ob;
#pragma unroll
          for (int r = 0; r < 4; r++){
            float v1 = acc1[ni][mi][r] + B1v[ni][r];
            float v2 = acc2[ni][mi][r] + B2v[ni][r];
            float sig = 1.f/(1.f + __expf(-v1));
            ob[r] = (__bf16)(v1*sig*v2);
          }
          *(bf16x4*)(H + (size_t)m*FFND + n) = ob;
          acc1[ni][mi] = (f32x4)(0.f);
          acc2[ni][mi] = (f32x4)(0.f);
        }
      }
      __builtin_amdgcn_sched_barrier(0);
    }
  }
}

// ---------------- GEMM 192x256 + residual + LayerNorm, 8 waves, grid 256 ----------------
// BN=256 = full row per block (needed for LN). M-tile 192 -> grid NTOK/192 = 256
// = exactly 1 block/CU (was 192 blocks = 0.75 CU utilization).
template<int K>
__global__ __launch_bounds__(512) void gemm_ln_kernel(
    const __bf16* __restrict__ A, const __bf16* __restrict__ W,
    const float* __restrict__ bias, float* __restrict__ z,
    const float* __restrict__ lng, const float* __restrict__ lnb,
    __bf16* __restrict__ outb, float* __restrict__ outf){
  __shared__ __align__(16) __bf16 As[2][192*32];
  __shared__ __align__(16) __bf16 Bs[2][256*32];
  __shared__ float redS[192][2], redQ[192][2];
  int bm = xcd_work();
  int wid = threadIdx.x >> 6, lane = threadIdx.x & 63;
  int wr = wid >> 1, wc = wid & 1;
  int li = lane & 15, g4 = (lane >> 4) << 2;
  f32x4 acc[8][3] = {};
  const __bf16* ga = A + (size_t)bm*192*K;
  const int NT = K/32;
  auto STAGE = [&](int b, int t){   // A-waves 3 glds, B-waves 4 glds
    int k0 = t*32;
    if (wid < 4){
#pragma unroll
      for (int j = 0; j < 3; j++){ int r = (wid*3 + j)*16; stage16x32(ga, K, k0, &As[b][r<<5], lane, r); }
    } else {
#pragma unroll
      for (int j = 0; j < 4; j++){ int r = ((wid-4)*4 + j)*16; stage16x32(W, K, k0, &Bs[b][r<<5], lane, r); }
    }
  };
  STAGE(0, 0);
  STAGE(1, 1);
  int cur = 0;
  for (int t = 0; t < NT; t++){
    if (t + 1 < NT) { VMWAIT(3); } else { VMWAIT(0); }
    __builtin_amdgcn_s_barrier();
    bf16x8 xf[3], wf[8];
#pragma unroll
    for (int mi = 0; mi < 3; mi++) xf[mi] = frag32(As[cur], wr*48 + mi*16 + li, lane);
#pragma unroll
    for (int ni = 0; ni < 8; ni++) wf[ni] = frag32(Bs[cur], wc*128 + ni*16 + li, lane);
    LGKM0();
    __builtin_amdgcn_sched_barrier(0);
    __builtin_amdgcn_s_barrier();
    if (t + 2 < NT) STAGE(cur, t+2);
    __builtin_amdgcn_s_setprio(1);
#pragma unroll
    for (int ni = 0; ni < 8; ni++)
#pragma unroll
      for (int mi = 0; mi < 3; mi++)
        acc[ni][mi] = __builtin_amdgcn_mfma_f32_16x16x32_bf16(wf[ni], xf[mi], acc[ni][mi], 0, 0, 0);
    __builtin_amdgcn_s_setprio(0);
    cur ^= 1;
  }
  float sA[3] = {}, qA[3] = {};
#pragma unroll
  for (int mi = 0; mi < 3; mi++){
    int m = bm*192 + wr*48 + mi*16 + li;
#pragma unroll
    for (int ni = 0; ni < 8; ni++){
      int n = wc*128 + ni*16 + g4;
      f32x4 zv = *(const f32x4*)(z + (size_t)m*DM + n);
      f32x4 bv = *(const f32x4*)(bias + n);
      f32x4 v = acc[ni][mi] + bv + zv;
      acc[ni][mi] = v;
      *(f32x4*)(z + (size_t)m*DM + n) = v;
#pragma unroll
      for (int r = 0; r < 4; r++){ sA[mi] += v[r]; qA[mi] += v[r]*v[r]; }
    }
  }
  __syncthreads();
#pragma unroll
  for (int mi = 0; mi < 3; mi++){
    float s = sA[mi], q = qA[mi];
    s += __shfl_xor(s, 16); q += __shfl_xor(q, 16);
    s += __shfl_xor(s, 32); q += __shfl_xor(q, 32);
    if (lane < 16){ redS[wr*48 + mi*16 + li][wc] = s; redQ[wr*48 + mi*16 + li][wc] = q; }
  }
  __syncthreads();
#pragma unroll
  for (int mi = 0; mi < 3; mi++){
    int ml = wr*48 + mi*16 + li;
    float s = redS[ml][0] + redS[ml][1];
    float q = redQ[ml][0] + redQ[ml][1];
    float mean = s * (1.f/DM);
    float rstd = rsqrtf(q*(1.f/DM) - mean*mean + 1e-5f);
    int m = bm*192 + ml;
#pragma unroll
    for (int ni = 0; ni < 8; ni++){
      int n = wc*128 + ni*16 + g4;
      f32x4 gv = *(const f32x4*)(lng + n);
      f32x4 bv = *(const f32x4*)(lnb + n);
      if (outb){
        bf16x4 o;
#pragma unroll
        for (int r = 0; r < 4; r++) o[r] = (__bf16)((acc[ni][mi][r] - mean)*rstd*gv[r] + bv[r]);
        *(bf16x4*)(outb + (size_t)m*DM + n) = o;
      } else {
        f32x4 o;
#pragma unroll
        for (int r = 0; r < 4; r++) o[r] = (acc[ni][mi][r] - mean)*rstd*gv[r] + bv[r];
        *(f32x4*)(outf + (size_t)m*DM + n) = o;
      }
    }
  }
}

// ---------------- attention: block per sequence, wave per head ----------------
__global__ __launch_bounds__(256) void attn_kernel(const __bf16* __restrict__ qkv, __bf16* __restrict__ ob){
  int b = blockIdx.x;
  int h = threadIdx.x >> 6, lane = threadIdx.x & 63;
  __shared__ __align__(16) __bf16 Qs[NHEAD][L_SEQ][HDIM];
  __shared__ __align__(16) __bf16 Ks[NHEAD][L_SEQ][HDIM];
  __shared__ float Ps[NHEAD][L_SEQ][L_SEQ];
  const __bf16* base = qkv + (size_t)b*L_SEQ*768;
  float V[L_SEQ];
#pragma unroll
  for (int t = 0; t < L_SEQ; t++){
    int sw = lane ^ ((t & 7) << 3);
    Qs[h][t][sw] = base[t*768 + h*64 + lane];
    Ks[h][t][sw] = base[t*768 + 256 + h*64 + lane];
    V[t] = (float)base[t*768 + 512 + h*64 + lane];
  }
  __syncthreads();
  for (int p = lane; p < L_SEQ*L_SEQ; p += 64){
    int q = p / L_SEQ, k = p - q*L_SEQ;
    if (k <= q){
      int qx = (q & 7) << 3, kx = (k & 7) << 3;
      const __bf16* qr = Qs[h][q];
      const __bf16* kr = Ks[h][k];
      float s = 0.f;
#pragma unroll
      for (int d = 0; d < 64; d += 4){
        bf16x4 qa = *(const bf16x4*)(qr + (d ^ qx));
        bf16x4 ka = *(const bf16x4*)(kr + (d ^ kx));
        s += (float)qa[0]*(float)ka[0] + (float)qa[1]*(float)ka[1]
           + (float)qa[2]*(float)ka[2] + (float)qa[3]*(float)ka[3];
      }
      Ps[h][q][k] = s * 0.125f;
    }
  }
  __syncthreads();
  for (int q = 0; q < L_SEQ; q++){
    float v = (lane <= q) ? Ps[h][q][lane] : -1e30f;
    float mx = wred_max(v);
    float e = (lane <= q) ? __expf(v - mx) : 0.f;
    float sm = wred_sum(e);
    if (lane < L_SEQ) Ps[h][q][lane] = e / sm;
  }
  __syncthreads();
  for (int q = 0; q < L_SEQ; q++){
    float o = 0.f;
    for (int k = 0; k <= q; k++) o += Ps[h][q][k] * V[k];
    ob[((size_t)b*L_SEQ + q)*DM + h*64 + lane] = (__bf16)o;
  }
}

// ---------------- per-token heads ----------------
__global__ __launch_bounds__(256) void heads_kernel(
    const float* __restrict__ z,
    const float* __restrict__ cls_w, const float* __restrict__ cls_b,
    const float* __restrict__ eg_w1, const float* __restrict__ eg_b1,
    const float* __restrict__ eg_w2, const float* __restrict__ eg_b2,
    const float* __restrict__ halt_w, const float* __restrict__ halt_b,
    float* __restrict__ halt_out, float* __restrict__ cls_out){
  int m = blockIdx.x*4 + (threadIdx.x >> 6);
  int lane = threadIdx.x & 63;
  int l = m % L_SEQ;
  float4 zv = ((const float4*)(z + (size_t)m*DM))[lane];
  float4 w0 = ((const float4*)(cls_w + ((size_t)l*2 + 0)*DM))[lane];
  float4 w1 = ((const float4*)(cls_w + ((size_t)l*2 + 1)*DM))[lane];
  float c0 = wred_sum(zv.x*w0.x + zv.y*w0.y + zv.z*w0.z + zv.w*w0.w) + cls_b[l*2 + 0];
  float c1 = wred_sum(zv.x*w1.x + zv.y*w1.y + zv.z*w1.z + zv.w*w1.w) + cls_b[l*2 + 1];
  float mx = fmaxf(c0, c1);
  float e0 = __expf(c0 - mx), e1 = __expf(c1 - mx);
  float inv = 1.f/(e0 + e1);
  float p0 = fminf(fmaxf(e0*inv, 1e-10f), 1.f);
  float p1 = fminf(fmaxf(e1*inv, 1e-10f), 1.f);
  float ent = -(p0*__logf(p0) + p1*__logf(p1));
  float entn = fminf(fmaxf(ent * 1.44269504f, 0.f), 1.f);
  const float4* wg = (const float4*)(eg_w1 + ((size_t)l*DM + 4*lane)*8);
  float hacc[8] = {};
#pragma unroll
  for (int dd = 0; dd < 4; dd++){
    float zd = (dd==0) ? zv.x : (dd==1) ? zv.y : (dd==2) ? zv.z : zv.w;
    float4 a = wg[dd*2], b = wg[dd*2 + 1];
    hacc[0] += zd*a.x; hacc[1] += zd*a.y; hacc[2] += zd*a.z; hacc[3] += zd*a.w;
    hacc[4] += zd*b.x; hacc[5] += zd*b.y; hacc[6] += zd*b.z; hacc[7] += zd*b.w;
  }
  float gin = 0.f;
#pragma unroll
  for (int j = 0; j < 8; j++){
    float hj = wred_sum(hacc[j]);
    hj = tanhf(hj + eg_b1[l*8 + j]);
    gin += hj * eg_w2[l*8 + j];
  }
  gin += eg_b2[l];
  float gate = 1.f/(1.f + __expf(-gin));
  float gated = entn * gate;
  const float* hw = halt_w + (size_t)l*257;
  float hp = zv.x*hw[4*lane] + zv.y*hw[4*lane+1] + zv.z*hw[4*lane+2] + zv.w*hw[4*lane+3];
  float hl = wred_sum(hp) + gated*hw[256] + halt_b[l];
  if (lane == 0) halt_out[m] = hl;
  if (lane < 2) cls_out[(size_t)m*2 + lane] = lane ? c1 : c0;
}

extern "C" void kernel_launch(void* const* d_in, const int* in_sizes, int n_in,
                              void* d_out, int out_size, void* d_ws, size_t ws_size,
                              hipStream_t stream){
  const float* teacher = (const float*)d_in[0];
  const float* in_ln_g = (const float*)d_in[1];
  const float* in_ln_b = (const float*)d_in[2];
  const float* proj_w  = (const float*)d_in[3];
  const float* proj_b  = (const float*)d_in[4];
  const float* cosc    = (const float*)d_in[5];
  const float* sinc    = (const float*)d_in[6];
  const float* pre_g   = (const float*)d_in[7];
  const float* pre_b   = (const float*)d_in[8];
  const float* l_ln1_g = (const float*)d_in[9];
  const float* l_ln1_b = (const float*)d_in[10];
  const float* l_inw   = (const float*)d_in[11];
  const float* l_inb   = (const float*)d_in[12];
  const float* l_outw  = (const float*)d_in[13];
  const float* l_outb  = (const float*)d_in[14];
  const float* l_ln2_g = (const float*)d_in[15];
  const float* l_ln2_b = (const float*)d_in[16];
  const float* l_w12   = (const float*)d_in[17];
  const float* l_b12   = (const float*)d_in[18];
  const float* l_w3    = (const float*)d_in[19];
  const float* l_b3    = (const float*)d_in[20];
  const float* post_g  = (const float*)d_in[21];
  const float* post_b  = (const float*)d_in[22];
  const float* eg_w1   = (const float*)d_in[23];
  const float* eg_b1   = (const float*)d_in[24];
  const float* eg_w2   = (const float*)d_in[25];
  const float* eg_b2   = (const float*)d_in[26];
  const float* halt_w  = (const float*)d_in[27];
  const float* halt_b  = (const float*)d_in[28];
  const float* cls_w   = (const float*)d_in[29];
  const float* cls_b   = (const float*)d_in[30];

  float* out = (float*)d_out;
  float* halt_out = out;
  float* cls_out  = out + NTOK;
  float* z_out    = out + NTOK + (size_t)NTOK*NCLS;

  char* ws = (char*)d_ws;
  size_t off = 0;
  auto alloc = [&](size_t bytes){ void* p = ws + off; off += (bytes + 255) & ~(size_t)255; return p; };
  float*  zbuf = (float*) alloc((size_t)NTOK*DM*4);
  __bf16* xnb  = (__bf16*)alloc((size_t)NTOK*DM*2);
  __bf16* qkvb = (__bf16*)alloc((size_t)NTOK*768*2);
  __bf16* obuf = (__bf16*)alloc((size_t)NTOK*DM*2);
  __bf16* bigb = (__bf16*)alloc((size_t)NTOK*1024*2);
  __bf16* w_proj = (__bf16*)alloc((size_t)262144*2);
  __bf16* w_in   = (__bf16*)alloc((size_t)2359296*2);
  __bf16* w_out  = (__bf16*)alloc((size_t)786432*2);
  __bf16* w_12   = (__bf16*)alloc((size_t)6291456*2);
  __bf16* w_3    = (__bf16*)alloc((size_t)3145728*2);

  cvt_all_kernel<<<2048, 256, 0, stream>>>(proj_w, w_proj, 262144/4,
                                           l_inw, w_in, 2359296/4,
                                           l_outw, w_out, 786432/4,
                                           l_w12, w_12, 6291456/4,
                                           l_w3, w_3, 3145728/4);

  ln1024_kernel<<<NTOK, 256, 0, stream>>>(teacher, in_ln_g, in_ln_b, bigb);
  gemm512_kernel<0, 1024><<<192, 512, 0, stream>>>(bigb, w_proj, proj_b, zbuf, nullptr, 256, 1);
  rope_preln_kernel<<<NTOK/4, 256, 0, stream>>>(zbuf, cosc, sinc, pre_g, pre_b, l_ln1_g, l_ln1_b, xnb);

  for (int i = 0; i < NLAYER; i++){
    gemm512_kernel<1, 256><<<576, 512, 0, stream>>>(xnb, w_in + (size_t)i*768*256, l_inb + i*768, nullptr, qkvb, 768, 3);
    attn_kernel<<<NBATCH, 256, 0, stream>>>(qkvb, obuf);
    gemm_ln_kernel<256><<<256, 512, 0, stream>>>(obuf, w_out + (size_t)i*256*256, l_outb + i*256,
                                                 zbuf, l_ln2_g + i*256, l_ln2_b + i*256, xnb, nullptr);
    gemm_glu_kernel<<<512, 512, 0, stream>>>(xnb, w_12 + (size_t)i*2048*256, l_b12 + i*2048, bigb);
    bool last = (i == NLAYER-1);
    gemm_ln_kernel<1024><<<256, 512, 0, stream>>>(bigb, w_3 + (size_t)i*256*1024, l_b3 + i*256,
                                                  zbuf,
                                                  last ? post_g : l_ln1_g + (i+1)*256,
                                                  last ? post_b : l_ln1_b + (i+1)*256,
                                                  last ? nullptr : xnb,
                                                  last ? z_out : nullptr);
  }

  heads_kernel<<<NTOK/4, 256, 0, stream>>>(z_out, cls_w, cls_b, eg_w1, eg_b1, eg_w2, eg_b2,
                                           halt_w, halt_b, halt_out, cls_out);
}

// Round 13
// 3882.716 us; speedup vs baseline: 1.2241x; 1.0115x over previous
//
#include <hip/hip_runtime.h>
#include <hip/hip_bf16.h>
#include <math.h>

#define L_SEQ 24
#define DT 1024
#define DM 256
#define NLAYER 12
#define NHEAD 4
#define HDIM 64
#define FFND 1024
#define NCLS 2
#define NBATCH 2048
#define NTOK (NBATCH*L_SEQ)   // 49152

typedef float f32x4 __attribute__((ext_vector_type(4)));
typedef __bf16 bf16x4 __attribute__((ext_vector_type(4)));
typedef __bf16 bf16x8 __attribute__((ext_vector_type(8)));

#define GLDS16(gp, lp) __builtin_amdgcn_global_load_lds((const __attribute__((address_space(1))) void*)(gp), (__attribute__((address_space(3))) void*)(lp), 16, 0, 0)
#define VMWAIT(N) asm volatile("s_waitcnt vmcnt(" #N ")" ::: "memory")
#define LGKM0()   asm volatile("s_waitcnt lgkmcnt(0)" ::: "memory")

__device__ inline float wred_sum(float v){
#pragma unroll
  for (int o = 32; o > 0; o >>= 1) v += __shfl_xor(v, o);
  return v;
}
__device__ inline float wred_max(float v){
#pragma unroll
  for (int o = 32; o > 0; o >>= 1) v = fmaxf(v, __shfl_xor(v, o));
  return v;
}

// ---- [R][32]-bf16 LDS tiles, BK=32: linear glds dest + global-source XOR swizzle ----
__device__ __forceinline__ void stage16x32(const __bf16* __restrict__ g, int ldk, int k0,
                                           __bf16* ldsbase, int lane, int rowbase){
  int r = rowbase + (lane >> 2);
  int cs = (lane & 3) ^ ((lane >> 3) & 3);
  GLDS16(g + (size_t)r*ldk + k0 + cs*8, ldsbase);
}
__device__ __forceinline__ bf16x8 frag32(const __bf16* tile, int row, int lane){
  int p = (lane >> 4) ^ ((row >> 1) & 3);
  return *(const bf16x8*)(tile + (row << 5) + (p << 3));
}

// XCD-aware swizzle (T1). Requires gridDim.x % 8 == 0.
__device__ __forceinline__ int xcd_work(){
  int nwg = gridDim.x, bid = blockIdx.x;
  return (bid & 7) * (nwg >> 3) + (bid >> 3);
}

// ---------------- merged weight fp32 -> bf16 convert ----------------
__global__ void cvt_all_kernel(const float* __restrict__ a0, __bf16* __restrict__ o0, int n0,
                               const float* __restrict__ a1, __bf16* __restrict__ o1, int n1,
                               const float* __restrict__ a2, __bf16* __restrict__ o2, int n2,
                               const float* __restrict__ a3, __bf16* __restrict__ o3, int n3,
                               const float* __restrict__ a4, __bf16* __restrict__ o4, int n4){
  int stride = gridDim.x * blockDim.x;
  int i0 = blockIdx.x * blockDim.x + threadIdx.x;
  const float* as[5] = {a0,a1,a2,a3,a4};
  __bf16* os[5] = {o0,o1,o2,o3,o4};
  int ns[5] = {n0,n1,n2,n3,n4};
#pragma unroll
  for (int s = 0; s < 5; s++){
    const float* a = as[s]; __bf16* o = os[s]; int n = ns[s];
    for (int i = i0; i < n; i += stride){
      float4 v = ((const float4*)a)[i];
      bf16x4 ov;
      ov[0] = (__bf16)v.x; ov[1] = (__bf16)v.y; ov[2] = (__bf16)v.z; ov[3] = (__bf16)v.w;
      ((bf16x4*)o)[i] = ov;
    }
  }
}

// ---------------- LN over 1024 (block per row) ----------------
__global__ __launch_bounds__(256) void ln1024_kernel(
    const float* __restrict__ in, const float* __restrict__ g, const float* __restrict__ bb,
    __bf16* __restrict__ out){
  int row = blockIdx.x;
  int tid = threadIdx.x, wid = tid >> 6, lane = tid & 63;
  float4 x = ((const float4*)(in + (size_t)row*DT))[tid];
  float s = x.x + x.y + x.z + x.w;
  float q = x.x*x.x + x.y*x.y + x.z*x.z + x.w*x.w;
  s = wred_sum(s); q = wred_sum(q);
  __shared__ float red[8];
  if (lane == 0){ red[wid] = s; red[4+wid] = q; }
  __syncthreads();
  s = red[0]+red[1]+red[2]+red[3];
  q = red[4]+red[5]+red[6]+red[7];
  float mean = s * (1.f/DT);
  float rstd = rsqrtf(q*(1.f/DT) - mean*mean + 1e-5f);
  float4 gv = ((const float4*)g)[tid], bv = ((const float4*)bb)[tid];
  bf16x4 o;
  o[0] = (__bf16)((x.x-mean)*rstd*gv.x + bv.x);
  o[1] = (__bf16)((x.y-mean)*rstd*gv.y + bv.y);
  o[2] = (__bf16)((x.z-mean)*rstd*gv.z + bv.z);
  o[3] = (__bf16)((x.w-mean)*rstd*gv.w + bv.w);
  ((bf16x4*)(out + (size_t)row*DT))[tid] = o;
}

// ---------------- RoPE + pre-LN + layer0 LN1 (wave per row) ----------------
__global__ __launch_bounds__(256) void rope_preln_kernel(
    float* __restrict__ z, const float* __restrict__ cosc, const float* __restrict__ sinc,
    const float* __restrict__ g, const float* __restrict__ bb,
    const float* __restrict__ g1, const float* __restrict__ b1, __bf16* __restrict__ xnb){
  int row = blockIdx.x*4 + (threadIdx.x >> 6);
  int lane = threadIdx.x & 63;
  int l = row % L_SEQ;
  float4 x = ((const float4*)(z + (size_t)row*DM))[lane];
  float4 p;
  p.x = __shfl_xor(x.x, 32); p.y = __shfl_xor(x.y, 32);
  p.z = __shfl_xor(x.z, 32); p.w = __shfl_xor(x.w, 32);
  float sgn = (lane < 32) ? -1.f : 1.f;
  float4 c = ((const float4*)(cosc + l*DM))[lane];
  float4 sn = ((const float4*)(sinc + l*DM))[lane];
  float4 xr;
  xr.x = x.x*c.x + sgn*p.x*sn.x;
  xr.y = x.y*c.y + sgn*p.y*sn.y;
  xr.z = x.z*c.z + sgn*p.z*sn.z;
  xr.w = x.w*c.w + sgn*p.w*sn.w;
  float s = wred_sum(xr.x + xr.y + xr.z + xr.w);
  float q = wred_sum(xr.x*xr.x + xr.y*xr.y + xr.z*xr.z + xr.w*xr.w);
  float mean = s * (1.f/DM);
  float rstd = rsqrtf(q*(1.f/DM) - mean*mean + 1e-5f);
  float4 gv = ((const float4*)g)[lane], bv = ((const float4*)bb)[lane];
  float4 y;
  y.x = (xr.x-mean)*rstd*gv.x + bv.x;
  y.y = (xr.y-mean)*rstd*gv.y + bv.y;
  y.z = (xr.z-mean)*rstd*gv.z + bv.z;
  y.w = (xr.w-mean)*rstd*gv.w + bv.w;
  ((float4*)(z + (size_t)row*DM))[lane] = y;
  float s2 = wred_sum(y.x + y.y + y.z + y.w);
  float q2 = wred_sum(y.x*y.x + y.y*y.y + y.z*y.z + y.w*y.w);
  float mean2 = s2 * (1.f/DM);
  float rstd2 = rsqrtf(q2*(1.f/DM) - mean2*mean2 + 1e-5f);
  float4 g1v = ((const float4*)g1)[lane], b1v = ((const float4*)b1)[lane];
  bf16x4 o;
  o[0] = (__bf16)((y.x-mean2)*rstd2*g1v.x + b1v.x);
  o[1] = (__bf16)((y.y-mean2)*rstd2*g1v.y + b1v.y);
  o[2] = (__bf16)((y.z-mean2)*rstd2*g1v.z + b1v.z);
  o[3] = (__bf16)((y.w-mean2)*rstd2*g1v.w + b1v.w);
  ((bf16x4*)(xnb + (size_t)row*DM))[lane] = o;
}

// ---------------- GEMM 256x256, 8 waves, BK=32, counted-vmcnt (proj/qkv) ----------------
template<int MODE, int K>
__global__ __launch_bounds__(512) void gemm512_kernel(
    const __bf16* __restrict__ A, const __bf16* __restrict__ W,
    const float* __restrict__ bias,
    float* __restrict__ Cf, __bf16* __restrict__ Cb,
    int N, int nt){
  __shared__ __align__(16) __bf16 As[2][256*32];
  __shared__ __align__(16) __bf16 Bs[2][256*32];
  int work = xcd_work();
  int bm = work / nt, bn = work % nt;
  int wid = threadIdx.x >> 6, lane = threadIdx.x & 63;
  int wr = wid >> 1, wc = wid & 1;
  int li = lane & 15, g4 = (lane >> 4) << 2;
  f32x4 acc[8][4] = {};
  const __bf16* ga = A + (size_t)bm*256*K;
  const __bf16* gb = W + (size_t)bn*256*K;
  const int NT = K/32;
  auto STAGE = [&](int b, int t){
    int k0 = t*32;
    if (wid < 4){
#pragma unroll
      for (int j = 0; j < 4; j++){ int r = (wid*4 + j)*16; stage16x32(ga, K, k0, &As[b][r<<5], lane, r); }
    } else {
#pragma unroll
      for (int j = 0; j < 4; j++){ int r = ((wid-4)*4 + j)*16; stage16x32(gb, K, k0, &Bs[b][r<<5], lane, r); }
    }
  };
  STAGE(0, 0);
  STAGE(1, 1);
  int cur = 0;
  for (int t = 0; t < NT; t++){
    if (t + 1 < NT) { VMWAIT(4); } else { VMWAIT(0); }
    __builtin_amdgcn_s_barrier();
    bf16x8 xf[4], wf[8];
#pragma unroll
    for (int mi = 0; mi < 4; mi++) xf[mi] = frag32(As[cur], wr*64 + mi*16 + li, lane);
#pragma unroll
    for (int ni = 0; ni < 8; ni++) wf[ni] = frag32(Bs[cur], wc*128 + ni*16 + li, lane);
    LGKM0();
    __builtin_amdgcn_sched_barrier(0);
    __builtin_amdgcn_s_barrier();
    if (t + 2 < NT) STAGE(cur, t+2);
    __builtin_amdgcn_s_setprio(1);
#pragma unroll
    for (int ni = 0; ni < 8; ni++)
#pragma unroll
      for (int mi = 0; mi < 4; mi++)
        acc[ni][mi] = __builtin_amdgcn_mfma_f32_16x16x32_bf16(wf[ni], xf[mi], acc[ni][mi], 0, 0, 0);
    __builtin_amdgcn_s_setprio(0);
    cur ^= 1;
  }
#pragma unroll
  for (int mi = 0; mi < 4; mi++){
    int m = bm*256 + wr*64 + mi*16 + li;
#pragma unroll
    for (int ni = 0; ni < 8; ni++){
      int n = bn*256 + wc*128 + ni*16 + g4;
      f32x4 bv = *(const f32x4*)(bias + n);
      f32x4 o = acc[ni][mi] + bv;
      if (MODE == 0){
        *(f32x4*)(Cf + (size_t)m*N + n) = o;
      } else {
        bf16x4 ob;
        ob[0] = (__bf16)o[0]; ob[1] = (__bf16)o[1]; ob[2] = (__bf16)o[2]; ob[3] = (__bf16)o[3];
        *(bf16x4*)(Cb + (size_t)m*N + n) = ob;
      }
    }
  }
}

// ---------------- continuous-pipeline fused w12 GEMM + SwiGLU ----------------
// Grid 512 (= 2 blocks/CU, one occupancy round); 3 tiles per block in one
// 24-step counted-vmcnt stream (pipeline never drains at tile boundaries).
__global__ __launch_bounds__(512) void gemm_glu_kernel(
    const __bf16* __restrict__ A, const __bf16* __restrict__ W12,
    const float* __restrict__ bias, __bf16* __restrict__ H){
  __shared__ __align__(16) __bf16 As[2][256*32];
  __shared__ __align__(16) __bf16 B1s[2][128*32];
  __shared__ __align__(16) __bf16 B2s[2][128*32];
  const int K = 256;
  int work = xcd_work();
  int wid = threadIdx.x >> 6, lane = threadIdx.x & 63;
  int wr = wid >> 1, wc = wid & 1;
  int li = lane & 15, g4 = (lane >> 4) << 2;
  f32x4 acc1[4][4] = {}, acc2[4][4] = {};
  f32x4 B1v[4], B2v[4];
  auto STAGE = [&](int buf, int g){   // 4 glds per lane
    int T = work*3 + (g >> 3);
    int bmT = T >> 3, bnT = T & 7;
    int k0 = (g & 7)*32;
    const __bf16* ga  = A   + (size_t)bmT*256*K;
    const __bf16* gb1 = W12 + (size_t)bnT*128*K;
    const __bf16* gb2 = gb1 + (size_t)1024*K;
    if (wid < 4){
#pragma unroll
      for (int j = 0; j < 4; j++){ int r = (wid*4 + j)*16; stage16x32(ga, K, k0, &As[buf][r<<5], lane, r); }
    } else if (wid < 6){
#pragma unroll
      for (int j = 0; j < 4; j++){ int r = ((wid-4)*4 + j)*16; stage16x32(gb1, K, k0, &B1s[buf][r<<5], lane, r); }
    } else {
#pragma unroll
      for (int j = 0; j < 4; j++){ int r = ((wid-6)*4 + j)*16; stage16x32(gb2, K, k0, &B2s[buf][r<<5], lane, r); }
    }
  };
  STAGE(0, 0);
  STAGE(1, 1);
  int cur = 0;
  for (int g = 0; g < 24; g++){
    int k = g & 7;
    if (g == 23)      { VMWAIT(0); }
    else if (k == 0)  { if (g) { VMWAIT(20); } else { VMWAIT(4); } }
    else if (k == 1)  { if (g == 1) { VMWAIT(12); } else { VMWAIT(28); } }
    else if (k == 2)  { VMWAIT(12); }
    else              { VMWAIT(4); }
    __builtin_amdgcn_s_barrier();
    bf16x8 xf[4], w1f[4], w2f[4];
#pragma unroll
    for (int mi = 0; mi < 4; mi++) xf[mi] = frag32(As[cur], wr*64 + mi*16 + li, lane);
#pragma unroll
    for (int ni = 0; ni < 4; ni++){
      w1f[ni] = frag32(B1s[cur], wc*64 + ni*16 + li, lane);
      w2f[ni] = frag32(B2s[cur], wc*64 + ni*16 + li, lane);
    }
    LGKM0();
    __builtin_amdgcn_sched_barrier(0);
    __builtin_amdgcn_s_barrier();
    if (g + 2 < 24) STAGE(cur, g + 2);
    __builtin_amdgcn_sched_barrier(0);
    if (k == 0){
      int bnT = (work*3 + (g >> 3)) & 7;
#pragma unroll
      for (int ni = 0; ni < 4; ni++){
        int n = bnT*128 + wc*64 + ni*16 + g4;
        B1v[ni] = *(const f32x4*)(bias + n);
        B2v[ni] = *(const f32x4*)(bias + 1024 + n);
      }
      __builtin_amdgcn_sched_barrier(0);
    }
    __builtin_amdgcn_s_setprio(1);
#pragma unroll
    for (int ni = 0; ni < 4; ni++)
#pragma unroll
      for (int mi = 0; mi < 4; mi++){
        acc1[ni][mi] = __builtin_amdgcn_mfma_f32_16x16x32_bf16(w1f[ni], xf[mi], acc1[ni][mi], 0, 0, 0);
        acc2[ni][mi] = __builtin_amdgcn_mfma_f32_16x16x32_bf16(w2f[ni], xf[mi], acc2[ni][mi], 0, 0, 0);
      }
    __builtin_amdgcn_s_setprio(0);
    cur ^= 1;
    if (k == 7){
      __builtin_amdgcn_sched_barrier(0);
      int T = work*3 + (g >> 3);
      int bmT = T >> 3, bnT = T & 7;
#pragma unroll
      for (int mi = 0; mi < 4; mi++){
        int m = bmT*256 + wr*64 + mi*16 + li;
#pragma unroll
        for (int ni = 0; ni < 4; ni++){
          int n = bnT*128 + wc*64 + ni*16 + g4;
          bf16x4 ob;
#pragma unroll
          for (int r = 0; r < 4; r++){
            float v1 = acc1[ni][mi][r] + B1v[ni][r];
            float v2 = acc2[ni][mi][r] + B2v[ni][r];
            float sig = 1.f/(1.f + __expf(-v1));
            ob[r] = (__bf16)(v1*sig*v2);
          }
          *(bf16x4*)(H + (size_t)m*FFND + n) = ob;
          acc1[ni][mi] = (f32x4)(0.f);
          acc2[ni][mi] = (f32x4)(0.f);
        }
      }
      __builtin_amdgcn_sched_barrier(0);
    }
  }
}

// ---------------- GEMM 192x256 + residual + LayerNorm, 8 waves, grid 256 ----------------
template<int K>
__global__ __launch_bounds__(512) void gemm_ln_kernel(
    const __bf16* __restrict__ A, const __bf16* __restrict__ W,
    const float* __restrict__ bias, float* __restrict__ z,
    const float* __restrict__ lng, const float* __restrict__ lnb,
    __bf16* __restrict__ outb, float* __restrict__ outf){
  __shared__ __align__(16) __bf16 As[2][192*32];
  __shared__ __align__(16) __bf16 Bs[2][256*32];
  __shared__ float redS[192][2], redQ[192][2];
  int bm = xcd_work();
  int wid = threadIdx.x >> 6, lane = threadIdx.x & 63;
  int wr = wid >> 1, wc = wid & 1;
  int li = lane & 15, g4 = (lane >> 4) << 2;
  f32x4 acc[8][3] = {};
  const __bf16* ga = A + (size_t)bm*192*K;
  const int NT = K/32;
  auto STAGE = [&](int b, int t){   // A-waves 3 glds, B-waves 4 glds
    int k0 = t*32;
    if (wid < 4){
#pragma unroll
      for (int j = 0; j < 3; j++){ int r = (wid*3 + j)*16; stage16x32(ga, K, k0, &As[b][r<<5], lane, r); }
    } else {
#pragma unroll
      for (int j = 0; j < 4; j++){ int r = ((wid-4)*4 + j)*16; stage16x32(W, K, k0, &Bs[b][r<<5], lane, r); }
    }
  };
  STAGE(0, 0);
  STAGE(1, 1);
  int cur = 0;
  for (int t = 0; t < NT; t++){
    if (t + 1 < NT) { if (wid < 4) { VMWAIT(3); } else { VMWAIT(4); } } else { VMWAIT(0); }
    __builtin_amdgcn_s_barrier();
    bf16x8 xf[3], wf[8];
#pragma unroll
    for (int mi = 0; mi < 3; mi++) xf[mi] = frag32(As[cur], wr*48 + mi*16 + li, lane);
#pragma unroll
    for (int ni = 0; ni < 8; ni++) wf[ni] = frag32(Bs[cur], wc*128 + ni*16 + li, lane);
    LGKM0();
    __builtin_amdgcn_sched_barrier(0);
    __builtin_amdgcn_s_barrier();
    if (t + 2 < NT) STAGE(cur, t+2);
    __builtin_amdgcn_s_setprio(1);
#pragma unroll
    for (int ni = 0; ni < 8; ni++)
#pragma unroll
      for (int mi = 0; mi < 3; mi++)
        acc[ni][mi] = __builtin_amdgcn_mfma_f32_16x16x32_bf16(wf[ni], xf[mi], acc[ni][mi], 0, 0, 0);
    __builtin_amdgcn_s_setprio(0);
    cur ^= 1;
  }
  float sA[3] = {}, qA[3] = {};
#pragma unroll
  for (int mi = 0; mi < 3; mi++){
    int m = bm*192 + wr*48 + mi*16 + li;
#pragma unroll
    for (int ni = 0; ni < 8; ni++){
      int n = wc*128 + ni*16 + g4;
      f32x4 zv = *(const f32x4*)(z + (size_t)m*DM + n);
      f32x4 bv = *(const f32x4*)(bias + n);
      f32x4 v = acc[ni][mi] + bv + zv;
      acc[ni][mi] = v;
      *(f32x4*)(z + (size_t)m*DM + n) = v;
#pragma unroll
      for (int r = 0; r < 4; r++){ sA[mi] += v[r]; qA[mi] += v[r]*v[r]; }
    }
  }
  __syncthreads();
#pragma unroll
  for (int mi = 0; mi < 3; mi++){
    float s = sA[mi], q = qA[mi];
    s += __shfl_xor(s, 16); q += __shfl_xor(q, 16);
    s += __shfl_xor(s, 32); q += __shfl_xor(q, 32);
    if (lane < 16){ redS[wr*48 + mi*16 + li][wc] = s; redQ[wr*48 + mi*16 + li][wc] = q; }
  }
  __syncthreads();
#pragma unroll
  for (int mi = 0; mi < 3; mi++){
    int ml = wr*48 + mi*16 + li;
    float s = redS[ml][0] + redS[ml][1];
    float q = redQ[ml][0] + redQ[ml][1];
    float mean = s * (1.f/DM);
    float rstd = rsqrtf(q*(1.f/DM) - mean*mean + 1e-5f);
    int m = bm*192 + ml;
#pragma unroll
    for (int ni = 0; ni < 8; ni++){
      int n = wc*128 + ni*16 + g4;
      f32x4 gv = *(const f32x4*)(lng + n);
      f32x4 bv = *(const f32x4*)(lnb + n);
      if (outb){
        bf16x4 o;
#pragma unroll
        for (int r = 0; r < 4; r++) o[r] = (__bf16)((acc[ni][mi][r] - mean)*rstd*gv[r] + bv[r]);
        *(bf16x4*)(outb + (size_t)m*DM + n) = o;
      } else {
        f32x4 o;
#pragma unroll
        for (int r = 0; r < 4; r++) o[r] = (acc[ni][mi][r] - mean)*rstd*gv[r] + bv[r];
        *(f32x4*)(outf + (size_t)m*DM + n) = o;
      }
    }
  }
}

// ---------------- attention: block per sequence, wave per head (vectorized loads) -------
__global__ __launch_bounds__(256) void attn_kernel(const __bf16* __restrict__ qkv, __bf16* __restrict__ ob){
  int b = blockIdx.x;
  int h = threadIdx.x >> 6, lane = threadIdx.x & 63;
  __shared__ __align__(16) __bf16 Qs[NHEAD][L_SEQ][HDIM];
  __shared__ __align__(16) __bf16 Ks[NHEAD][L_SEQ][HDIM];
  __shared__ float Ps[NHEAD][L_SEQ][L_SEQ];
  const __bf16* base = qkv + (size_t)b*L_SEQ*768;
  // vectorized Q/K staging: 6 iters x (4 rows x 16 quads); swizzle keeps 4-contig
#pragma unroll
  for (int i = 0; i < 6; i++){
    int gq = i*64 + lane;
    int t = gq >> 4, c4 = (gq & 15) << 2;
    int sw = c4 ^ ((t & 7) << 3);
    *(bf16x4*)&Qs[h][t][sw] = *(const bf16x4*)(base + t*768 + h*64 + c4);
    *(bf16x4*)&Ks[h][t][sw] = *(const bf16x4*)(base + t*768 + 256 + h*64 + c4);
  }
  float V[L_SEQ];
#pragma unroll
  for (int t = 0; t < L_SEQ; t++) V[t] = (float)base[t*768 + 512 + h*64 + lane];
  __syncthreads();
  for (int p = lane; p < L_SEQ*L_SEQ; p += 64){
    int q = p / L_SEQ, k = p - q*L_SEQ;
    if (k <= q){
      int qx = (q & 7) << 3, kx = (k & 7) << 3;
      const __bf16* qr = Qs[h][q];
      const __bf16* kr = Ks[h][k];
      float s = 0.f;
#pragma unroll
      for (int d = 0; d < 64; d += 4){
        bf16x4 qa = *(const bf16x4*)(qr + (d ^ qx));
        bf16x4 ka = *(const bf16x4*)(kr + (d ^ kx));
        s += (float)qa[0]*(float)ka[0] + (float)qa[1]*(float)ka[1]
           + (float)qa[2]*(float)ka[2] + (float)qa[3]*(float)ka[3];
      }
      Ps[h][q][k] = s * 0.125f;
    }
  }
  __syncthreads();
  for (int q = 0; q < L_SEQ; q++){
    float v = (lane <= q) ? Ps[h][q][lane] : -1e30f;
    float mx = wred_max(v);
    float e = (lane <= q) ? __expf(v - mx) : 0.f;
    float sm = wred_sum(e);
    if (lane < L_SEQ) Ps[h][q][lane] = e / sm;
  }
  __syncthreads();
  for (int q = 0; q < L_SEQ; q++){
    float o = 0.f;
    for (int k = 0; k <= q; k++) o += Ps[h][q][k] * V[k];
    ob[((size_t)b*L_SEQ + q)*DM + h*64 + lane] = (__bf16)o;
  }
}

// ---------------- per-token heads ----------------
__global__ __launch_bounds__(256) void heads_kernel(
    const float* __restrict__ z,
    const float* __restrict__ cls_w, const float* __restrict__ cls_b,
    const float* __restrict__ eg_w1, const float* __restrict__ eg_b1,
    const float* __restrict__ eg_w2, const float* __restrict__ eg_b2,
    const float* __restrict__ halt_w, const float* __restrict__ halt_b,
    float* __restrict__ halt_out, float* __restrict__ cls_out){
  int m = blockIdx.x*4 + (threadIdx.x >> 6);
  int lane = threadIdx.x & 63;
  int l = m % L_SEQ;
  float4 zv = ((const float4*)(z + (size_t)m*DM))[lane];
  float4 w0 = ((const float4*)(cls_w + ((size_t)l*2 + 0)*DM))[lane];
  float4 w1 = ((const float4*)(cls_w + ((size_t)l*2 + 1)*DM))[lane];
  float c0 = wred_sum(zv.x*w0.x + zv.y*w0.y + zv.z*w0.z + zv.w*w0.w) + cls_b[l*2 + 0];
  float c1 = wred_sum(zv.x*w1.x + zv.y*w1.y + zv.z*w1.z + zv.w*w1.w) + cls_b[l*2 + 1];
  float mx = fmaxf(c0, c1);
  float e0 = __expf(c0 - mx), e1 = __expf(c1 - mx);
  float inv = 1.f/(e0 + e1);
  float p0 = fminf(fmaxf(e0*inv, 1e-10f), 1.f);
  float p1 = fminf(fmaxf(e1*inv, 1e-10f), 1.f);
  float ent = -(p0*__logf(p0) + p1*__logf(p1));
  float entn = fminf(fmaxf(ent * 1.44269504f, 0.f), 1.f);
  const float4* wg = (const float4*)(eg_w1 + ((size_t)l*DM + 4*lane)*8);
  float hacc[8] = {};
#pragma unroll
  for (int dd = 0; dd < 4; dd++){
    float zd = (dd==0) ? zv.x : (dd==1) ? zv.y : (dd==2) ? zv.z : zv.w;
    float4 a = wg[dd*2], b = wg[dd*2 + 1];
    hacc[0] += zd*a.x; hacc[1] += zd*a.y; hacc[2] += zd*a.z; hacc[3] += zd*a.w;
    hacc[4] += zd*b.x; hacc[5] += zd*b.y; hacc[6] += zd*b.z; hacc[7] += zd*b.w;
  }
  float gin = 0.f;
#pragma unroll
  for (int j = 0; j < 8; j++){
    float hj = wred_sum(hacc[j]);
    hj = tanhf(hj + eg_b1[l*8 + j]);
    gin += hj * eg_w2[l*8 + j];
  }
  gin += eg_b2[l];
  float gate = 1.f/(1.f + __expf(-gin));
  float gated = entn * gate;
  const float* hw = halt_w + (size_t)l*257;
  float hp = zv.x*hw[4*lane] + zv.y*hw[4*lane+1] + zv.z*hw[4*lane+2] + zv.w*hw[4*lane+3];
  float hl = wred_sum(hp) + gated*hw[256] + halt_b[l];
  if (lane == 0) halt_out[m] = hl;
  if (lane < 2) cls_out[(size_t)m*2 + lane] = lane ? c1 : c0;
}

extern "C" void kernel_launch(void* const* d_in, const int* in_sizes, int n_in,
                              void* d_out, int out_size, void* d_ws, size_t ws_size,
                              hipStream_t stream){
  const float* teacher = (const float*)d_in[0];
  const float* in_ln_g = (const float*)d_in[1];
  const float* in_ln_b = (const float*)d_in[2];
  const float* proj_w  = (const float*)d_in[3];
  const float* proj_b  = (const float*)d_in[4];
  const float* cosc    = (const float*)d_in[5];
  const float* sinc    = (const float*)d_in[6];
  const float* pre_g   = (const float*)d_in[7];
  const float* pre_b   = (const float*)d_in[8];
  const float* l_ln1_g = (const float*)d_in[9];
  const float* l_ln1_b = (const float*)d_in[10];
  const float* l_inw   = (const float*)d_in[11];
  const float* l_inb   = (const float*)d_in[12];
  const float* l_outw  = (const float*)d_in[13];
  const float* l_outb  = (const float*)d_in[14];
  const float* l_ln2_g = (const float*)d_in[15];
  const float* l_ln2_b = (const float*)d_in[16];
  const float* l_w12   = (const float*)d_in[17];
  const float* l_b12   = (const float*)d_in[18];
  const float* l_w3    = (const float*)d_in[19];
  const float* l_b3    = (const float*)d_in[20];
  const float* post_g  = (const float*)d_in[21];
  const float* post_b  = (const float*)d_in[22];
  const float* eg_w1   = (const float*)d_in[23];
  const float* eg_b1   = (const float*)d_in[24];
  const float* eg_w2   = (const float*)d_in[25];
  const float* eg_b2   = (const float*)d_in[26];
  const float* halt_w  = (const float*)d_in[27];
  const float* halt_b  = (const float*)d_in[28];
  const float* cls_w   = (const float*)d_in[29];
  const float* cls_b   = (const float*)d_in[30];

  float* out = (float*)d_out;
  float* halt_out = out;
  float* cls_out  = out + NTOK;
  float* z_out    = out + NTOK + (size_t)NTOK*NCLS;

  char* ws = (char*)d_ws;
  size_t off = 0;
  auto alloc = [&](size_t bytes){ void* p = ws + off; off += (bytes + 255) & ~(size_t)255; return p; };
  float*  zbuf = (float*) alloc((size_t)NTOK*DM*4);
  __bf16* xnb  = (__bf16*)alloc((size_t)NTOK*DM*2);
  __bf16* qkvb = (__bf16*)alloc((size_t)NTOK*768*2);
  __bf16* obuf = (__bf16*)alloc((size_t)NTOK*DM*2);
  __bf16* bigb = (__bf16*)alloc((size_t)NTOK*1024*2);
  __bf16* w_proj = (__bf16*)alloc((size_t)262144*2);
  __bf16* w_in   = (__bf16*)alloc((size_t)2359296*2);
  __bf16* w_out  = (__bf16*)alloc((size_t)786432*2);
  __bf16* w_12   = (__bf16*)alloc((size_t)6291456*2);
  __bf16* w_3    = (__bf16*)alloc((size_t)3145728*2);

  cvt_all_kernel<<<2048, 256, 0, stream>>>(proj_w, w_proj, 262144/4,
                                           l_inw, w_in, 2359296/4,
                                           l_outw, w_out, 786432/4,
                                           l_w12, w_12, 6291456/4,
                                           l_w3, w_3, 3145728/4);

  ln1024_kernel<<<NTOK, 256, 0, stream>>>(teacher, in_ln_g, in_ln_b, bigb);
  gemm512_kernel<0, 1024><<<192, 512, 0, stream>>>(bigb, w_proj, proj_b, zbuf, nullptr, 256, 1);
  rope_preln_kernel<<<NTOK/4, 256, 0, stream>>>(zbuf, cosc, sinc, pre_g, pre_b, l_ln1_g, l_ln1_b, xnb);

  for (int i = 0; i < NLAYER; i++){
    gemm512_kernel<1, 256><<<576, 512, 0, stream>>>(xnb, w_in + (size_t)i*768*256, l_inb + i*768, nullptr, qkvb, 768, 3);
    attn_kernel<<<NBATCH, 256, 0, stream>>>(qkvb, obuf);
    gemm_ln_kernel<256><<<256, 512, 0, stream>>>(obuf, w_out + (size_t)i*256*256, l_outb + i*256,
                                                 zbuf, l_ln2_g + i*256, l_ln2_b + i*256, xnb, nullptr);
    gemm_glu_kernel<<<512, 512, 0, stream>>>(xnb, w_12 + (size_t)i*2048*256, l_b12 + i*2048, bigb);
    bool last = (i == NLAYER-1);
    gemm_ln_kernel<1024><<<256, 512, 0, stream>>>(bigb, w_3 + (size_t)i*256*1024, l_b3 + i*256,
                                                  zbuf,
                                                  last ? post_g : l_ln1_g + (i+1)*256,
                                                  last ? post_b : l_ln1_b + (i+1)*256,
                                                  last ? nullptr : xnb,
                                                  last ? z_out : nullptr);
  }

  heads_kernel<<<NTOK/4, 256, 0, stream>>>(z_out, cls_w, cls_b, eg_w1, eg_b1, eg_w2, eg_b2,
                                           halt_w, halt_b, halt_out, cls_out);
}

// Round 14
// 3840.420 us; speedup vs baseline: 1.2376x; 1.0110x over previous
//
#include <hip/hip_runtime.h>
#include <hip/hip_bf16.h>
#include <math.h>

#define L_SEQ 24
#define DT 1024
#define DM 256
#define NLAYER 12
#define NHEAD 4
#define HDIM 64
#define FFND 1024
#define NCLS 2
#define NBATCH 2048
#define NTOK (NBATCH*L_SEQ)   // 49152

typedef float f32x4 __attribute__((ext_vector_type(4)));
typedef __bf16 bf16x4 __attribute__((ext_vector_type(4)));
typedef __bf16 bf16x8 __attribute__((ext_vector_type(8)));

#define GLDS16(gp, lp) __builtin_amdgcn_global_load_lds((const __attribute__((address_space(1))) void*)(gp), (__attribute__((address_space(3))) void*)(lp), 16, 0, 0)
#define VMWAIT(N) asm volatile("s_waitcnt vmcnt(" #N ")" ::: "memory")
#define LGKM0()   asm volatile("s_waitcnt lgkmcnt(0)" ::: "memory")

__device__ inline float wred_sum(float v){
#pragma unroll
  for (int o = 32; o > 0; o >>= 1) v += __shfl_xor(v, o);
  return v;
}
__device__ inline float wred_max(float v){
#pragma unroll
  for (int o = 32; o > 0; o >>= 1) v = fmaxf(v, __shfl_xor(v, o));
  return v;
}

// ---- [R][32]-bf16 LDS tiles, BK=32: linear glds dest + global-source XOR swizzle ----
__device__ __forceinline__ void stage16x32(const __bf16* __restrict__ g, int ldk, int k0,
                                           __bf16* ldsbase, int lane, int rowbase){
  int r = rowbase + (lane >> 2);
  int cs = (lane & 3) ^ ((lane >> 3) & 3);
  GLDS16(g + (size_t)r*ldk + k0 + cs*8, ldsbase);
}
__device__ __forceinline__ bf16x8 frag32(const __bf16* tile, int row, int lane){
  int p = (lane >> 4) ^ ((row >> 1) & 3);
  return *(const bf16x8*)(tile + (row << 5) + (p << 3));
}

// XCD-aware swizzle (T1). Requires gridDim.x % 8 == 0.
__device__ __forceinline__ int xcd_work(){
  int nwg = gridDim.x, bid = blockIdx.x;
  return (bid & 7) * (nwg >> 3) + (bid >> 3);
}

// ---------------- merged weight fp32 -> bf16 convert ----------------
__global__ void cvt_all_kernel(const float* __restrict__ a0, __bf16* __restrict__ o0, int n0,
                               const float* __restrict__ a1, __bf16* __restrict__ o1, int n1,
                               const float* __restrict__ a2, __bf16* __restrict__ o2, int n2,
                               const float* __restrict__ a3, __bf16* __restrict__ o3, int n3,
                               const float* __restrict__ a4, __bf16* __restrict__ o4, int n4){
  int stride = gridDim.x * blockDim.x;
  int i0 = blockIdx.x * blockDim.x + threadIdx.x;
  const float* as[5] = {a0,a1,a2,a3,a4};
  __bf16* os[5] = {o0,o1,o2,o3,o4};
  int ns[5] = {n0,n1,n2,n3,n4};
#pragma unroll
  for (int s = 0; s < 5; s++){
    const float* a = as[s]; __bf16* o = os[s]; int n = ns[s];
    for (int i = i0; i < n; i += stride){
      float4 v = ((const float4*)a)[i];
      bf16x4 ov;
      ov[0] = (__bf16)v.x; ov[1] = (__bf16)v.y; ov[2] = (__bf16)v.z; ov[3] = (__bf16)v.w;
      ((bf16x4*)o)[i] = ov;
    }
  }
}

// ---------------- LN over 1024 (block per row) ----------------
__global__ __launch_bounds__(256) void ln1024_kernel(
    const float* __restrict__ in, const float* __restrict__ g, const float* __restrict__ bb,
    __bf16* __restrict__ out){
  int row = blockIdx.x;
  int tid = threadIdx.x, wid = tid >> 6, lane = tid & 63;
  float4 x = ((const float4*)(in + (size_t)row*DT))[tid];
  float s = x.x + x.y + x.z + x.w;
  float q = x.x*x.x + x.y*x.y + x.z*x.z + x.w*x.w;
  s = wred_sum(s); q = wred_sum(q);
  __shared__ float red[8];
  if (lane == 0){ red[wid] = s; red[4+wid] = q; }
  __syncthreads();
  s = red[0]+red[1]+red[2]+red[3];
  q = red[4]+red[5]+red[6]+red[7];
  float mean = s * (1.f/DT);
  float rstd = rsqrtf(q*(1.f/DT) - mean*mean + 1e-5f);
  float4 gv = ((const float4*)g)[tid], bv = ((const float4*)bb)[tid];
  bf16x4 o;
  o[0] = (__bf16)((x.x-mean)*rstd*gv.x + bv.x);
  o[1] = (__bf16)((x.y-mean)*rstd*gv.y + bv.y);
  o[2] = (__bf16)((x.z-mean)*rstd*gv.z + bv.z);
  o[3] = (__bf16)((x.w-mean)*rstd*gv.w + bv.w);
  ((bf16x4*)(out + (size_t)row*DT))[tid] = o;
}

// ---------------- RoPE + pre-LN + layer0 LN1 (wave per row) ----------------
__global__ __launch_bounds__(256) void rope_preln_kernel(
    float* __restrict__ z, const float* __restrict__ cosc, const float* __restrict__ sinc,
    const float* __restrict__ g, const float* __restrict__ bb,
    const float* __restrict__ g1, const float* __restrict__ b1, __bf16* __restrict__ xnb){
  int row = blockIdx.x*4 + (threadIdx.x >> 6);
  int lane = threadIdx.x & 63;
  int l = row % L_SEQ;
  float4 x = ((const float4*)(z + (size_t)row*DM))[lane];
  float4 p;
  p.x = __shfl_xor(x.x, 32); p.y = __shfl_xor(x.y, 32);
  p.z = __shfl_xor(x.z, 32); p.w = __shfl_xor(x.w, 32);
  float sgn = (lane < 32) ? -1.f : 1.f;
  float4 c = ((const float4*)(cosc + l*DM))[lane];
  float4 sn = ((const float4*)(sinc + l*DM))[lane];
  float4 xr;
  xr.x = x.x*c.x + sgn*p.x*sn.x;
  xr.y = x.y*c.y + sgn*p.y*sn.y;
  xr.z = x.z*c.z + sgn*p.z*sn.z;
  xr.w = x.w*c.w + sgn*p.w*sn.w;
  float s = wred_sum(xr.x + xr.y + xr.z + xr.w);
  float q = wred_sum(xr.x*xr.x + xr.y*xr.y + xr.z*xr.z + xr.w*xr.w);
  float mean = s * (1.f/DM);
  float rstd = rsqrtf(q*(1.f/DM) - mean*mean + 1e-5f);
  float4 gv = ((const float4*)g)[lane], bv = ((const float4*)bb)[lane];
  float4 y;
  y.x = (xr.x-mean)*rstd*gv.x + bv.x;
  y.y = (xr.y-mean)*rstd*gv.y + bv.y;
  y.z = (xr.z-mean)*rstd*gv.z + bv.z;
  y.w = (xr.w-mean)*rstd*gv.w + bv.w;
  ((float4*)(z + (size_t)row*DM))[lane] = y;
  float s2 = wred_sum(y.x + y.y + y.z + y.w);
  float q2 = wred_sum(y.x*y.x + y.y*y.y + y.z*y.z + y.w*y.w);
  float mean2 = s2 * (1.f/DM);
  float rstd2 = rsqrtf(q2*(1.f/DM) - mean2*mean2 + 1e-5f);
  float4 g1v = ((const float4*)g1)[lane], b1v = ((const float4*)b1)[lane];
  bf16x4 o;
  o[0] = (__bf16)((y.x-mean2)*rstd2*g1v.x + b1v.x);
  o[1] = (__bf16)((y.y-mean2)*rstd2*g1v.y + b1v.y);
  o[2] = (__bf16)((y.z-mean2)*rstd2*g1v.z + b1v.z);
  o[3] = (__bf16)((y.w-mean2)*rstd2*g1v.w + b1v.w);
  ((bf16x4*)(xnb + (size_t)row*DM))[lane] = o;
}

// ---------------- GEMM 256x256, 8 waves, BK=32, counted-vmcnt (proj/qkv) ----------------
template<int MODE, int K>
__global__ __launch_bounds__(512) void gemm512_kernel(
    const __bf16* __restrict__ A, const __bf16* __restrict__ W,
    const float* __restrict__ bias,
    float* __restrict__ Cf, __bf16* __restrict__ Cb,
    int N, int nt){
  __shared__ __align__(16) __bf16 As[2][256*32];
  __shared__ __align__(16) __bf16 Bs[2][256*32];
  int work = xcd_work();
  int bm = work / nt, bn = work % nt;
  int wid = threadIdx.x >> 6, lane = threadIdx.x & 63;
  int wr = wid >> 1, wc = wid & 1;
  int li = lane & 15, g4 = (lane >> 4) << 2;
  f32x4 acc[8][4] = {};
  const __bf16* ga = A + (size_t)bm*256*K;
  const __bf16* gb = W + (size_t)bn*256*K;
  const int NT = K/32;
  auto STAGE = [&](int b, int t){
    int k0 = t*32;
    if (wid < 4){
#pragma unroll
      for (int j = 0; j < 4; j++){ int r = (wid*4 + j)*16; stage16x32(ga, K, k0, &As[b][r<<5], lane, r); }
    } else {
#pragma unroll
      for (int j = 0; j < 4; j++){ int r = ((wid-4)*4 + j)*16; stage16x32(gb, K, k0, &Bs[b][r<<5], lane, r); }
    }
  };
  STAGE(0, 0);
  STAGE(1, 1);
  int cur = 0;
  for (int t = 0; t < NT; t++){
    if (t + 1 < NT) { VMWAIT(4); } else { VMWAIT(0); }
    __builtin_amdgcn_s_barrier();
    bf16x8 xf[4], wf[8];
#pragma unroll
    for (int mi = 0; mi < 4; mi++) xf[mi] = frag32(As[cur], wr*64 + mi*16 + li, lane);
#pragma unroll
    for (int ni = 0; ni < 8; ni++) wf[ni] = frag32(Bs[cur], wc*128 + ni*16 + li, lane);
    LGKM0();
    __builtin_amdgcn_sched_barrier(0);
    __builtin_amdgcn_s_barrier();
    if (t + 2 < NT) STAGE(cur, t+2);
    __builtin_amdgcn_s_setprio(1);
#pragma unroll
    for (int ni = 0; ni < 8; ni++)
#pragma unroll
      for (int mi = 0; mi < 4; mi++)
        acc[ni][mi] = __builtin_amdgcn_mfma_f32_16x16x32_bf16(wf[ni], xf[mi], acc[ni][mi], 0, 0, 0);
    __builtin_amdgcn_s_setprio(0);
    cur ^= 1;
  }
#pragma unroll
  for (int mi = 0; mi < 4; mi++){
    int m = bm*256 + wr*64 + mi*16 + li;
#pragma unroll
    for (int ni = 0; ni < 8; ni++){
      int n = bn*256 + wc*128 + ni*16 + g4;
      f32x4 bv = *(const f32x4*)(bias + n);
      f32x4 o = acc[ni][mi] + bv;
      if (MODE == 0){
        *(f32x4*)(Cf + (size_t)m*N + n) = o;
      } else {
        bf16x4 ob;
        ob[0] = (__bf16)o[0]; ob[1] = (__bf16)o[1]; ob[2] = (__bf16)o[2]; ob[3] = (__bf16)o[3];
        *(bf16x4*)(Cb + (size_t)m*N + n) = ob;
      }
    }
  }
}

// ---------------- continuous-pipeline fused w12 GEMM + SwiGLU ----------------
__global__ __launch_bounds__(512) void gemm_glu_kernel(
    const __bf16* __restrict__ A, const __bf16* __restrict__ W12,
    const float* __restrict__ bias, __bf16* __restrict__ H){
  __shared__ __align__(16) __bf16 As[2][256*32];
  __shared__ __align__(16) __bf16 B1s[2][128*32];
  __shared__ __align__(16) __bf16 B2s[2][128*32];
  const int K = 256;
  int work = xcd_work();
  int wid = threadIdx.x >> 6, lane = threadIdx.x & 63;
  int wr = wid >> 1, wc = wid & 1;
  int li = lane & 15, g4 = (lane >> 4) << 2;
  f32x4 acc1[4][4] = {}, acc2[4][4] = {};
  f32x4 B1v[4], B2v[4];
  auto STAGE = [&](int buf, int g){
    int T = work*3 + (g >> 3);
    int bmT = T >> 3, bnT = T & 7;
    int k0 = (g & 7)*32;
    const __bf16* ga  = A   + (size_t)bmT*256*K;
    const __bf16* gb1 = W12 + (size_t)bnT*128*K;
    const __bf16* gb2 = gb1 + (size_t)1024*K;
    if (wid < 4){
#pragma unroll
      for (int j = 0; j < 4; j++){ int r = (wid*4 + j)*16; stage16x32(ga, K, k0, &As[buf][r<<5], lane, r); }
    } else if (wid < 6){
#pragma unroll
      for (int j = 0; j < 4; j++){ int r = ((wid-4)*4 + j)*16; stage16x32(gb1, K, k0, &B1s[buf][r<<5], lane, r); }
    } else {
#pragma unroll
      for (int j = 0; j < 4; j++){ int r = ((wid-6)*4 + j)*16; stage16x32(gb2, K, k0, &B2s[buf][r<<5], lane, r); }
    }
  };
  STAGE(0, 0);
  STAGE(1, 1);
  int cur = 0;
  for (int g = 0; g < 24; g++){
    int k = g & 7;
    if (g == 23)      { VMWAIT(0); }
    else if (k == 0)  { if (g) { VMWAIT(20); } else { VMWAIT(4); } }
    else if (k == 1)  { if (g == 1) { VMWAIT(12); } else { VMWAIT(28); } }
    else if (k == 2)  { VMWAIT(12); }
    else              { VMWAIT(4); }
    __builtin_amdgcn_s_barrier();
    bf16x8 xf[4], w1f[4], w2f[4];
#pragma unroll
    for (int mi = 0; mi < 4; mi++) xf[mi] = frag32(As[cur], wr*64 + mi*16 + li, lane);
#pragma unroll
    for (int ni = 0; ni < 4; ni++){
      w1f[ni] = frag32(B1s[cur], wc*64 + ni*16 + li, lane);
      w2f[ni] = frag32(B2s[cur], wc*64 + ni*16 + li, lane);
    }
    LGKM0();
    __builtin_amdgcn_sched_barrier(0);
    __builtin_amdgcn_s_barrier();
    if (g + 2 < 24) STAGE(cur, g + 2);
    __builtin_amdgcn_sched_barrier(0);
    if (k == 0){
      int bnT = (work*3 + (g >> 3)) & 7;
#pragma unroll
      for (int ni = 0; ni < 4; ni++){
        int n = bnT*128 + wc*64 + ni*16 + g4;
        B1v[ni] = *(const f32x4*)(bias + n);
        B2v[ni] = *(const f32x4*)(bias + 1024 + n);
      }
      __builtin_amdgcn_sched_barrier(0);
    }
    __builtin_amdgcn_s_setprio(1);
#pragma unroll
    for (int ni = 0; ni < 4; ni++)
#pragma unroll
      for (int mi = 0; mi < 4; mi++){
        acc1[ni][mi] = __builtin_amdgcn_mfma_f32_16x16x32_bf16(w1f[ni], xf[mi], acc1[ni][mi], 0, 0, 0);
        acc2[ni][mi] = __builtin_amdgcn_mfma_f32_16x16x32_bf16(w2f[ni], xf[mi], acc2[ni][mi], 0, 0, 0);
      }
    __builtin_amdgcn_s_setprio(0);
    cur ^= 1;
    if (k == 7){
      __builtin_amdgcn_sched_barrier(0);
      int T = work*3 + (g >> 3);
      int bmT = T >> 3, bnT = T & 7;
#pragma unroll
      for (int mi = 0; mi < 4; mi++){
        int m = bmT*256 + wr*64 + mi*16 + li;
#pragma unroll
        for (int ni = 0; ni < 4; ni++){
          int n = bnT*128 + wc*64 + ni*16 + g4;
          bf16x4 ob;
#pragma unroll
          for (int r = 0; r < 4; r++){
            float v1 = acc1[ni][mi][r] + B1v[ni][r];
            float v2 = acc2[ni][mi][r] + B2v[ni][r];
            float sig = 1.f/(1.f + __expf(-v1));
            ob[r] = (__bf16)(v1*sig*v2);
          }
          *(bf16x4*)(H + (size_t)m*FFND + n) = ob;
          acc1[ni][mi] = (f32x4)(0.f);
          acc2[ni][mi] = (f32x4)(0.f);
        }
      }
      __builtin_amdgcn_sched_barrier(0);
    }
  }
}

// ---------------- GEMM 192x256 + residual + LayerNorm, 8 waves, grid 256 ----------------
// z store skipped when outf (last layer: z only feeds z_out = LN(z)).
template<int K>
__global__ __launch_bounds__(512) void gemm_ln_kernel(
    const __bf16* __restrict__ A, const __bf16* __restrict__ W,
    const float* __restrict__ bias, float* __restrict__ z,
    const float* __restrict__ lng, const float* __restrict__ lnb,
    __bf16* __restrict__ outb, float* __restrict__ outf){
  __shared__ __align__(16) __bf16 As[2][192*32];
  __shared__ __align__(16) __bf16 Bs[2][256*32];
  __shared__ float redS[192][2], redQ[192][2];
  int bm = xcd_work();
  int wid = threadIdx.x >> 6, lane = threadIdx.x & 63;
  int wr = wid >> 1, wc = wid & 1;
  int li = lane & 15, g4 = (lane >> 4) << 2;
  f32x4 acc[8][3] = {};
  const __bf16* ga = A + (size_t)bm*192*K;
  const int NT = K/32;
  auto STAGE = [&](int b, int t){
    int k0 = t*32;
    if (wid < 4){
#pragma unroll
      for (int j = 0; j < 3; j++){ int r = (wid*3 + j)*16; stage16x32(ga, K, k0, &As[b][r<<5], lane, r); }
    } else {
#pragma unroll
      for (int j = 0; j < 4; j++){ int r = ((wid-4)*4 + j)*16; stage16x32(W, K, k0, &Bs[b][r<<5], lane, r); }
    }
  };
  STAGE(0, 0);
  STAGE(1, 1);
  int cur = 0;
  for (int t = 0; t < NT; t++){
    if (t + 1 < NT) { if (wid < 4) { VMWAIT(3); } else { VMWAIT(4); } } else { VMWAIT(0); }
    __builtin_amdgcn_s_barrier();
    bf16x8 xf[3], wf[8];
#pragma unroll
    for (int mi = 0; mi < 3; mi++) xf[mi] = frag32(As[cur], wr*48 + mi*16 + li, lane);
#pragma unroll
    for (int ni = 0; ni < 8; ni++) wf[ni] = frag32(Bs[cur], wc*128 + ni*16 + li, lane);
    LGKM0();
    __builtin_amdgcn_sched_barrier(0);
    __builtin_amdgcn_s_barrier();
    if (t + 2 < NT) STAGE(cur, t+2);
    __builtin_amdgcn_s_setprio(1);
#pragma unroll
    for (int ni = 0; ni < 8; ni++)
#pragma unroll
      for (int mi = 0; mi < 3; mi++)
        acc[ni][mi] = __builtin_amdgcn_mfma_f32_16x16x32_bf16(wf[ni], xf[mi], acc[ni][mi], 0, 0, 0);
    __builtin_amdgcn_s_setprio(0);
    cur ^= 1;
  }
  float sA[3] = {}, qA[3] = {};
#pragma unroll
  for (int mi = 0; mi < 3; mi++){
    int m = bm*192 + wr*48 + mi*16 + li;
#pragma unroll
    for (int ni = 0; ni < 8; ni++){
      int n = wc*128 + ni*16 + g4;
      f32x4 zv = *(const f32x4*)(z + (size_t)m*DM + n);
      f32x4 bv = *(const f32x4*)(bias + n);
      f32x4 v = acc[ni][mi] + bv + zv;
      acc[ni][mi] = v;
      if (outb) *(f32x4*)(z + (size_t)m*DM + n) = v;
#pragma unroll
      for (int r = 0; r < 4; r++){ sA[mi] += v[r]; qA[mi] += v[r]*v[r]; }
    }
  }
  __syncthreads();
#pragma unroll
  for (int mi = 0; mi < 3; mi++){
    float s = sA[mi], q = qA[mi];
    s += __shfl_xor(s, 16); q += __shfl_xor(q, 16);
    s += __shfl_xor(s, 32); q += __shfl_xor(q, 32);
    if (lane < 16){ redS[wr*48 + mi*16 + li][wc] = s; redQ[wr*48 + mi*16 + li][wc] = q; }
  }
  __syncthreads();
#pragma unroll
  for (int mi = 0; mi < 3; mi++){
    int ml = wr*48 + mi*16 + li;
    float s = redS[ml][0] + redS[ml][1];
    float q = redQ[ml][0] + redQ[ml][1];
    float mean = s * (1.f/DM);
    float rstd = rsqrtf(q*(1.f/DM) - mean*mean + 1e-5f);
    int m = bm*192 + ml;
#pragma unroll
    for (int ni = 0; ni < 8; ni++){
      int n = wc*128 + ni*16 + g4;
      f32x4 gv = *(const f32x4*)(lng + n);
      f32x4 bv = *(const f32x4*)(lnb + n);
      if (outb){
        bf16x4 o;
#pragma unroll
        for (int r = 0; r < 4; r++) o[r] = (__bf16)((acc[ni][mi][r] - mean)*rstd*gv[r] + bv[r]);
        *(bf16x4*)(outb + (size_t)m*DM + n) = o;
      } else {
        f32x4 o;
#pragma unroll
        for (int r = 0; r < 4; r++) o[r] = (acc[ni][mi][r] - mean)*rstd*gv[r] + bv[r];
        *(f32x4*)(outf + (size_t)m*DM + n) = o;
      }
    }
  }
}

// ---------------- attention: MFMA QK^T + VALU softmax/PV (block/seq, wave/head) --------
// Q/K staged into [32][64] LDS tiles with 16B-slot XOR swizzle (phys = slot ^ (row&7)),
// S = Q K^T via 8x mfma_16x16x32 per wave (acc: m=q=li, n=k=4*(lane>>4)+r). Rows 24-31
// are never written (garbage feeds only unused q>=24 / k>=24 outputs). Softmax and PV
// unchanged from the verified VALU version.
__global__ __launch_bounds__(256) void attn_kernel(const __bf16* __restrict__ qkv, __bf16* __restrict__ ob){
  int b = blockIdx.x;
  int h = threadIdx.x >> 6, lane = threadIdx.x & 63;
  __shared__ __align__(16) __bf16 Qs[NHEAD][32][64];
  __shared__ __align__(16) __bf16 Ks[NHEAD][32][64];
  __shared__ float Ps[NHEAD][L_SEQ][L_SEQ];
  const __bf16* base = qkv + (size_t)b*L_SEQ*768;
  // stage Q,K (vectorized bf16x4): row t, global quad c4; slot = c4>>3, phys = slot^(t&7)
#pragma unroll
  for (int i = 0; i < 6; i++){
    int gq = i*64 + lane;
    int t = gq >> 4, c4 = (gq & 15) << 2;
    int ad = t*64 + ((c4 >> 3) ^ (t & 7))*8 + (c4 & 7);
    *(bf16x4*)&Qs[h][0][ad] = *(const bf16x4*)(base + t*768 + h*64 + c4);
    *(bf16x4*)&Ks[h][0][ad] = *(const bf16x4*)(base + t*768 + 256 + h*64 + c4);
  }
  float V[L_SEQ];
#pragma unroll
  for (int t = 0; t < L_SEQ; t++) V[t] = (float)base[t*768 + 512 + h*64 + lane];
  __syncthreads();
  // S = Q K^T via MFMA (2 k-halves x 2x2 tiles)
  int li = lane & 15, g = lane >> 4;
  f32x4 accs[2][2] = {};   // [kt][qt]
#pragma unroll
  for (int kk = 0; kk < 2; kk++){
    bf16x8 qf[2], kf[2];
#pragma unroll
    for (int x = 0; x < 2; x++){
      int row = x*16 + li;
      int sl = (kk*4 + g) ^ (row & 7);
      qf[x] = *(const bf16x8*)&Qs[h][0][row*64 + sl*8];
      kf[x] = *(const bf16x8*)&Ks[h][0][row*64 + sl*8];
    }
#pragma unroll
    for (int kt = 0; kt < 2; kt++)
#pragma unroll
      for (int qt = 0; qt < 2; qt++)
        accs[kt][qt] = __builtin_amdgcn_mfma_f32_16x16x32_bf16(kf[kt], qf[qt], accs[kt][qt], 0, 0, 0);
  }
  // scatter valid S entries (scaled) into Ps[q][k]
#pragma unroll
  for (int kt = 0; kt < 2; kt++)
#pragma unroll
    for (int qt = 0; qt < 2; qt++){
      int q = qt*16 + li;
      if (q < L_SEQ){
#pragma unroll
        for (int r = 0; r < 4; r++){
          int k = kt*16 + g*4 + r;
          if (k < L_SEQ) Ps[h][q][k] = accs[kt][qt][r] * 0.125f;
        }
      }
    }
  __syncthreads();
  for (int q = 0; q < L_SEQ; q++){
    float v = (lane <= q) ? Ps[h][q][lane] : -1e30f;
    float mx = wred_max(v);
    float e = (lane <= q) ? __expf(v - mx) : 0.f;
    float sm = wred_sum(e);
    if (lane < L_SEQ) Ps[h][q][lane] = e / sm;
  }
  __syncthreads();
  for (int q = 0; q < L_SEQ; q++){
    float o = 0.f;
    for (int k = 0; k <= q; k++) o += Ps[h][q][k] * V[k];
    ob[((size_t)b*L_SEQ + q)*DM + h*64 + lane] = (__bf16)o;
  }
}

// ---------------- per-token heads ----------------
__global__ __launch_bounds__(256) void heads_kernel(
    const float* __restrict__ z,
    const float* __restrict__ cls_w, const float* __restrict__ cls_b,
    const float* __restrict__ eg_w1, const float* __restrict__ eg_b1,
    const float* __restrict__ eg_w2, const float* __restrict__ eg_b2,
    const float* __restrict__ halt_w, const float* __restrict__ halt_b,
    float* __restrict__ halt_out, float* __restrict__ cls_out){
  int m = blockIdx.x*4 + (threadIdx.x >> 6);
  int lane = threadIdx.x & 63;
  int l = m % L_SEQ;
  float4 zv = ((const float4*)(z + (size_t)m*DM))[lane];
  float4 w0 = ((const float4*)(cls_w + ((size_t)l*2 + 0)*DM))[lane];
  float4 w1 = ((const float4*)(cls_w + ((size_t)l*2 + 1)*DM))[lane];
  float c0 = wred_sum(zv.x*w0.x + zv.y*w0.y + zv.z*w0.z + zv.w*w0.w) + cls_b[l*2 + 0];
  float c1 = wred_sum(zv.x*w1.x + zv.y*w1.y + zv.z*w1.z + zv.w*w1.w) + cls_b[l*2 + 1];
  float mx = fmaxf(c0, c1);
  float e0 = __expf(c0 - mx), e1 = __expf(c1 - mx);
  float inv = 1.f/(e0 + e1);
  float p0 = fminf(fmaxf(e0*inv, 1e-10f), 1.f);
  float p1 = fminf(fmaxf(e1*inv, 1e-10f), 1.f);
  float ent = -(p0*__logf(p0) + p1*__logf(p1));
  float entn = fminf(fmaxf(ent * 1.44269504f, 0.f), 1.f);
  const float4* wg = (const float4*)(eg_w1 + ((size_t)l*DM + 4*lane)*8);
  float hacc[8] = {};
#pragma unroll
  for (int dd = 0; dd < 4; dd++){
    float zd = (dd==0) ? zv.x : (dd==1) ? zv.y : (dd==2) ? zv.z : zv.w;
    float4 a = wg[dd*2], b = wg[dd*2 + 1];
    hacc[0] += zd*a.x; hacc[1] += zd*a.y; hacc[2] += zd*a.z; hacc[3] += zd*a.w;
    hacc[4] += zd*b.x; hacc[5] += zd*b.y; hacc[6] += zd*b.z; hacc[7] += zd*b.w;
  }
  float gin = 0.f;
#pragma unroll
  for (int j = 0; j < 8; j++){
    float hj = wred_sum(hacc[j]);
    hj = tanhf(hj + eg_b1[l*8 + j]);
    gin += hj * eg_w2[l*8 + j];
  }
  gin += eg_b2[l];
  float gate = 1.f/(1.f + __expf(-gin));
  float gated = entn * gate;
  const float* hw = halt_w + (size_t)l*257;
  float hp = zv.x*hw[4*lane] + zv.y*hw[4*lane+1] + zv.z*hw[4*lane+2] + zv.w*hw[4*lane+3];
  float hl = wred_sum(hp) + gated*hw[256] + halt_b[l];
  if (lane == 0) halt_out[m] = hl;
  if (lane < 2) cls_out[(size_t)m*2 + lane] = lane ? c1 : c0;
}

extern "C" void kernel_launch(void* const* d_in, const int* in_sizes, int n_in,
                              void* d_out, int out_size, void* d_ws, size_t ws_size,
                              hipStream_t stream){
  const float* teacher = (const float*)d_in[0];
  const float* in_ln_g = (const float*)d_in[1];
  const float* in_ln_b = (const float*)d_in[2];
  const float* proj_w  = (const float*)d_in[3];
  const float* proj_b  = (const float*)d_in[4];
  const float* cosc    = (const float*)d_in[5];
  const float* sinc    = (const float*)d_in[6];
  const float* pre_g   = (const float*)d_in[7];
  const float* pre_b   = (const float*)d_in[8];
  const float* l_ln1_g = (const float*)d_in[9];
  const float* l_ln1_b = (const float*)d_in[10];
  const float* l_inw   = (const float*)d_in[11];
  const float* l_inb   = (const float*)d_in[12];
  const float* l_outw  = (const float*)d_in[13];
  const float* l_outb  = (const float*)d_in[14];
  const float* l_ln2_g = (const float*)d_in[15];
  const float* l_ln2_b = (const float*)d_in[16];
  const float* l_w12   = (const float*)d_in[17];
  const float* l_b12   = (const float*)d_in[18];
  const float* l_w3    = (const float*)d_in[19];
  const float* l_b3    = (const float*)d_in[20];
  const float* post_g  = (const float*)d_in[21];
  const float* post_b  = (const float*)d_in[22];
  const float* eg_w1   = (const float*)d_in[23];
  const float* eg_b1   = (const float*)d_in[24];
  const float* eg_w2   = (const float*)d_in[25];
  const float* eg_b2   = (const float*)d_in[26];
  const float* halt_w  = (const float*)d_in[27];
  const float* halt_b  = (const float*)d_in[28];
  const float* cls_w   = (const float*)d_in[29];
  const float* cls_b   = (const float*)d_in[30];

  float* out = (float*)d_out;
  float* halt_out = out;
  float* cls_out  = out + NTOK;
  float* z_out    = out + NTOK + (size_t)NTOK*NCLS;

  char* ws = (char*)d_ws;
  size_t off = 0;
  auto alloc = [&](size_t bytes){ void* p = ws + off; off += (bytes + 255) & ~(size_t)255; return p; };
  float*  zbuf = (float*) alloc((size_t)NTOK*DM*4);
  __bf16* xnb  = (__bf16*)alloc((size_t)NTOK*DM*2);
  __bf16* qkvb = (__bf16*)alloc((size_t)NTOK*768*2);
  __bf16* obuf = (__bf16*)alloc((size_t)NTOK*DM*2);
  __bf16* bigb = (__bf16*)alloc((size_t)NTOK*1024*2);
  __bf16* w_proj = (__bf16*)alloc((size_t)262144*2);
  __bf16* w_in   = (__bf16*)alloc((size_t)2359296*2);
  __bf16* w_out  = (__bf16*)alloc((size_t)786432*2);
  __bf16* w_12   = (__bf16*)alloc((size_t)6291456*2);
  __bf16* w_3    = (__bf16*)alloc((size_t)3145728*2);

  cvt_all_kernel<<<2048, 256, 0, stream>>>(proj_w, w_proj, 262144/4,
                                           l_inw, w_in, 2359296/4,
                                           l_outw, w_out, 786432/4,
                                           l_w12, w_12, 6291456/4,
                                           l_w3, w_3, 3145728/4);

  ln1024_kernel<<<NTOK, 256, 0, stream>>>(teacher, in_ln_g, in_ln_b, bigb);
  gemm512_kernel<0, 1024><<<192, 512, 0, stream>>>(bigb, w_proj, proj_b, zbuf, nullptr, 256, 1);
  rope_preln_kernel<<<NTOK/4, 256, 0, stream>>>(zbuf, cosc, sinc, pre_g, pre_b, l_ln1_g, l_ln1_b, xnb);

  for (int i = 0; i < NLAYER; i++){
    gemm512_kernel<1, 256><<<576, 512, 0, stream>>>(xnb, w_in + (size_t)i*768*256, l_inb + i*768, nullptr, qkvb, 768, 3);
    attn_kernel<<<NBATCH, 256, 0, stream>>>(qkvb, obuf);
    gemm_ln_kernel<256><<<256, 512, 0, stream>>>(obuf, w_out + (size_t)i*256*256, l_outb + i*256,
                                                 zbuf, l_ln2_g + i*256, l_ln2_b + i*256, xnb, nullptr);
    gemm_glu_kernel<<<512, 512, 0, stream>>>(xnb, w_12 + (size_t)i*2048*256, l_b12 + i*2048, bigb);
    bool last = (i == NLAYER-1);
    gemm_ln_kernel<1024><<<256, 512, 0, stream>>>(bigb, w_3 + (size_t)i*256*1024, l_b3 + i*256,
                                                  zbuf,
                                                  last ? post_g : l_ln1_g + (i+1)*256,
                                                  last ? post_b : l_ln1_b + (i+1)*256,
                                                  last ? nullptr : xnb,
                                                  last ? z_out : nullptr);
  }

  heads_kernel<<<NTOK/4, 256, 0, stream>>>(z_out, cls_w, cls_b, eg_w1, eg_b1, eg_w2, eg_b2,
                                           halt_w, halt_b, halt_out, cls_out);
}